// Round 10
// baseline (1081.908 us; speedup 1.0000x reference)
//
#include <hip/hip_runtime.h>
#include <math.h>

#define NPOINTS 16384
#define KNN     32
#define NBASIS  27

typedef unsigned long long ull;

// ===================== helpers =====================

__device__ __forceinline__ unsigned fkey(float f) {
  // monotone order-preserving map fp32 -> uint32 (3 VALU: ashr, or, xor)
  unsigned u = __float_as_uint(f);
  unsigned m = (unsigned)((int)u >> 31) | 0x80000000u;
  return u ^ m;
}

__device__ __forceinline__ ull shflx64(ull v, int mask) {
  int lo = __shfl_xor((int)(unsigned)(v & 0xFFFFFFFFULL), mask, 64);
  int hi = __shfl_xor((int)(unsigned)(v >> 32), mask, 64);
  return ((ull)(unsigned)hi << 32) | (ull)(unsigned)lo;
}

// ===================== faithful ssyevd(3x3) port (double arith, fp32 eps) ============

__device__ __forceinline__ void slartg_dev(double f, double g, double* c, double* s, double* r) {
#pragma clang fp contract(off)
  // LAPACK >= 3.10 convention (c >= 0)
  if (g == 0.0) { *c = 1.0; *s = 0.0; *r = f; }
  else if (f == 0.0) { *c = 0.0; *s = (g >= 0.0 ? 1.0 : -1.0); *r = fabs(g); }
  else {
    double d = sqrt(f * f + g * g);
    *c = fabs(f) / d;
    *r = (f >= 0.0) ? d : -d;
    *s = g / (*r);
  }
}

__device__ __forceinline__ void slaev2_dev(double a, double b, double c,
                                           double* rt1, double* rt2, double* cs1, double* sn1) {
#pragma clang fp contract(off)
  double sm = a + c, df = a - c, adf = fabs(df), tb = b + b, ab = fabs(tb);
  double acmx, acmn;
  if (fabs(a) > fabs(c)) { acmx = a; acmn = c; } else { acmx = c; acmn = a; }
  double rt;
  if (adf > ab)      rt = adf * sqrt(1.0 + (ab / adf) * (ab / adf));
  else if (adf < ab) rt = ab * sqrt(1.0 + (adf / ab) * (adf / ab));
  else               rt = ab * sqrt(2.0);
  int sgn1;
  if (sm < 0.0) { *rt1 = 0.5 * (sm - rt); sgn1 = -1; *rt2 = (acmx / *rt1) * acmn - (b / *rt1) * b; }
  else if (sm > 0.0) { *rt1 = 0.5 * (sm + rt); sgn1 = 1; *rt2 = (acmx / *rt1) * acmn - (b / *rt1) * b; }
  else { *rt1 = 0.5 * rt; *rt2 = -0.5 * rt; sgn1 = 1; }
  int sgn2; double cs;
  if (df >= 0.0) { cs = df + rt; sgn2 = 1; } else { cs = df - rt; sgn2 = -1; }
  double acs = fabs(cs);
  if (acs > ab) { double ct = -tb / cs; double sn = 1.0 / sqrt(1.0 + ct * ct); *sn1 = sn; *cs1 = ct * sn; }
  else {
    if (ab == 0.0) { *cs1 = 1.0; *sn1 = 0.0; }
    else { double tn = -cs / tb; double c1 = 1.0 / sqrt(1.0 + tn * tn); *cs1 = c1; *sn1 = tn * c1; }
  }
  if (sgn1 == sgn2) { double tn = *cs1; *cs1 = -(*sn1); *sn1 = tn; }
}

// Input: lower triangle of symmetric 3x3 (fp32 cov). Output: V columns in DESCENDING
// eigenvalue order (LAPACK ascending, reversed) = np/jnp eigh + [:, :, ::-1].
__device__ void eigh3(float A00, float A10, float A20, float A11, float A21, float A22,
                      float V[3][3]) {
#pragma clang fp contract(off)
  const double EPS    = 5.9604644775390625e-08;   // fp32 slamch('E')
  const double EPS2   = EPS * EPS;
  const double SAFMIN = 1.1754943508222875e-38;   // fp32 slamch('S')
  double d[3], e[2];
  double tau = 0.0, v2 = 0.0;
  // ---- ssytd2 (uplo='L'), single Householder on [A10; A20]
  {
    double alpha = (double)A10, x = (double)A20;
    double a11 = (double)A11, a21 = (double)A21, a22 = (double)A22;
    double beta;
    if (x == 0.0) { tau = 0.0; v2 = 0.0; beta = alpha; }
    else {
      double nrm = sqrt(alpha * alpha + x * x);          // slapy2
      beta = (alpha >= 0.0) ? -nrm : nrm;                // -sign(nrm, alpha)
      tau = (beta - alpha) / beta;
      v2 = x / (alpha - beta);
    }
    if (tau != 0.0) {
      double w0 = tau * (a11 + a21 * v2);
      double w1 = tau * (a21 + a22 * v2);
      double cc = 0.5 * tau * (w0 + w1 * v2);
      w0 -= cc; w1 -= cc * v2;
      a11 -= 2.0 * w0;
      a21 -= (v2 * w0 + w1);
      a22 -= 2.0 * v2 * w1;
    }
    d[0] = (double)A00; d[1] = a11; d[2] = a22;
    e[0] = beta; e[1] = a21;
  }
  double Z[3][3] = { {1.0, 0.0, 0.0}, {0.0, 1.0, 0.0}, {0.0, 0.0, 1.0} };
  // ---- ssteqr('I', n=3)
  {
    int l1 = 1, jtot = 0;
    const int nmaxit = 90;
    double wc[2], wsn[2];
    while (l1 <= 3) {
      if (l1 > 1) e[l1 - 2] = 0.0;
      int m = 3;
      for (int mm = l1; mm <= 2; ++mm) {
        double tst = fabs(e[mm - 1]);
        if (tst == 0.0) { m = mm; break; }
        if (tst <= (sqrt(fabs(d[mm - 1])) * sqrt(fabs(d[mm]))) * EPS) { e[mm - 1] = 0.0; m = mm; break; }
      }
      int l = l1, lsv = l, lend = m, lendsv = lend;
      l1 = m + 1;
      if (lend == l) continue;
      double anorm = 0.0;
      for (int i = l; i <= lend; ++i)     anorm = fmax(anorm, fabs(d[i - 1]));
      for (int i = l; i <= lend - 1; ++i) anorm = fmax(anorm, fabs(e[i - 1]));
      if (anorm == 0.0) continue;
      if (fabs(d[lend - 1]) < fabs(d[l - 1])) { lend = lsv; l = lendsv; }
      if (lend > l) {
        // ===== QL =====
        bool done = false;
        while (!done) {
          int mq = lend;
          for (int mm = l; mm <= lend - 1; ++mm) {
            double tst = e[mm - 1] * e[mm - 1];
            if (tst <= (EPS2 * fabs(d[mm - 1])) * fabs(d[mm]) + SAFMIN) { mq = mm; break; }
          }
          if (mq < lend) e[mq - 1] = 0.0;
          double p = d[l - 1];
          if (mq == l) { d[l - 1] = p; ++l; if (l > lend) done = true; continue; }
          if (mq == l + 1) {
            double rt1, rt2, cc, ssn;
            slaev2_dev(d[l - 1], e[l - 1], d[l], &rt1, &rt2, &cc, &ssn);
            for (int i = 0; i < 3; ++i) {
              double t = Z[i][l];
              Z[i][l]     = cc * t - ssn * Z[i][l - 1];
              Z[i][l - 1] = ssn * t + cc * Z[i][l - 1];
            }
            d[l - 1] = rt1; d[l] = rt2; e[l - 1] = 0.0;
            l += 2; if (l > lend) done = true; continue;
          }
          if (jtot >= nmaxit) break;
          ++jtot;
          double g = (d[l] - p) / (2.0 * e[l - 1]);
          double r = sqrt(g * g + 1.0);
          g = d[mq - 1] - p + e[l - 1] / (g + ((g >= 0.0) ? r : -r));
          double ssn = 1.0, cc = 1.0;
          p = 0.0;
          for (int i = mq - 1; i >= l; --i) {
            double f = ssn * e[i - 1], b = cc * e[i - 1];
            slartg_dev(g, f, &cc, &ssn, &r);
            if (i != mq - 1) e[i] = r;
            g = d[i] - p;
            r = (d[i - 1] - g) * ssn + 2.0 * cc * b;
            p = ssn * r;
            d[i] = g + p;
            g = cc * r - b;
            wc[i - 1] = cc; wsn[i - 1] = -ssn;
          }
          for (int j = mq - 1; j >= l; --j) {
            double cj = wc[j - 1], sj = wsn[j - 1];
            for (int i = 0; i < 3; ++i) {
              double t = Z[i][j];
              Z[i][j]     = cj * t - sj * Z[i][j - 1];
              Z[i][j - 1] = sj * t + cj * Z[i][j - 1];
            }
          }
          d[l - 1] -= p; e[l - 1] = g;
        }
      } else {
        // ===== QR =====
        bool done = false;
        while (!done) {
          int mq = lend;
          for (int mm = l; mm >= lend + 1; --mm) {
            double tst = e[mm - 2] * e[mm - 2];
            if (tst <= (EPS2 * fabs(d[mm - 1])) * fabs(d[mm - 2]) + SAFMIN) { mq = mm; break; }
          }
          if (mq > lend) e[mq - 2] = 0.0;
          double p = d[l - 1];
          if (mq == l) { d[l - 1] = p; --l; if (l < lend) done = true; continue; }
          if (mq == l - 1) {
            double rt1, rt2, cc, ssn;
            slaev2_dev(d[l - 2], e[l - 2], d[l - 1], &rt1, &rt2, &cc, &ssn);
            for (int i = 0; i < 3; ++i) {
              double t = Z[i][l - 1];
              Z[i][l - 1] = cc * t - ssn * Z[i][l - 2];
              Z[i][l - 2] = ssn * t + cc * Z[i][l - 2];
            }
            d[l - 2] = rt1; d[l - 1] = rt2; e[l - 2] = 0.0;
            l -= 2; if (l < lend) done = true; continue;
          }
          if (jtot >= nmaxit) break;
          ++jtot;
          double g = (d[l - 2] - p) / (2.0 * e[l - 2]);
          double r = sqrt(g * g + 1.0);
          g = d[mq - 1] - p + e[l - 2] / (g + ((g >= 0.0) ? r : -r));
          double ssn = 1.0, cc = 1.0;
          p = 0.0;
          for (int i = mq; i <= l - 1; ++i) {
            double f = ssn * e[i - 1], b = cc * e[i - 1];
            slartg_dev(g, f, &cc, &ssn, &r);
            if (i != mq) e[i - 2] = r;
            g = d[i - 1] - p;
            r = (d[i] - g) * ssn + 2.0 * cc * b;
            p = ssn * r;
            d[i - 1] = g + p;
            g = cc * r - b;
            wc[i - 1] = cc; wsn[i - 1] = ssn;
          }
          for (int j = mq; j <= l - 1; ++j) {
            double cj = wc[j - 1], sj = wsn[j - 1];
            for (int i = 0; i < 3; ++i) {
              double t = Z[i][j];
              Z[i][j]     = cj * t - sj * Z[i][j - 1];
              Z[i][j - 1] = sj * t + cj * Z[i][j - 1];
            }
          }
          d[l - 1] -= p; e[l - 2] = g;
        }
      }
    }
    // ---- ascending selection sort with column swaps (as in ssteqr)
    for (int ii = 2; ii <= 3; ++ii) {
      int i0 = ii - 1, k = i0;
      double p = d[i0 - 1];
      for (int j = ii; j <= 3; ++j) if (d[j - 1] < p) { k = j; p = d[j - 1]; }
      if (k != i0) {
        d[k - 1] = d[i0 - 1]; d[i0 - 1] = p;
        for (int rr = 0; rr < 3; ++rr) { double t = Z[rr][i0 - 1]; Z[rr][i0 - 1] = Z[rr][k - 1]; Z[rr][k - 1] = t; }
      }
    }
  }
  // ---- sormtr: Z := H1 * Z
  if (tau != 0.0) {
    for (int j = 0; j < 3; ++j) {
      double w = Z[1][j] + v2 * Z[2][j];
      Z[1][j] -= tau * w;
      Z[2][j] -= tau * v2 * w;
    }
  }
  for (int i = 0; i < 3; ++i)
    for (int j = 0; j < 3; ++j)
      V[i][j] = (float)Z[i][2 - j];
}

// ===================== kernel 0: pack pos -> float4 {x,y,z,sq} =====================
__global__ __launch_bounds__(256) void pack_kernel(const float* __restrict__ pos,
                                                   float4* __restrict__ pos4) {
#pragma clang fp contract(off)
  int i = blockIdx.x * 256 + threadIdx.x;
  if (i < NPOINTS) {
    float x = pos[3 * i + 0], y = pos[3 * i + 1], z = pos[3 * i + 2];
    float sq = (x * x + y * y) + z * z;   // XLA reduce order (same as r6)
    pos4[i] = make_float4(x, y, z, sq);
  }
}

// ===================== kernel 1: exact KNN, 4 rows/wave, threshold + compact ============
// Order: C = (fkey(d2) << 32) | (0xFFFFFFFF - idx). 32 smallest C == r6-verified
// semantics (key asc, ties -> HIGHER index first). Chain-A d2 unchanged.
#define WPB 4    // waves per block
#define RPW 4    // rows per wave -> 16 rows per block
#define CAP 128  // candidate capacity per row (overflow P ~ 0; serial fallback kept)

__global__ __launch_bounds__(256) void knn_kernel(const float4* __restrict__ pos4,
                                                  unsigned* __restrict__ idx_out) {
#pragma clang fp contract(off)
  __shared__ ull cand[WPB][RPW][CAP];
  __shared__ ull sel[WPB][RPW][KNN];
  const int tid  = threadIdx.x;
  const int lane = tid & 63;
  const int wave = tid >> 6;
  const int rowbase = (blockIdx.x * WPB + wave) * RPW;

  float rx[RPW], ry[RPW], rz[RPW], rq[RPW];
#pragma unroll
  for (int r = 0; r < RPW; ++r) {
    const float4 rp = pos4[rowbase + r];
    rx[r] = rp.x; ry[r] = rp.y; rz[r] = rp.z; rq[r] = rp.w;
  }

  // ---- phase A: branchless per-lane top-2 keys, 4 rows per point-load ----
  unsigned k1[RPW], k2[RPW];
#pragma unroll
  for (int r = 0; r < RPW; ++r) { k1[r] = 0xFFFFFFFFu; k2[r] = 0xFFFFFFFFu; }
#pragma unroll 2
  for (int ch = 0; ch < NPOINTS / 64; ++ch) {
    const int j = ch * 64 + lane;
    const float4 p = pos4[j];
#pragma unroll
    for (int r = 0; r < RPW; ++r) {
      const float mdot = __builtin_fmaf(rz[r], p.z, __builtin_fmaf(ry[r], p.y, rx[r] * p.x));
      const float d2 = (rq[r] + p.w) - 2.0f * mdot;
      const unsigned key = fkey(d2);
      const unsigned t = (k1[r] > key) ? k1[r] : key;
      k1[r] = (k1[r] < key) ? k1[r] : key;
      k2[r] = (k2[r] < t) ? k2[r] : t;
    }
  }

  // ---- per-row Tt = 32nd smallest of pool {k1,k2} x 64 lanes (>= true T32) ----
  unsigned Tt[RPW];
#pragma unroll
  for (int r = 0; r < RPW; ++r) {
    int head = 0;
    unsigned T = 0;
    for (int it = 0; it < KNN; ++it) {
      unsigned v = (head == 0) ? k1[r] : ((head == 1) ? k2[r] : 0xFFFFFFFFu);
      unsigned m = v;
      for (int off = 1; off < 64; off <<= 1) {
        unsigned o = (unsigned)__shfl_xor((int)m, off, 64);
        m = (o < m) ? o : m;
      }
      ull win = __ballot(v == m);
      int wl = __ffsll((long long)win) - 1;
      if (lane == wl) ++head;
      T = m;
    }
    Tt[r] = T;
  }

  // ---- phase B: compact candidates with key <= Tt per row ----
  unsigned cnt[RPW];
#pragma unroll
  for (int r = 0; r < RPW; ++r) cnt[r] = 0;
#pragma unroll 2
  for (int ch = 0; ch < NPOINTS / 64; ++ch) {
    const int j = ch * 64 + lane;
    const float4 p = pos4[j];
#pragma unroll
    for (int r = 0; r < RPW; ++r) {
      const float mdot = __builtin_fmaf(rz[r], p.z, __builtin_fmaf(ry[r], p.y, rx[r] * p.x));
      const float d2 = (rq[r] + p.w) - 2.0f * mdot;
      const unsigned key = fkey(d2);
      const bool c = (key <= Tt[r]);
      const ull m = __ballot(c);
      if (c) {
        unsigned slot = cnt[r] + (unsigned)__popcll(m & ((1ULL << lane) - 1ULL));
        if (slot < CAP)
          cand[wave][r][slot] = ((ull)key << 32) | (ull)(0xFFFFFFFFu - (unsigned)j);
      }
      cnt[r] += (unsigned)__popcll(m);
    }
  }
  __builtin_amdgcn_s_waitcnt(0);   // drain our ds_writes (wave-private region)

#pragma unroll
  for (int r = 0; r < RPW; ++r) {
    if (cnt[r] <= (unsigned)CAP) {
      // exact wave-parallel extraction of 32 smallest C from <=128 candidates
      ull c0 = (lane < (int)cnt[r]) ? cand[wave][r][lane] : ~0ULL;
      ull c1 = ((lane + 64) < (int)cnt[r]) ? cand[wave][r][lane + 64] : ~0ULL;
      ull lo = (c0 < c1) ? c0 : c1;
      ull hi = (c0 < c1) ? c1 : c0;
      int head = 0;
      for (int it = 0; it < KNN; ++it) {
        ull v = (head == 0) ? lo : ((head == 1) ? hi : ~0ULL);
        ull m = v;
        for (int off = 1; off < 64; off <<= 1) {
          ull o = shflx64(m, off);
          m = (o < m) ? o : m;
        }
        ull win = __ballot(v == m);
        int wl = __ffsll((long long)win) - 1;
        if (lane == wl) ++head;
        if (lane == 0) sel[wave][r][it] = m;
      }
    } else {
      // exact serial fallback (probability ~0)
      if (lane == 0) {
        int n2 = 0;
        for (int j = 0; j < NPOINTS; ++j) {
          const float4 p = pos4[j];
          const float mdot = __builtin_fmaf(rz[r], p.z, __builtin_fmaf(ry[r], p.y, rx[r] * p.x));
          const float d2 = (rq[r] + p.w) - 2.0f * mdot;
          const unsigned key = fkey(d2);
          const ull C = ((ull)key << 32) | (ull)(0xFFFFFFFFu - (unsigned)j);
          if (n2 < KNN) {
            int b = n2 - 1;
            while (b >= 0 && sel[wave][r][b] > C) { sel[wave][r][b + 1] = sel[wave][r][b]; --b; }
            sel[wave][r][b + 1] = C;
            ++n2;
          } else if (C < sel[wave][r][KNN - 1]) {
            int b = KNN - 2;
            while (b >= 0 && sel[wave][r][b] > C) { sel[wave][r][b + 1] = sel[wave][r][b]; --b; }
            sel[wave][r][b + 1] = C;
          }
        }
      }
    }
  }
  __builtin_amdgcn_s_waitcnt(0);

  // finalize (lane 0): decompose, sort by (key asc, idx asc), emit (as r6/r8/r9)
  if (lane == 0) {
#pragma unroll
    for (int r = 0; r < RPW; ++r) {
      unsigned kk[KNN], ii[KNN];
      for (int a = 0; a < KNN; ++a) {
        ull C = sel[wave][r][a];
        kk[a] = (unsigned)(C >> 32);
        ii[a] = 0xFFFFFFFFu - (unsigned)(C & 0xFFFFFFFFULL);
      }
      for (int a = 1; a < KNN; ++a) {
        unsigned ka = kk[a], ia = ii[a];
        int b = a - 1;
        while (b >= 0 && (kk[b] > ka || (kk[b] == ka && ii[b] > ia))) {
          kk[b + 1] = kk[b]; ii[b + 1] = ii[b]; --b;
        }
        kk[b + 1] = ka; ii[b + 1] = ia;
      }
      unsigned ob = (unsigned)(rowbase + r) * KNN;
      for (int a = 0; a < KNN; ++a) idx_out[ob + a] = ii[a];
    }
  }
}

// ===================== kernel 2: mean + cov + eigh per point (fp32) =====================
__global__ __launch_bounds__(256) void pca_kernel(const float* __restrict__ pos,
                                                  const unsigned* __restrict__ idx,
                                                  float* __restrict__ center,
                                                  float* __restrict__ Vmat) {
#pragma clang fp contract(off)
  int n = blockIdx.x * 256 + threadIdx.x;
  if (n >= NPOINTS) return;
  float sx = 0.f, sy = 0.f, sz = 0.f;
  for (int k = 0; k < KNN; ++k) {
    unsigned j = idx[n * KNN + k];
    sx += pos[j * 3 + 0];
    sy += pos[j * 3 + 1];
    sz += pos[j * 3 + 2];
  }
  float cx = sx * 0.03125f, cy = sy * 0.03125f, cz = sz * 0.03125f;
  float c00 = 0.f, c10 = 0.f, c20 = 0.f, c11 = 0.f, c21 = 0.f, c22 = 0.f;
  for (int k = 0; k < KNN; ++k) {
    unsigned j = idx[n * KNN + k];
    float lx = pos[j * 3 + 0] - cx;
    float ly = pos[j * 3 + 1] - cy;
    float lz = pos[j * 3 + 2] - cz;
    c00 += lx * lx; c10 += lx * ly; c20 += lx * lz;
    c11 += ly * ly; c21 += ly * lz; c22 += lz * lz;
  }
  c00 *= 0.03125f; c10 *= 0.03125f; c20 *= 0.03125f;
  c11 *= 0.03125f; c21 *= 0.03125f; c22 *= 0.03125f;
  float V[3][3];
  eigh3(c00, c10, c20, c11, c21, c22, V);
  center[n * 3 + 0] = cx; center[n * 3 + 1] = cy; center[n * 3 + 2] = cz;
  for (int i = 0; i < 3; ++i)
    for (int j2 = 0; j2 < 3; ++j2)
      Vmat[n * 9 + i * 3 + j2] = V[i][j2];
}

// ===================== kernel 3: basis + G[b,i] + 27x (64x64) matmuls =====================
#define NT 8
__global__ __launch_bounds__(256) void conv_kernel(const float* __restrict__ pos,
                                                   const float* __restrict__ chan,
                                                   const float* __restrict__ coeff,
                                                   const unsigned* __restrict__ idx,
                                                   const float* __restrict__ center,
                                                   const float* __restrict__ Vmat,
                                                   float* __restrict__ out) {
#pragma clang fp contract(off)
  __shared__ float G[NT][NBASIS][64];
  __shared__ float Tsh[NT][64];
  const int tid  = threadIdx.x;
  const int lane = tid & 63;
  const int wave = tid >> 6;
  const int n0 = blockIdx.x * NT;

  for (int rep = 0; rep < 2; ++rep) {
    const int nl = wave * 2 + rep;
    const int n = n0 + nl;
    const float cx = center[n * 3 + 0], cy = center[n * 3 + 1], cz = center[n * 3 + 2];
    const float V00 = Vmat[n * 9 + 0], V01 = Vmat[n * 9 + 1], V02 = Vmat[n * 9 + 2];
    const float V10 = Vmat[n * 9 + 3], V11 = Vmat[n * 9 + 4], V12 = Vmat[n * 9 + 5];
    const float V20 = Vmat[n * 9 + 6], V21 = Vmat[n * 9 + 7], V22 = Vmat[n * 9 + 8];
    float g[NBASIS];
#pragma unroll
    for (int b = 0; b < NBASIS; ++b) g[b] = 0.f;
    for (int k = 0; k < KNN; ++k) {
      const unsigned j = idx[n * KNN + k];
      const float lx = pos[j * 3 + 0] - cx;
      const float ly = pos[j * 3 + 1] - cy;
      const float lz = pos[j * 3 + 2] - cz;
      const float X  = lx * V00 + ly * V10 + lz * V20;
      const float Y  = lx * V01 + ly * V11 + lz * V21;
      const float Zc = lx * V02 + ly * V12 + lz * V22;
      const float r = sqrtf(((X * X + Y * Y) + Zc * Zc) + 1e-8f);
      float u = Zc / r;
      u = fminf(fmaxf(u, -0.999999f), 0.999999f);
      const float ct1 = u, ct2 = 2.f * u * u - 1.f;
      const float rho2 = X * X + Y * Y;
      const float cp1 = (rho2 > 0.f) ? (X / sqrtf(rho2)) : 1.f;
      const float cp2 = 2.f * cp1 * cp1 - 1.f;
      const float f = chan[(size_t)j * 64 + lane];
      const float pr1 = r, pr2 = r * r;
      float tc[9];
      tc[0] = 1.f; tc[1] = cp1; tc[2] = cp2;
      tc[3] = ct1; tc[4] = ct1 * cp1; tc[5] = ct1 * cp2;
      tc[6] = ct2; tc[7] = ct2 * cp1; tc[8] = ct2 * cp2;
#pragma unroll
      for (int m9 = 0; m9 < 9; ++m9) {
        g[m9]      = __builtin_fmaf(tc[m9],       f, g[m9]);
        g[9 + m9]  = __builtin_fmaf(pr1 * tc[m9], f, g[9 + m9]);
        g[18 + m9] = __builtin_fmaf(pr2 * tc[m9], f, g[18 + m9]);
      }
    }
#pragma unroll
    for (int b = 0; b < NBASIS; ++b) G[nl][b][lane] = g[b];
  }
  __syncthreads();

  float acc0 = 0.f, acc1 = 0.f;
  for (int b = 0; b < NBASIS; ++b) {
#pragma unroll 8
    for (int i = 0; i < 64; ++i) {
      const float c = coeff[(size_t)(b * 64 + i) * 64 + lane];
      acc0 = __builtin_fmaf(c, G[wave * 2 + 0][b][i], acc0);
      acc1 = __builtin_fmaf(c, G[wave * 2 + 1][b][i], acc1);
    }
  }
  __syncthreads();
  Tsh[wave * 2 + 0][lane] = acc0 * 0.03125f;
  Tsh[wave * 2 + 1][lane] = acc1 * 0.03125f;
  __syncthreads();
#pragma unroll
  for (int s = 0; s < 2; ++s) {
    const int el = tid + s * 256;
    const int o = el >> 3, nn = el & 7;
    out[(size_t)o * NPOINTS + (n0 + nn)] = Tsh[nn][o];
  }
}

// ===================== launch =====================
extern "C" void kernel_launch(void* const* d_in, const int* in_sizes, int n_in,
                              void* d_out, int out_size, void* d_ws, size_t ws_size,
                              hipStream_t stream) {
  (void)in_sizes; (void)n_in; (void)out_size; (void)ws_size;
  const float* pos   = (const float*)d_in[0];
  const float* chan  = (const float*)d_in[1];
  const float* coeff = (const float*)d_in[2];
  float* out = (float*)d_out;
  unsigned char* ws = (unsigned char*)d_ws;
  float4*   pos4   = (float4*)(ws);                                    // 256 KiB
  unsigned* idx    = (unsigned*)(ws + (size_t)NPOINTS * 16);           // 2 MiB
  float*    center = (float*)(ws + (size_t)NPOINTS * 16 + (size_t)NPOINTS * KNN * 4);          // 192 KiB
  float*    Vmat   = (float*)(ws + (size_t)NPOINTS * 16 + (size_t)NPOINTS * KNN * 4
                              + (size_t)NPOINTS * 12);                 // 576 KiB
  hipLaunchKernelGGL(pack_kernel, dim3(NPOINTS / 256),        dim3(256), 0, stream, pos, pos4);
  hipLaunchKernelGGL(knn_kernel,  dim3(NPOINTS / (WPB * RPW)), dim3(256), 0, stream, pos4, idx);
  hipLaunchKernelGGL(pca_kernel,  dim3(NPOINTS / 256),        dim3(256), 0, stream, pos, idx, center, Vmat);
  hipLaunchKernelGGL(conv_kernel, dim3(NPOINTS / NT),         dim3(256), 0, stream, pos, chan, coeff, idx, center, Vmat, out);
}

// Round 11
// 1034.977 us; speedup vs baseline: 1.0453x; 1.0453x over previous
//
#include <hip/hip_runtime.h>
#include <math.h>

#define NPOINTS 16384
#define KNN     32
#define NBASIS  27

typedef unsigned long long ull;

// ===================== helpers =====================

__device__ __forceinline__ unsigned fkey(float f) {
  // monotone order-preserving map fp32 -> uint32 (3 VALU: ashr, or, xor)
  unsigned u = __float_as_uint(f);
  unsigned m = (unsigned)((int)u >> 31) | 0x80000000u;
  return u ^ m;
}

__device__ __forceinline__ ull shflx64(ull v, int mask) {
  int lo = __shfl_xor((int)(unsigned)(v & 0xFFFFFFFFULL), mask, 64);
  int hi = __shfl_xor((int)(unsigned)(v >> 32), mask, 64);
  return ((ull)(unsigned)hi << 32) | (ull)(unsigned)lo;
}

// ===================== faithful ssyevd(3x3) port (double arith, fp32 eps) ============

__device__ __forceinline__ void slartg_dev(double f, double g, double* c, double* s, double* r) {
#pragma clang fp contract(off)
  // LAPACK >= 3.10 convention (c >= 0)
  if (g == 0.0) { *c = 1.0; *s = 0.0; *r = f; }
  else if (f == 0.0) { *c = 0.0; *s = (g >= 0.0 ? 1.0 : -1.0); *r = fabs(g); }
  else {
    double d = sqrt(f * f + g * g);
    *c = fabs(f) / d;
    *r = (f >= 0.0) ? d : -d;
    *s = g / (*r);
  }
}

__device__ __forceinline__ void slaev2_dev(double a, double b, double c,
                                           double* rt1, double* rt2, double* cs1, double* sn1) {
#pragma clang fp contract(off)
  double sm = a + c, df = a - c, adf = fabs(df), tb = b + b, ab = fabs(tb);
  double acmx, acmn;
  if (fabs(a) > fabs(c)) { acmx = a; acmn = c; } else { acmx = c; acmn = a; }
  double rt;
  if (adf > ab)      rt = adf * sqrt(1.0 + (ab / adf) * (ab / adf));
  else if (adf < ab) rt = ab * sqrt(1.0 + (adf / ab) * (adf / ab));
  else               rt = ab * sqrt(2.0);
  int sgn1;
  if (sm < 0.0) { *rt1 = 0.5 * (sm - rt); sgn1 = -1; *rt2 = (acmx / *rt1) * acmn - (b / *rt1) * b; }
  else if (sm > 0.0) { *rt1 = 0.5 * (sm + rt); sgn1 = 1; *rt2 = (acmx / *rt1) * acmn - (b / *rt1) * b; }
  else { *rt1 = 0.5 * rt; *rt2 = -0.5 * rt; sgn1 = 1; }
  int sgn2; double cs;
  if (df >= 0.0) { cs = df + rt; sgn2 = 1; } else { cs = df - rt; sgn2 = -1; }
  double acs = fabs(cs);
  if (acs > ab) { double ct = -tb / cs; double sn = 1.0 / sqrt(1.0 + ct * ct); *sn1 = sn; *cs1 = ct * sn; }
  else {
    if (ab == 0.0) { *cs1 = 1.0; *sn1 = 0.0; }
    else { double tn = -cs / tb; double c1 = 1.0 / sqrt(1.0 + tn * tn); *cs1 = c1; *sn1 = tn * c1; }
  }
  if (sgn1 == sgn2) { double tn = *cs1; *cs1 = -(*sn1); *sn1 = tn; }
}

// Input: lower triangle of symmetric 3x3 (fp32 cov). Output: V columns in DESCENDING
// eigenvalue order (LAPACK ascending, reversed) = np/jnp eigh + [:, :, ::-1].
__device__ void eigh3(float A00, float A10, float A20, float A11, float A21, float A22,
                      float V[3][3]) {
#pragma clang fp contract(off)
  const double EPS    = 5.9604644775390625e-08;   // fp32 slamch('E')
  const double EPS2   = EPS * EPS;
  const double SAFMIN = 1.1754943508222875e-38;   // fp32 slamch('S')
  double d[3], e[2];
  double tau = 0.0, v2 = 0.0;
  // ---- ssytd2 (uplo='L'), single Householder on [A10; A20]
  {
    double alpha = (double)A10, x = (double)A20;
    double a11 = (double)A11, a21 = (double)A21, a22 = (double)A22;
    double beta;
    if (x == 0.0) { tau = 0.0; v2 = 0.0; beta = alpha; }
    else {
      double nrm = sqrt(alpha * alpha + x * x);          // slapy2
      beta = (alpha >= 0.0) ? -nrm : nrm;                // -sign(nrm, alpha)
      tau = (beta - alpha) / beta;
      v2 = x / (alpha - beta);
    }
    if (tau != 0.0) {
      double w0 = tau * (a11 + a21 * v2);
      double w1 = tau * (a21 + a22 * v2);
      double cc = 0.5 * tau * (w0 + w1 * v2);
      w0 -= cc; w1 -= cc * v2;
      a11 -= 2.0 * w0;
      a21 -= (v2 * w0 + w1);
      a22 -= 2.0 * v2 * w1;
    }
    d[0] = (double)A00; d[1] = a11; d[2] = a22;
    e[0] = beta; e[1] = a21;
  }
  double Z[3][3] = { {1.0, 0.0, 0.0}, {0.0, 1.0, 0.0}, {0.0, 0.0, 1.0} };
  // ---- ssteqr('I', n=3)
  {
    int l1 = 1, jtot = 0;
    const int nmaxit = 90;
    double wc[2], wsn[2];
    while (l1 <= 3) {
      if (l1 > 1) e[l1 - 2] = 0.0;
      int m = 3;
      for (int mm = l1; mm <= 2; ++mm) {
        double tst = fabs(e[mm - 1]);
        if (tst == 0.0) { m = mm; break; }
        if (tst <= (sqrt(fabs(d[mm - 1])) * sqrt(fabs(d[mm]))) * EPS) { e[mm - 1] = 0.0; m = mm; break; }
      }
      int l = l1, lsv = l, lend = m, lendsv = lend;
      l1 = m + 1;
      if (lend == l) continue;
      double anorm = 0.0;
      for (int i = l; i <= lend; ++i)     anorm = fmax(anorm, fabs(d[i - 1]));
      for (int i = l; i <= lend - 1; ++i) anorm = fmax(anorm, fabs(e[i - 1]));
      if (anorm == 0.0) continue;
      if (fabs(d[lend - 1]) < fabs(d[l - 1])) { lend = lsv; l = lendsv; }
      if (lend > l) {
        // ===== QL =====
        bool done = false;
        while (!done) {
          int mq = lend;
          for (int mm = l; mm <= lend - 1; ++mm) {
            double tst = e[mm - 1] * e[mm - 1];
            if (tst <= (EPS2 * fabs(d[mm - 1])) * fabs(d[mm]) + SAFMIN) { mq = mm; break; }
          }
          if (mq < lend) e[mq - 1] = 0.0;
          double p = d[l - 1];
          if (mq == l) { d[l - 1] = p; ++l; if (l > lend) done = true; continue; }
          if (mq == l + 1) {
            double rt1, rt2, cc, ssn;
            slaev2_dev(d[l - 1], e[l - 1], d[l], &rt1, &rt2, &cc, &ssn);
            for (int i = 0; i < 3; ++i) {
              double t = Z[i][l];
              Z[i][l]     = cc * t - ssn * Z[i][l - 1];
              Z[i][l - 1] = ssn * t + cc * Z[i][l - 1];
            }
            d[l - 1] = rt1; d[l] = rt2; e[l - 1] = 0.0;
            l += 2; if (l > lend) done = true; continue;
          }
          if (jtot >= nmaxit) break;
          ++jtot;
          double g = (d[l] - p) / (2.0 * e[l - 1]);
          double r = sqrt(g * g + 1.0);
          g = d[mq - 1] - p + e[l - 1] / (g + ((g >= 0.0) ? r : -r));
          double ssn = 1.0, cc = 1.0;
          p = 0.0;
          for (int i = mq - 1; i >= l; --i) {
            double f = ssn * e[i - 1], b = cc * e[i - 1];
            slartg_dev(g, f, &cc, &ssn, &r);
            if (i != mq - 1) e[i] = r;
            g = d[i] - p;
            r = (d[i - 1] - g) * ssn + 2.0 * cc * b;
            p = ssn * r;
            d[i] = g + p;
            g = cc * r - b;
            wc[i - 1] = cc; wsn[i - 1] = -ssn;
          }
          for (int j = mq - 1; j >= l; --j) {
            double cj = wc[j - 1], sj = wsn[j - 1];
            for (int i = 0; i < 3; ++i) {
              double t = Z[i][j];
              Z[i][j]     = cj * t - sj * Z[i][j - 1];
              Z[i][j - 1] = sj * t + cj * Z[i][j - 1];
            }
          }
          d[l - 1] -= p; e[l - 1] = g;
        }
      } else {
        // ===== QR =====
        bool done = false;
        while (!done) {
          int mq = lend;
          for (int mm = l; mm >= lend + 1; --mm) {
            double tst = e[mm - 2] * e[mm - 2];
            if (tst <= (EPS2 * fabs(d[mm - 1])) * fabs(d[mm - 2]) + SAFMIN) { mq = mm; break; }
          }
          if (mq > lend) e[mq - 2] = 0.0;
          double p = d[l - 1];
          if (mq == l) { d[l - 1] = p; --l; if (l < lend) done = true; continue; }
          if (mq == l - 1) {
            double rt1, rt2, cc, ssn;
            slaev2_dev(d[l - 2], e[l - 2], d[l - 1], &rt1, &rt2, &cc, &ssn);
            for (int i = 0; i < 3; ++i) {
              double t = Z[i][l - 1];
              Z[i][l - 1] = cc * t - ssn * Z[i][l - 2];
              Z[i][l - 2] = ssn * t + cc * Z[i][l - 2];
            }
            d[l - 2] = rt1; d[l - 1] = rt2; e[l - 2] = 0.0;
            l -= 2; if (l < lend) done = true; continue;
          }
          if (jtot >= nmaxit) break;
          ++jtot;
          double g = (d[l - 2] - p) / (2.0 * e[l - 2]);
          double r = sqrt(g * g + 1.0);
          g = d[mq - 1] - p + e[l - 2] / (g + ((g >= 0.0) ? r : -r));
          double ssn = 1.0, cc = 1.0;
          p = 0.0;
          for (int i = mq; i <= l - 1; ++i) {
            double f = ssn * e[i - 1], b = cc * e[i - 1];
            slartg_dev(g, f, &cc, &ssn, &r);
            if (i != mq) e[i - 2] = r;
            g = d[i - 1] - p;
            r = (d[i] - g) * ssn + 2.0 * cc * b;
            p = ssn * r;
            d[i - 1] = g + p;
            g = cc * r - b;
            wc[i - 1] = cc; wsn[i - 1] = ssn;
          }
          for (int j = mq; j <= l - 1; ++j) {
            double cj = wc[j - 1], sj = wsn[j - 1];
            for (int i = 0; i < 3; ++i) {
              double t = Z[i][j];
              Z[i][j]     = cj * t - sj * Z[i][j - 1];
              Z[i][j - 1] = sj * t + cj * Z[i][j - 1];
            }
          }
          d[l - 1] -= p; e[l - 2] = g;
        }
      }
    }
    // ---- ascending selection sort with column swaps (as in ssteqr)
    for (int ii = 2; ii <= 3; ++ii) {
      int i0 = ii - 1, k = i0;
      double p = d[i0 - 1];
      for (int j = ii; j <= 3; ++j) if (d[j - 1] < p) { k = j; p = d[j - 1]; }
      if (k != i0) {
        d[k - 1] = d[i0 - 1]; d[i0 - 1] = p;
        for (int rr = 0; rr < 3; ++rr) { double t = Z[rr][i0 - 1]; Z[rr][i0 - 1] = Z[rr][k - 1]; Z[rr][k - 1] = t; }
      }
    }
  }
  // ---- sormtr: Z := H1 * Z
  if (tau != 0.0) {
    for (int j = 0; j < 3; ++j) {
      double w = Z[1][j] + v2 * Z[2][j];
      Z[1][j] -= tau * w;
      Z[2][j] -= tau * v2 * w;
    }
  }
  for (int i = 0; i < 3; ++i)
    for (int j = 0; j < 3; ++j)
      V[i][j] = (float)Z[i][2 - j];
}

// ===================== kernel 0: pack pos -> float4 {x,y,z,sq} =====================
__global__ __launch_bounds__(256) void pack_kernel(const float* __restrict__ pos,
                                                   float4* __restrict__ pos4) {
#pragma clang fp contract(off)
  int i = blockIdx.x * 256 + threadIdx.x;
  if (i < NPOINTS) {
    float x = pos[3 * i + 0], y = pos[3 * i + 1], z = pos[3 * i + 2];
    float sq = (x * x + y * y) + z * z;   // XLA reduce order (same as r6)
    pos4[i] = make_float4(x, y, z, sq);
  }
}

// ===================== kernel 1: exact KNN, LDS-tiled, threshold + compact ============
// Order: C = (fkey(d2) << 32) | (0xFFFFFFFF - idx). 32 smallest C == r6-verified
// semantics (key asc, ties -> HIGHER index first). Chain-A d2 unchanged.
// r10 lesson: global-stream loop is L2-LATENCY-bound. Stage 16KB tiles in LDS once
// per block; 16 rows consume each tile (16x less global traffic, pipelined ds_read).
// Phase A threshold tracked as raw float d2 (saves fkey in hot loop; slack-only —
// compaction superset still certified, exact 64-bit extraction unchanged).
#define WPB  4    // waves per block
#define RPW  4    // rows per wave -> 16 rows per block
#define TPTS 1024 // tile points (16 KB)
#define NTIL (NPOINTS / TPTS)
#define CAP  128  // candidate capacity per row (overflow P ~ 0; serial fallback kept)

__global__ __launch_bounds__(256) void knn_kernel(const float4* __restrict__ pos4,
                                                  unsigned* __restrict__ idx_out) {
#pragma clang fp contract(off)
  __shared__ float4 tile[TPTS];            // 16 KB
  __shared__ ull cand[WPB][RPW][CAP];      // 16 KB
  __shared__ ull sel[WPB][RPW][KNN];       // 4 KB
  const int tid  = threadIdx.x;
  const int lane = tid & 63;
  const int wave = tid >> 6;
  const int rowbase = (blockIdx.x * WPB + wave) * RPW;
  const float INF = __int_as_float(0x7f800000);

  float rx[RPW], ry[RPW], rz[RPW], rq[RPW];
#pragma unroll
  for (int r = 0; r < RPW; ++r) {
    const float4 rp = pos4[rowbase + r];
    rx[r] = rp.x; ry[r] = rp.y; rz[r] = rp.z; rq[r] = rp.w;
  }

  // ---- phase A: branchless per-lane top-2 d2 (float), tiles staged in LDS ----
  float k1f[RPW], k2f[RPW];
#pragma unroll
  for (int r = 0; r < RPW; ++r) { k1f[r] = INF; k2f[r] = INF; }
  for (int t = 0; t < NTIL; ++t) {
    __syncthreads();                       // prior tile fully consumed (r2 lesson)
#pragma unroll
    for (int q = 0; q < TPTS / 256; ++q)
      tile[q * 256 + tid] = pos4[t * TPTS + q * 256 + tid];
    __syncthreads();
#pragma unroll 4
    for (int ch = 0; ch < TPTS / 64; ++ch) {
      const float4 p = tile[ch * 64 + lane];
#pragma unroll
      for (int r = 0; r < RPW; ++r) {
        const float mdot = __builtin_fmaf(rz[r], p.z, __builtin_fmaf(ry[r], p.y, rx[r] * p.x));
        const float d2 = (rq[r] + p.w) - 2.0f * mdot;
        const float mx = fmaxf(k1f[r], d2);
        k1f[r] = fminf(k1f[r], d2);
        k2f[r] = fminf(k2f[r], mx);
      }
    }
  }

  // ---- per-row float threshold Tt = 32nd smallest of pool {k1f,k2f} x 64 lanes ----
  // Sub-multiset order-statistic bound: Tt >= true 32nd-smallest d2 -> superset below.
  float Ttf[RPW];
#pragma unroll
  for (int r = 0; r < RPW; ++r) {
    int head = 0;
    float T = 0.f;
    for (int it = 0; it < KNN; ++it) {
      float v = (head == 0) ? k1f[r] : ((head == 1) ? k2f[r] : INF);
      float m = v;
      for (int off = 1; off < 64; off <<= 1) {
        float o = __shfl_xor(m, off, 64);
        m = fminf(m, o);
      }
      ull win = __ballot(v == m);
      int wl = __ffsll((long long)win) - 1;
      if (lane == wl) ++head;
      T = m;
    }
    Ttf[r] = T;
  }

  // ---- phase B: compact candidates with d2 <= Ttf per row (LDS-tiled re-stream) ----
  unsigned cnt[RPW];
#pragma unroll
  for (int r = 0; r < RPW; ++r) cnt[r] = 0;
  for (int t = 0; t < NTIL; ++t) {
    __syncthreads();
#pragma unroll
    for (int q = 0; q < TPTS / 256; ++q)
      tile[q * 256 + tid] = pos4[t * TPTS + q * 256 + tid];
    __syncthreads();
#pragma unroll 2
    for (int ch = 0; ch < TPTS / 64; ++ch) {
      const int j = t * TPTS + ch * 64 + lane;
      const float4 p = tile[ch * 64 + lane];
#pragma unroll
      for (int r = 0; r < RPW; ++r) {
        const float mdot = __builtin_fmaf(rz[r], p.z, __builtin_fmaf(ry[r], p.y, rx[r] * p.x));
        const float d2 = (rq[r] + p.w) - 2.0f * mdot;
        const bool c = (d2 <= Ttf[r]);
        const ull m = __ballot(c);
        if (c) {
          unsigned slot = cnt[r] + (unsigned)__popcll(m & ((1ULL << lane) - 1ULL));
          if (slot < CAP)
            cand[wave][r][slot] = ((ull)fkey(d2) << 32) | (ull)(0xFFFFFFFFu - (unsigned)j);
        }
        cnt[r] += (unsigned)__popcll(m);
      }
    }
  }
  __builtin_amdgcn_s_waitcnt(0);   // drain our ds_writes (wave-private region)

#pragma unroll
  for (int r = 0; r < RPW; ++r) {
    if (cnt[r] <= (unsigned)CAP) {
      // exact wave-parallel extraction of 32 smallest C from <=128 candidates
      ull c0 = (lane < (int)cnt[r]) ? cand[wave][r][lane] : ~0ULL;
      ull c1 = ((lane + 64) < (int)cnt[r]) ? cand[wave][r][lane + 64] : ~0ULL;
      ull lo = (c0 < c1) ? c0 : c1;
      ull hi = (c0 < c1) ? c1 : c0;
      int head = 0;
      for (int it = 0; it < KNN; ++it) {
        ull v = (head == 0) ? lo : ((head == 1) ? hi : ~0ULL);
        ull m = v;
        for (int off = 1; off < 64; off <<= 1) {
          ull o = shflx64(m, off);
          m = (o < m) ? o : m;
        }
        ull win = __ballot(v == m);
        int wl = __ffsll((long long)win) - 1;
        if (lane == wl) ++head;
        if (lane == 0) sel[wave][r][it] = m;
      }
    } else {
      // exact serial fallback (probability ~0)
      if (lane == 0) {
        int n2 = 0;
        for (int j = 0; j < NPOINTS; ++j) {
          const float4 p = pos4[j];
          const float mdot = __builtin_fmaf(rz[r], p.z, __builtin_fmaf(ry[r], p.y, rx[r] * p.x));
          const float d2 = (rq[r] + p.w) - 2.0f * mdot;
          const unsigned key = fkey(d2);
          const ull C = ((ull)key << 32) | (ull)(0xFFFFFFFFu - (unsigned)j);
          if (n2 < KNN) {
            int b = n2 - 1;
            while (b >= 0 && sel[wave][r][b] > C) { sel[wave][r][b + 1] = sel[wave][r][b]; --b; }
            sel[wave][r][b + 1] = C;
            ++n2;
          } else if (C < sel[wave][r][KNN - 1]) {
            int b = KNN - 2;
            while (b >= 0 && sel[wave][r][b] > C) { sel[wave][r][b + 1] = sel[wave][r][b]; --b; }
            sel[wave][r][b + 1] = C;
          }
        }
      }
    }
  }
  __builtin_amdgcn_s_waitcnt(0);

  // finalize (lane 0): decompose, sort by (key asc, idx asc), emit (as r6/r8/r9)
  if (lane == 0) {
#pragma unroll
    for (int r = 0; r < RPW; ++r) {
      unsigned kk[KNN], ii[KNN];
      for (int a = 0; a < KNN; ++a) {
        ull C = sel[wave][r][a];
        kk[a] = (unsigned)(C >> 32);
        ii[a] = 0xFFFFFFFFu - (unsigned)(C & 0xFFFFFFFFULL);
      }
      for (int a = 1; a < KNN; ++a) {
        unsigned ka = kk[a], ia = ii[a];
        int b = a - 1;
        while (b >= 0 && (kk[b] > ka || (kk[b] == ka && ii[b] > ia))) {
          kk[b + 1] = kk[b]; ii[b + 1] = ii[b]; --b;
        }
        kk[b + 1] = ka; ii[b + 1] = ia;
      }
      unsigned ob = (unsigned)(rowbase + r) * KNN;
      for (int a = 0; a < KNN; ++a) idx_out[ob + a] = ii[a];
    }
  }
}

// ===================== kernel 2: mean + cov + eigh per point (fp32) =====================
__global__ __launch_bounds__(256) void pca_kernel(const float* __restrict__ pos,
                                                  const unsigned* __restrict__ idx,
                                                  float* __restrict__ center,
                                                  float* __restrict__ Vmat) {
#pragma clang fp contract(off)
  int n = blockIdx.x * 256 + threadIdx.x;
  if (n >= NPOINTS) return;
  float sx = 0.f, sy = 0.f, sz = 0.f;
  for (int k = 0; k < KNN; ++k) {
    unsigned j = idx[n * KNN + k];
    sx += pos[j * 3 + 0];
    sy += pos[j * 3 + 1];
    sz += pos[j * 3 + 2];
  }
  float cx = sx * 0.03125f, cy = sy * 0.03125f, cz = sz * 0.03125f;
  float c00 = 0.f, c10 = 0.f, c20 = 0.f, c11 = 0.f, c21 = 0.f, c22 = 0.f;
  for (int k = 0; k < KNN; ++k) {
    unsigned j = idx[n * KNN + k];
    float lx = pos[j * 3 + 0] - cx;
    float ly = pos[j * 3 + 1] - cy;
    float lz = pos[j * 3 + 2] - cz;
    c00 += lx * lx; c10 += lx * ly; c20 += lx * lz;
    c11 += ly * ly; c21 += ly * lz; c22 += lz * lz;
  }
  c00 *= 0.03125f; c10 *= 0.03125f; c20 *= 0.03125f;
  c11 *= 0.03125f; c21 *= 0.03125f; c22 *= 0.03125f;
  float V[3][3];
  eigh3(c00, c10, c20, c11, c21, c22, V);
  center[n * 3 + 0] = cx; center[n * 3 + 1] = cy; center[n * 3 + 2] = cz;
  for (int i = 0; i < 3; ++i)
    for (int j2 = 0; j2 < 3; ++j2)
      Vmat[n * 9 + i * 3 + j2] = V[i][j2];
}

// ===================== kernel 3: basis + G[b,i] + 27x (64x64) matmuls =====================
#define NT 8
__global__ __launch_bounds__(256) void conv_kernel(const float* __restrict__ pos,
                                                   const float* __restrict__ chan,
                                                   const float* __restrict__ coeff,
                                                   const unsigned* __restrict__ idx,
                                                   const float* __restrict__ center,
                                                   const float* __restrict__ Vmat,
                                                   float* __restrict__ out) {
#pragma clang fp contract(off)
  __shared__ float G[NT][NBASIS][64];
  __shared__ float Tsh[NT][64];
  const int tid  = threadIdx.x;
  const int lane = tid & 63;
  const int wave = tid >> 6;
  const int n0 = blockIdx.x * NT;

  for (int rep = 0; rep < 2; ++rep) {
    const int nl = wave * 2 + rep;
    const int n = n0 + nl;
    const float cx = center[n * 3 + 0], cy = center[n * 3 + 1], cz = center[n * 3 + 2];
    const float V00 = Vmat[n * 9 + 0], V01 = Vmat[n * 9 + 1], V02 = Vmat[n * 9 + 2];
    const float V10 = Vmat[n * 9 + 3], V11 = Vmat[n * 9 + 4], V12 = Vmat[n * 9 + 5];
    const float V20 = Vmat[n * 9 + 6], V21 = Vmat[n * 9 + 7], V22 = Vmat[n * 9 + 8];
    float g[NBASIS];
#pragma unroll
    for (int b = 0; b < NBASIS; ++b) g[b] = 0.f;
    for (int k = 0; k < KNN; ++k) {
      const unsigned j = idx[n * KNN + k];
      const float lx = pos[j * 3 + 0] - cx;
      const float ly = pos[j * 3 + 1] - cy;
      const float lz = pos[j * 3 + 2] - cz;
      const float X  = lx * V00 + ly * V10 + lz * V20;
      const float Y  = lx * V01 + ly * V11 + lz * V21;
      const float Zc = lx * V02 + ly * V12 + lz * V22;
      const float r = sqrtf(((X * X + Y * Y) + Zc * Zc) + 1e-8f);
      float u = Zc / r;
      u = fminf(fmaxf(u, -0.999999f), 0.999999f);
      const float ct1 = u, ct2 = 2.f * u * u - 1.f;
      const float rho2 = X * X + Y * Y;
      const float cp1 = (rho2 > 0.f) ? (X / sqrtf(rho2)) : 1.f;
      const float cp2 = 2.f * cp1 * cp1 - 1.f;
      const float f = chan[(size_t)j * 64 + lane];
      const float pr1 = r, pr2 = r * r;
      float tc[9];
      tc[0] = 1.f; tc[1] = cp1; tc[2] = cp2;
      tc[3] = ct1; tc[4] = ct1 * cp1; tc[5] = ct1 * cp2;
      tc[6] = ct2; tc[7] = ct2 * cp1; tc[8] = ct2 * cp2;
#pragma unroll
      for (int m9 = 0; m9 < 9; ++m9) {
        g[m9]      = __builtin_fmaf(tc[m9],       f, g[m9]);
        g[9 + m9]  = __builtin_fmaf(pr1 * tc[m9], f, g[9 + m9]);
        g[18 + m9] = __builtin_fmaf(pr2 * tc[m9], f, g[18 + m9]);
      }
    }
#pragma unroll
    for (int b = 0; b < NBASIS; ++b) G[nl][b][lane] = g[b];
  }
  __syncthreads();

  float acc0 = 0.f, acc1 = 0.f;
  for (int b = 0; b < NBASIS; ++b) {
#pragma unroll 8
    for (int i = 0; i < 64; ++i) {
      const float c = coeff[(size_t)(b * 64 + i) * 64 + lane];
      acc0 = __builtin_fmaf(c, G[wave * 2 + 0][b][i], acc0);
      acc1 = __builtin_fmaf(c, G[wave * 2 + 1][b][i], acc1);
    }
  }
  __syncthreads();
  Tsh[wave * 2 + 0][lane] = acc0 * 0.03125f;
  Tsh[wave * 2 + 1][lane] = acc1 * 0.03125f;
  __syncthreads();
#pragma unroll
  for (int s = 0; s < 2; ++s) {
    const int el = tid + s * 256;
    const int o = el >> 3, nn = el & 7;
    out[(size_t)o * NPOINTS + (n0 + nn)] = Tsh[nn][o];
  }
}

// ===================== launch =====================
extern "C" void kernel_launch(void* const* d_in, const int* in_sizes, int n_in,
                              void* d_out, int out_size, void* d_ws, size_t ws_size,
                              hipStream_t stream) {
  (void)in_sizes; (void)n_in; (void)out_size; (void)ws_size;
  const float* pos   = (const float*)d_in[0];
  const float* chan  = (const float*)d_in[1];
  const float* coeff = (const float*)d_in[2];
  float* out = (float*)d_out;
  unsigned char* ws = (unsigned char*)d_ws;
  float4*   pos4   = (float4*)(ws);                                    // 256 KiB
  unsigned* idx    = (unsigned*)(ws + (size_t)NPOINTS * 16);           // 2 MiB
  float*    center = (float*)(ws + (size_t)NPOINTS * 16 + (size_t)NPOINTS * KNN * 4);          // 192 KiB
  float*    Vmat   = (float*)(ws + (size_t)NPOINTS * 16 + (size_t)NPOINTS * KNN * 4
                              + (size_t)NPOINTS * 12);                 // 576 KiB
  hipLaunchKernelGGL(pack_kernel, dim3(NPOINTS / 256),         dim3(256), 0, stream, pos, pos4);
  hipLaunchKernelGGL(knn_kernel,  dim3(NPOINTS / (WPB * RPW)), dim3(256), 0, stream, pos4, idx);
  hipLaunchKernelGGL(pca_kernel,  dim3(NPOINTS / 256),         dim3(256), 0, stream, pos, idx, center, Vmat);
  hipLaunchKernelGGL(conv_kernel, dim3(NPOINTS / NT),          dim3(256), 0, stream, pos, chan, coeff, idx, center, Vmat, out);
}

// Round 12
// 915.897 us; speedup vs baseline: 1.1813x; 1.1300x over previous
//
#include <hip/hip_runtime.h>
#include <math.h>

#define NPOINTS 16384
#define KNN     32
#define NBASIS  27

typedef unsigned long long ull;

// ===================== helpers =====================

__device__ __forceinline__ unsigned fkey(float f) {
  // monotone order-preserving map fp32 -> uint32 (3 VALU: ashr, or, xor)
  unsigned u = __float_as_uint(f);
  unsigned m = (unsigned)((int)u >> 31) | 0x80000000u;
  return u ^ m;
}

__device__ __forceinline__ ull shflx64(ull v, int mask) {
  int lo = __shfl_xor((int)(unsigned)(v & 0xFFFFFFFFULL), mask, 64);
  int hi = __shfl_xor((int)(unsigned)(v >> 32), mask, 64);
  return ((ull)(unsigned)hi << 32) | (ull)(unsigned)lo;
}

// count of set bits in m strictly below this lane (2 VALU)
__device__ __forceinline__ unsigned prefix64(ull m) {
  return __builtin_amdgcn_mbcnt_hi((unsigned)(m >> 32),
         __builtin_amdgcn_mbcnt_lo((unsigned)m, 0u));
}

// ===================== faithful ssyevd(3x3) port (double arith, fp32 eps) ============

__device__ __forceinline__ void slartg_dev(double f, double g, double* c, double* s, double* r) {
#pragma clang fp contract(off)
  // LAPACK >= 3.10 convention (c >= 0)
  if (g == 0.0) { *c = 1.0; *s = 0.0; *r = f; }
  else if (f == 0.0) { *c = 0.0; *s = (g >= 0.0 ? 1.0 : -1.0); *r = fabs(g); }
  else {
    double d = sqrt(f * f + g * g);
    *c = fabs(f) / d;
    *r = (f >= 0.0) ? d : -d;
    *s = g / (*r);
  }
}

__device__ __forceinline__ void slaev2_dev(double a, double b, double c,
                                           double* rt1, double* rt2, double* cs1, double* sn1) {
#pragma clang fp contract(off)
  double sm = a + c, df = a - c, adf = fabs(df), tb = b + b, ab = fabs(tb);
  double acmx, acmn;
  if (fabs(a) > fabs(c)) { acmx = a; acmn = c; } else { acmx = c; acmn = a; }
  double rt;
  if (adf > ab)      rt = adf * sqrt(1.0 + (ab / adf) * (ab / adf));
  else if (adf < ab) rt = ab * sqrt(1.0 + (adf / ab) * (adf / ab));
  else               rt = ab * sqrt(2.0);
  int sgn1;
  if (sm < 0.0) { *rt1 = 0.5 * (sm - rt); sgn1 = -1; *rt2 = (acmx / *rt1) * acmn - (b / *rt1) * b; }
  else if (sm > 0.0) { *rt1 = 0.5 * (sm + rt); sgn1 = 1; *rt2 = (acmx / *rt1) * acmn - (b / *rt1) * b; }
  else { *rt1 = 0.5 * rt; *rt2 = -0.5 * rt; sgn1 = 1; }
  int sgn2; double cs;
  if (df >= 0.0) { cs = df + rt; sgn2 = 1; } else { cs = df - rt; sgn2 = -1; }
  double acs = fabs(cs);
  if (acs > ab) { double ct = -tb / cs; double sn = 1.0 / sqrt(1.0 + ct * ct); *sn1 = sn; *cs1 = ct * sn; }
  else {
    if (ab == 0.0) { *cs1 = 1.0; *sn1 = 0.0; }
    else { double tn = -cs / tb; double c1 = 1.0 / sqrt(1.0 + tn * tn); *cs1 = c1; *sn1 = tn * c1; }
  }
  if (sgn1 == sgn2) { double tn = *cs1; *cs1 = -(*sn1); *sn1 = tn; }
}

// Input: lower triangle of symmetric 3x3 (fp32 cov). Output: V columns in DESCENDING
// eigenvalue order (LAPACK ascending, reversed) = np/jnp eigh + [:, :, ::-1].
__device__ void eigh3(float A00, float A10, float A20, float A11, float A21, float A22,
                      float V[3][3]) {
#pragma clang fp contract(off)
  const double EPS    = 5.9604644775390625e-08;   // fp32 slamch('E')
  const double EPS2   = EPS * EPS;
  const double SAFMIN = 1.1754943508222875e-38;   // fp32 slamch('S')
  double d[3], e[2];
  double tau = 0.0, v2 = 0.0;
  // ---- ssytd2 (uplo='L'), single Householder on [A10; A20]
  {
    double alpha = (double)A10, x = (double)A20;
    double a11 = (double)A11, a21 = (double)A21, a22 = (double)A22;
    double beta;
    if (x == 0.0) { tau = 0.0; v2 = 0.0; beta = alpha; }
    else {
      double nrm = sqrt(alpha * alpha + x * x);          // slapy2
      beta = (alpha >= 0.0) ? -nrm : nrm;                // -sign(nrm, alpha)
      tau = (beta - alpha) / beta;
      v2 = x / (alpha - beta);
    }
    if (tau != 0.0) {
      double w0 = tau * (a11 + a21 * v2);
      double w1 = tau * (a21 + a22 * v2);
      double cc = 0.5 * tau * (w0 + w1 * v2);
      w0 -= cc; w1 -= cc * v2;
      a11 -= 2.0 * w0;
      a21 -= (v2 * w0 + w1);
      a22 -= 2.0 * v2 * w1;
    }
    d[0] = (double)A00; d[1] = a11; d[2] = a22;
    e[0] = beta; e[1] = a21;
  }
  double Z[3][3] = { {1.0, 0.0, 0.0}, {0.0, 1.0, 0.0}, {0.0, 0.0, 1.0} };
  // ---- ssteqr('I', n=3)
  {
    int l1 = 1, jtot = 0;
    const int nmaxit = 90;
    double wc[2], wsn[2];
    while (l1 <= 3) {
      if (l1 > 1) e[l1 - 2] = 0.0;
      int m = 3;
      for (int mm = l1; mm <= 2; ++mm) {
        double tst = fabs(e[mm - 1]);
        if (tst == 0.0) { m = mm; break; }
        if (tst <= (sqrt(fabs(d[mm - 1])) * sqrt(fabs(d[mm]))) * EPS) { e[mm - 1] = 0.0; m = mm; break; }
      }
      int l = l1, lsv = l, lend = m, lendsv = lend;
      l1 = m + 1;
      if (lend == l) continue;
      double anorm = 0.0;
      for (int i = l; i <= lend; ++i)     anorm = fmax(anorm, fabs(d[i - 1]));
      for (int i = l; i <= lend - 1; ++i) anorm = fmax(anorm, fabs(e[i - 1]));
      if (anorm == 0.0) continue;
      if (fabs(d[lend - 1]) < fabs(d[l - 1])) { lend = lsv; l = lendsv; }
      if (lend > l) {
        // ===== QL =====
        bool done = false;
        while (!done) {
          int mq = lend;
          for (int mm = l; mm <= lend - 1; ++mm) {
            double tst = e[mm - 1] * e[mm - 1];
            if (tst <= (EPS2 * fabs(d[mm - 1])) * fabs(d[mm]) + SAFMIN) { mq = mm; break; }
          }
          if (mq < lend) e[mq - 1] = 0.0;
          double p = d[l - 1];
          if (mq == l) { d[l - 1] = p; ++l; if (l > lend) done = true; continue; }
          if (mq == l + 1) {
            double rt1, rt2, cc, ssn;
            slaev2_dev(d[l - 1], e[l - 1], d[l], &rt1, &rt2, &cc, &ssn);
            for (int i = 0; i < 3; ++i) {
              double t = Z[i][l];
              Z[i][l]     = cc * t - ssn * Z[i][l - 1];
              Z[i][l - 1] = ssn * t + cc * Z[i][l - 1];
            }
            d[l - 1] = rt1; d[l] = rt2; e[l - 1] = 0.0;
            l += 2; if (l > lend) done = true; continue;
          }
          if (jtot >= nmaxit) break;
          ++jtot;
          double g = (d[l] - p) / (2.0 * e[l - 1]);
          double r = sqrt(g * g + 1.0);
          g = d[mq - 1] - p + e[l - 1] / (g + ((g >= 0.0) ? r : -r));
          double ssn = 1.0, cc = 1.0;
          p = 0.0;
          for (int i = mq - 1; i >= l; --i) {
            double f = ssn * e[i - 1], b = cc * e[i - 1];
            slartg_dev(g, f, &cc, &ssn, &r);
            if (i != mq - 1) e[i] = r;
            g = d[i] - p;
            r = (d[i - 1] - g) * ssn + 2.0 * cc * b;
            p = ssn * r;
            d[i] = g + p;
            g = cc * r - b;
            wc[i - 1] = cc; wsn[i - 1] = -ssn;
          }
          for (int j = mq - 1; j >= l; --j) {
            double cj = wc[j - 1], sj = wsn[j - 1];
            for (int i = 0; i < 3; ++i) {
              double t = Z[i][j];
              Z[i][j]     = cj * t - sj * Z[i][j - 1];
              Z[i][j - 1] = sj * t + cj * Z[i][j - 1];
            }
          }
          d[l - 1] -= p; e[l - 1] = g;
        }
      } else {
        // ===== QR =====
        bool done = false;
        while (!done) {
          int mq = lend;
          for (int mm = l; mm >= lend + 1; --mm) {
            double tst = e[mm - 2] * e[mm - 2];
            if (tst <= (EPS2 * fabs(d[mm - 1])) * fabs(d[mm - 2]) + SAFMIN) { mq = mm; break; }
          }
          if (mq > lend) e[mq - 2] = 0.0;
          double p = d[l - 1];
          if (mq == l) { d[l - 1] = p; --l; if (l < lend) done = true; continue; }
          if (mq == l - 1) {
            double rt1, rt2, cc, ssn;
            slaev2_dev(d[l - 2], e[l - 2], d[l - 1], &rt1, &rt2, &cc, &ssn);
            for (int i = 0; i < 3; ++i) {
              double t = Z[i][l - 1];
              Z[i][l - 1] = cc * t - ssn * Z[i][l - 2];
              Z[i][l - 2] = ssn * t + cc * Z[i][l - 2];
            }
            d[l - 2] = rt1; d[l - 1] = rt2; e[l - 2] = 0.0;
            l -= 2; if (l < lend) done = true; continue;
          }
          if (jtot >= nmaxit) break;
          ++jtot;
          double g = (d[l - 2] - p) / (2.0 * e[l - 2]);
          double r = sqrt(g * g + 1.0);
          g = d[mq - 1] - p + e[l - 2] / (g + ((g >= 0.0) ? r : -r));
          double ssn = 1.0, cc = 1.0;
          p = 0.0;
          for (int i = mq; i <= l - 1; ++i) {
            double f = ssn * e[i - 1], b = cc * e[i - 1];
            slartg_dev(g, f, &cc, &ssn, &r);
            if (i != mq) e[i - 2] = r;
            g = d[i - 1] - p;
            r = (d[i] - g) * ssn + 2.0 * cc * b;
            p = ssn * r;
            d[i - 1] = g + p;
            g = cc * r - b;
            wc[i - 1] = cc; wsn[i - 1] = ssn;
          }
          for (int j = mq; j <= l - 1; ++j) {
            double cj = wc[j - 1], sj = wsn[j - 1];
            for (int i = 0; i < 3; ++i) {
              double t = Z[i][j];
              Z[i][j]     = cj * t - sj * Z[i][j - 1];
              Z[i][j - 1] = sj * t + cj * Z[i][j - 1];
            }
          }
          d[l - 1] -= p; e[l - 2] = g;
        }
      }
    }
    // ---- ascending selection sort with column swaps (as in ssteqr)
    for (int ii = 2; ii <= 3; ++ii) {
      int i0 = ii - 1, k = i0;
      double p = d[i0 - 1];
      for (int j = ii; j <= 3; ++j) if (d[j - 1] < p) { k = j; p = d[j - 1]; }
      if (k != i0) {
        d[k - 1] = d[i0 - 1]; d[i0 - 1] = p;
        for (int rr = 0; rr < 3; ++rr) { double t = Z[rr][i0 - 1]; Z[rr][i0 - 1] = Z[rr][k - 1]; Z[rr][k - 1] = t; }
      }
    }
  }
  // ---- sormtr: Z := H1 * Z
  if (tau != 0.0) {
    for (int j = 0; j < 3; ++j) {
      double w = Z[1][j] + v2 * Z[2][j];
      Z[1][j] -= tau * w;
      Z[2][j] -= tau * v2 * w;
    }
  }
  for (int i = 0; i < 3; ++i)
    for (int j = 0; j < 3; ++j)
      V[i][j] = (float)Z[i][2 - j];
}

// ===================== kernel 0: pack pos -> float4 {x,y,z,sq} =====================
__global__ __launch_bounds__(256) void pack_kernel(const float* __restrict__ pos,
                                                   float4* __restrict__ pos4) {
#pragma clang fp contract(off)
  int i = blockIdx.x * 256 + threadIdx.x;
  if (i < NPOINTS) {
    float x = pos[3 * i + 0], y = pos[3 * i + 1], z = pos[3 * i + 2];
    float sq = (x * x + y * y) + z * z;   // XLA reduce order (same as r6)
    pos4[i] = make_float4(x, y, z, sq);
  }
}

// ===================== kernel 1: exact KNN, LDS-tiled, k1-threshold + compact =========
// Order: C = (fkey(d2) << 32) | (0xFFFFFFFF - idx). 32 smallest C == r6-verified
// semantics (key asc, ties -> HIGHER index first). Chain-A d2 unchanged.
// r12 instruction diet: (1) phase A keeps only per-lane MIN d2 (1 v_min/pair-row);
//     threshold = 32nd smallest of 64 lane-minima. Certified: <=31 global values are
//     strictly < T32, each in one lane => <=31 lane-minima < T32 => Tt >= T32.
// (2) mbcnt for compaction prefix. (3) finalize emits from C-order directly,
//     reversing only bit-equal-key runs (idx desc -> asc). Selection set identical.
#define WPB  4    // waves per block
#define RPW  4    // rows per wave -> 16 rows per block
#define TPTS 1024 // tile points (16 KB)
#define NTIL (NPOINTS / TPTS)
#define CAP  128  // candidate capacity per row (E[cnt]~44; serial fallback kept)

__global__ __launch_bounds__(256) void knn_kernel(const float4* __restrict__ pos4,
                                                  unsigned* __restrict__ idx_out) {
#pragma clang fp contract(off)
  __shared__ float4 tile[TPTS];            // 16 KB
  __shared__ ull cand[WPB][RPW][CAP];      // 16 KB
  __shared__ ull sel[WPB][RPW][KNN];       // 4 KB
  const int tid  = threadIdx.x;
  const int lane = tid & 63;
  const int wave = tid >> 6;
  const int rowbase = (blockIdx.x * WPB + wave) * RPW;
  const float INF = __int_as_float(0x7f800000);

  float rx[RPW], ry[RPW], rz[RPW], rq[RPW];
#pragma unroll
  for (int r = 0; r < RPW; ++r) {
    const float4 rp = pos4[rowbase + r];
    rx[r] = rp.x; ry[r] = rp.y; rz[r] = rp.z; rq[r] = rp.w;
  }

  // ---- phase A: per-lane MIN d2 only (1 v_min per pair-row) ----
  float k1f[RPW];
#pragma unroll
  for (int r = 0; r < RPW; ++r) k1f[r] = INF;
  for (int t = 0; t < NTIL; ++t) {
    __syncthreads();                       // prior tile fully consumed (r2 lesson)
#pragma unroll
    for (int q = 0; q < TPTS / 256; ++q)
      tile[q * 256 + tid] = pos4[t * TPTS + q * 256 + tid];
    __syncthreads();
#pragma unroll 4
    for (int ch = 0; ch < TPTS / 64; ++ch) {
      const float4 p = tile[ch * 64 + lane];
#pragma unroll
      for (int r = 0; r < RPW; ++r) {
        const float mdot = __builtin_fmaf(rz[r], p.z, __builtin_fmaf(ry[r], p.y, rx[r] * p.x));
        const float d2 = (rq[r] + p.w) - 2.0f * mdot;
        k1f[r] = fminf(k1f[r], d2);
      }
    }
  }

  // ---- per-row float threshold Tt = 32nd smallest of the 64 lane minima ----
  float Ttf[RPW];
#pragma unroll
  for (int r = 0; r < RPW; ++r) {
    int head = 0;
    float T = 0.f;
    for (int it = 0; it < KNN; ++it) {
      float v = (head == 0) ? k1f[r] : INF;
      float m = v;
      for (int off = 1; off < 64; off <<= 1) {
        float o = __shfl_xor(m, off, 64);
        m = fminf(m, o);
      }
      ull win = __ballot(v == m);
      int wl = __ffsll((long long)win) - 1;
      if (lane == wl) ++head;
      T = m;
    }
    Ttf[r] = T;
  }

  // ---- phase B: compact candidates with d2 <= Ttf per row (LDS-tiled re-stream) ----
  unsigned cnt[RPW];
#pragma unroll
  for (int r = 0; r < RPW; ++r) cnt[r] = 0;
  for (int t = 0; t < NTIL; ++t) {
    __syncthreads();
#pragma unroll
    for (int q = 0; q < TPTS / 256; ++q)
      tile[q * 256 + tid] = pos4[t * TPTS + q * 256 + tid];
    __syncthreads();
#pragma unroll 2
    for (int ch = 0; ch < TPTS / 64; ++ch) {
      const int j = t * TPTS + ch * 64 + lane;
      const float4 p = tile[ch * 64 + lane];
#pragma unroll
      for (int r = 0; r < RPW; ++r) {
        const float mdot = __builtin_fmaf(rz[r], p.z, __builtin_fmaf(ry[r], p.y, rx[r] * p.x));
        const float d2 = (rq[r] + p.w) - 2.0f * mdot;
        const bool c = (d2 <= Ttf[r]);
        const ull m = __ballot(c);
        if (c) {
          unsigned slot = cnt[r] + prefix64(m);
          if (slot < CAP)
            cand[wave][r][slot] = ((ull)fkey(d2) << 32) | (ull)(0xFFFFFFFFu - (unsigned)j);
        }
        cnt[r] += (unsigned)__popcll(m);
      }
    }
  }
  __builtin_amdgcn_s_waitcnt(0);   // drain our ds_writes (wave-private region)

#pragma unroll
  for (int r = 0; r < RPW; ++r) {
    if (cnt[r] <= (unsigned)CAP) {
      // exact wave-parallel extraction of 32 smallest C from <=128 candidates
      ull c0 = (lane < (int)cnt[r]) ? cand[wave][r][lane] : ~0ULL;
      ull c1 = ((lane + 64) < (int)cnt[r]) ? cand[wave][r][lane + 64] : ~0ULL;
      ull lo = (c0 < c1) ? c0 : c1;
      ull hi = (c0 < c1) ? c1 : c0;
      int head = 0;
      for (int it = 0; it < KNN; ++it) {
        ull v = (head == 0) ? lo : ((head == 1) ? hi : ~0ULL);
        ull m = v;
        for (int off = 1; off < 64; off <<= 1) {
          ull o = shflx64(m, off);
          m = (o < m) ? o : m;
        }
        ull win = __ballot(v == m);
        int wl = __ffsll((long long)win) - 1;
        if (lane == wl) ++head;
        if (lane == 0) sel[wave][r][it] = m;
      }
    } else {
      // exact serial fallback (probability ~0)
      if (lane == 0) {
        int n2 = 0;
        for (int j = 0; j < NPOINTS; ++j) {
          const float4 p = pos4[j];
          const float mdot = __builtin_fmaf(rz[r], p.z, __builtin_fmaf(ry[r], p.y, rx[r] * p.x));
          const float d2 = (rq[r] + p.w) - 2.0f * mdot;
          const unsigned key = fkey(d2);
          const ull C = ((ull)key << 32) | (ull)(0xFFFFFFFFu - (unsigned)j);
          if (n2 < KNN) {
            int b = n2 - 1;
            while (b >= 0 && sel[wave][r][b] > C) { sel[wave][r][b + 1] = sel[wave][r][b]; --b; }
            sel[wave][r][b + 1] = C;
            ++n2;
          } else if (C < sel[wave][r][KNN - 1]) {
            int b = KNN - 2;
            while (b >= 0 && sel[wave][r][b] > C) { sel[wave][r][b + 1] = sel[wave][r][b]; --b; }
            sel[wave][r][b + 1] = C;
          }
        }
      }
    }
  }
  __builtin_amdgcn_s_waitcnt(0);

  // finalize (lane 0): C-ascending == (key asc, idx desc). Emission wants
  // (key asc, idx asc): reverse idx within bit-equal-key runs only (rare).
  if (lane == 0) {
#pragma unroll
    for (int r = 0; r < RPW; ++r) {
      unsigned kk[KNN], ii[KNN];
      for (int a = 0; a < KNN; ++a) {
        ull C = sel[wave][r][a];
        kk[a] = (unsigned)(C >> 32);
        ii[a] = 0xFFFFFFFFu - (unsigned)(C & 0xFFFFFFFFULL);
      }
      int a = 0;
      while (a < KNN) {
        int b = a;
        while (b + 1 < KNN && kk[b + 1] == kk[a]) ++b;
        for (int x = a, y = b; x < y; ++x, --y) { unsigned tmp = ii[x]; ii[x] = ii[y]; ii[y] = tmp; }
        a = b + 1;
      }
      unsigned ob = (unsigned)(rowbase + r) * KNN;
      for (int q = 0; q < KNN; ++q) idx_out[ob + q] = ii[q];
    }
  }
}

// ===================== kernel 2: mean + cov + eigh per point (fp32) =====================
__global__ __launch_bounds__(256) void pca_kernel(const float* __restrict__ pos,
                                                  const unsigned* __restrict__ idx,
                                                  float* __restrict__ center,
                                                  float* __restrict__ Vmat) {
#pragma clang fp contract(off)
  int n = blockIdx.x * 256 + threadIdx.x;
  if (n >= NPOINTS) return;
  float sx = 0.f, sy = 0.f, sz = 0.f;
  for (int k = 0; k < KNN; ++k) {
    unsigned j = idx[n * KNN + k];
    sx += pos[j * 3 + 0];
    sy += pos[j * 3 + 1];
    sz += pos[j * 3 + 2];
  }
  float cx = sx * 0.03125f, cy = sy * 0.03125f, cz = sz * 0.03125f;
  float c00 = 0.f, c10 = 0.f, c20 = 0.f, c11 = 0.f, c21 = 0.f, c22 = 0.f;
  for (int k = 0; k < KNN; ++k) {
    unsigned j = idx[n * KNN + k];
    float lx = pos[j * 3 + 0] - cx;
    float ly = pos[j * 3 + 1] - cy;
    float lz = pos[j * 3 + 2] - cz;
    c00 += lx * lx; c10 += lx * ly; c20 += lx * lz;
    c11 += ly * ly; c21 += ly * lz; c22 += lz * lz;
  }
  c00 *= 0.03125f; c10 *= 0.03125f; c20 *= 0.03125f;
  c11 *= 0.03125f; c21 *= 0.03125f; c22 *= 0.03125f;
  float V[3][3];
  eigh3(c00, c10, c20, c11, c21, c22, V);
  center[n * 3 + 0] = cx; center[n * 3 + 1] = cy; center[n * 3 + 2] = cz;
  for (int i = 0; i < 3; ++i)
    for (int j2 = 0; j2 < 3; ++j2)
      Vmat[n * 9 + i * 3 + j2] = V[i][j2];
}

// ===================== kernel 3: basis + G[b,i] + 27x (64x64) matmuls =====================
#define NT 8
__global__ __launch_bounds__(256) void conv_kernel(const float* __restrict__ pos,
                                                   const float* __restrict__ chan,
                                                   const float* __restrict__ coeff,
                                                   const unsigned* __restrict__ idx,
                                                   const float* __restrict__ center,
                                                   const float* __restrict__ Vmat,
                                                   float* __restrict__ out) {
#pragma clang fp contract(off)
  __shared__ float G[NT][NBASIS][64];
  __shared__ float Tsh[NT][64];
  const int tid  = threadIdx.x;
  const int lane = tid & 63;
  const int wave = tid >> 6;
  const int n0 = blockIdx.x * NT;

  for (int rep = 0; rep < 2; ++rep) {
    const int nl = wave * 2 + rep;
    const int n = n0 + nl;
    const float cx = center[n * 3 + 0], cy = center[n * 3 + 1], cz = center[n * 3 + 2];
    const float V00 = Vmat[n * 9 + 0], V01 = Vmat[n * 9 + 1], V02 = Vmat[n * 9 + 2];
    const float V10 = Vmat[n * 9 + 3], V11 = Vmat[n * 9 + 4], V12 = Vmat[n * 9 + 5];
    const float V20 = Vmat[n * 9 + 6], V21 = Vmat[n * 9 + 7], V22 = Vmat[n * 9 + 8];
    float g[NBASIS];
#pragma unroll
    for (int b = 0; b < NBASIS; ++b) g[b] = 0.f;
    for (int k = 0; k < KNN; ++k) {
      const unsigned j = idx[n * KNN + k];
      const float lx = pos[j * 3 + 0] - cx;
      const float ly = pos[j * 3 + 1] - cy;
      const float lz = pos[j * 3 + 2] - cz;
      const float X  = lx * V00 + ly * V10 + lz * V20;
      const float Y  = lx * V01 + ly * V11 + lz * V21;
      const float Zc = lx * V02 + ly * V12 + lz * V22;
      const float r = sqrtf(((X * X + Y * Y) + Zc * Zc) + 1e-8f);
      float u = Zc / r;
      u = fminf(fmaxf(u, -0.999999f), 0.999999f);
      const float ct1 = u, ct2 = 2.f * u * u - 1.f;
      const float rho2 = X * X + Y * Y;
      const float cp1 = (rho2 > 0.f) ? (X / sqrtf(rho2)) : 1.f;
      const float cp2 = 2.f * cp1 * cp1 - 1.f;
      const float f = chan[(size_t)j * 64 + lane];
      const float pr1 = r, pr2 = r * r;
      float tc[9];
      tc[0] = 1.f; tc[1] = cp1; tc[2] = cp2;
      tc[3] = ct1; tc[4] = ct1 * cp1; tc[5] = ct1 * cp2;
      tc[6] = ct2; tc[7] = ct2 * cp1; tc[8] = ct2 * cp2;
#pragma unroll
      for (int m9 = 0; m9 < 9; ++m9) {
        g[m9]      = __builtin_fmaf(tc[m9],       f, g[m9]);
        g[9 + m9]  = __builtin_fmaf(pr1 * tc[m9], f, g[9 + m9]);
        g[18 + m9] = __builtin_fmaf(pr2 * tc[m9], f, g[18 + m9]);
      }
    }
#pragma unroll
    for (int b = 0; b < NBASIS; ++b) G[nl][b][lane] = g[b];
  }
  __syncthreads();

  float acc0 = 0.f, acc1 = 0.f;
  for (int b = 0; b < NBASIS; ++b) {
#pragma unroll 8
    for (int i = 0; i < 64; ++i) {
      const float c = coeff[(size_t)(b * 64 + i) * 64 + lane];
      acc0 = __builtin_fmaf(c, G[wave * 2 + 0][b][i], acc0);
      acc1 = __builtin_fmaf(c, G[wave * 2 + 1][b][i], acc1);
    }
  }
  __syncthreads();
  Tsh[wave * 2 + 0][lane] = acc0 * 0.03125f;
  Tsh[wave * 2 + 1][lane] = acc1 * 0.03125f;
  __syncthreads();
#pragma unroll
  for (int s = 0; s < 2; ++s) {
    const int el = tid + s * 256;
    const int o = el >> 3, nn = el & 7;
    out[(size_t)o * NPOINTS + (n0 + nn)] = Tsh[nn][o];
  }
}

// ===================== launch =====================
extern "C" void kernel_launch(void* const* d_in, const int* in_sizes, int n_in,
                              void* d_out, int out_size, void* d_ws, size_t ws_size,
                              hipStream_t stream) {
  (void)in_sizes; (void)n_in; (void)out_size; (void)ws_size;
  const float* pos   = (const float*)d_in[0];
  const float* chan  = (const float*)d_in[1];
  const float* coeff = (const float*)d_in[2];
  float* out = (float*)d_out;
  unsigned char* ws = (unsigned char*)d_ws;
  float4*   pos4   = (float4*)(ws);                                    // 256 KiB
  unsigned* idx    = (unsigned*)(ws + (size_t)NPOINTS * 16);           // 2 MiB
  float*    center = (float*)(ws + (size_t)NPOINTS * 16 + (size_t)NPOINTS * KNN * 4);          // 192 KiB
  float*    Vmat   = (float*)(ws + (size_t)NPOINTS * 16 + (size_t)NPOINTS * KNN * 4
                              + (size_t)NPOINTS * 12);                 // 576 KiB
  hipLaunchKernelGGL(pack_kernel, dim3(NPOINTS / 256),         dim3(256), 0, stream, pos, pos4);
  hipLaunchKernelGGL(knn_kernel,  dim3(NPOINTS / (WPB * RPW)), dim3(256), 0, stream, pos4, idx);
  hipLaunchKernelGGL(pca_kernel,  dim3(NPOINTS / 256),         dim3(256), 0, stream, pos, idx, center, Vmat);
  hipLaunchKernelGGL(conv_kernel, dim3(NPOINTS / NT),          dim3(256), 0, stream, pos, chan, coeff, idx, center, Vmat, out);
}

// Round 13
// 871.827 us; speedup vs baseline: 1.2410x; 1.0505x over previous
//
#include <hip/hip_runtime.h>
#include <math.h>

#define NPOINTS 16384
#define KNN     32
#define NBASIS  27

typedef unsigned long long ull;

// ===================== helpers =====================

__device__ __forceinline__ unsigned fkey(float f) {
  // monotone order-preserving map fp32 -> uint32 (3 VALU: ashr, or, xor)
  unsigned u = __float_as_uint(f);
  unsigned m = (unsigned)((int)u >> 31) | 0x80000000u;
  return u ^ m;
}

__device__ __forceinline__ ull shflx64(ull v, int mask) {
  int lo = __shfl_xor((int)(unsigned)(v & 0xFFFFFFFFULL), mask, 64);
  int hi = __shfl_xor((int)(unsigned)(v >> 32), mask, 64);
  return ((ull)(unsigned)hi << 32) | (ull)(unsigned)lo;
}

// count of set bits in m strictly below this lane (2 VALU)
__device__ __forceinline__ unsigned prefix64(ull m) {
  return __builtin_amdgcn_mbcnt_hi((unsigned)(m >> 32),
         __builtin_amdgcn_mbcnt_lo((unsigned)m, 0u));
}

// ===================== faithful ssyevd(3x3) port (double arith, fp32 eps) ============

__device__ __forceinline__ void slartg_dev(double f, double g, double* c, double* s, double* r) {
#pragma clang fp contract(off)
  // LAPACK >= 3.10 convention (c >= 0)
  if (g == 0.0) { *c = 1.0; *s = 0.0; *r = f; }
  else if (f == 0.0) { *c = 0.0; *s = (g >= 0.0 ? 1.0 : -1.0); *r = fabs(g); }
  else {
    double d = sqrt(f * f + g * g);
    *c = fabs(f) / d;
    *r = (f >= 0.0) ? d : -d;
    *s = g / (*r);
  }
}

__device__ __forceinline__ void slaev2_dev(double a, double b, double c,
                                           double* rt1, double* rt2, double* cs1, double* sn1) {
#pragma clang fp contract(off)
  double sm = a + c, df = a - c, adf = fabs(df), tb = b + b, ab = fabs(tb);
  double acmx, acmn;
  if (fabs(a) > fabs(c)) { acmx = a; acmn = c; } else { acmx = c; acmn = a; }
  double rt;
  if (adf > ab)      rt = adf * sqrt(1.0 + (ab / adf) * (ab / adf));
  else if (adf < ab) rt = ab * sqrt(1.0 + (adf / ab) * (adf / ab));
  else               rt = ab * sqrt(2.0);
  int sgn1;
  if (sm < 0.0) { *rt1 = 0.5 * (sm - rt); sgn1 = -1; *rt2 = (acmx / *rt1) * acmn - (b / *rt1) * b; }
  else if (sm > 0.0) { *rt1 = 0.5 * (sm + rt); sgn1 = 1; *rt2 = (acmx / *rt1) * acmn - (b / *rt1) * b; }
  else { *rt1 = 0.5 * rt; *rt2 = -0.5 * rt; sgn1 = 1; }
  int sgn2; double cs;
  if (df >= 0.0) { cs = df + rt; sgn2 = 1; } else { cs = df - rt; sgn2 = -1; }
  double acs = fabs(cs);
  if (acs > ab) { double ct = -tb / cs; double sn = 1.0 / sqrt(1.0 + ct * ct); *sn1 = sn; *cs1 = ct * sn; }
  else {
    if (ab == 0.0) { *cs1 = 1.0; *sn1 = 0.0; }
    else { double tn = -cs / tb; double c1 = 1.0 / sqrt(1.0 + tn * tn); *cs1 = c1; *sn1 = tn * c1; }
  }
  if (sgn1 == sgn2) { double tn = *cs1; *cs1 = -(*sn1); *sn1 = tn; }
}

// Input: lower triangle of symmetric 3x3 (fp32 cov). Output: V columns in DESCENDING
// eigenvalue order (LAPACK ascending, reversed) = np/jnp eigh + [:, :, ::-1].
__device__ void eigh3(float A00, float A10, float A20, float A11, float A21, float A22,
                      float V[3][3]) {
#pragma clang fp contract(off)
  const double EPS    = 5.9604644775390625e-08;   // fp32 slamch('E')
  const double EPS2   = EPS * EPS;
  const double SAFMIN = 1.1754943508222875e-38;   // fp32 slamch('S')
  double d[3], e[2];
  double tau = 0.0, v2 = 0.0;
  // ---- ssytd2 (uplo='L'), single Householder on [A10; A20]
  {
    double alpha = (double)A10, x = (double)A20;
    double a11 = (double)A11, a21 = (double)A21, a22 = (double)A22;
    double beta;
    if (x == 0.0) { tau = 0.0; v2 = 0.0; beta = alpha; }
    else {
      double nrm = sqrt(alpha * alpha + x * x);          // slapy2
      beta = (alpha >= 0.0) ? -nrm : nrm;                // -sign(nrm, alpha)
      tau = (beta - alpha) / beta;
      v2 = x / (alpha - beta);
    }
    if (tau != 0.0) {
      double w0 = tau * (a11 + a21 * v2);
      double w1 = tau * (a21 + a22 * v2);
      double cc = 0.5 * tau * (w0 + w1 * v2);
      w0 -= cc; w1 -= cc * v2;
      a11 -= 2.0 * w0;
      a21 -= (v2 * w0 + w1);
      a22 -= 2.0 * v2 * w1;
    }
    d[0] = (double)A00; d[1] = a11; d[2] = a22;
    e[0] = beta; e[1] = a21;
  }
  double Z[3][3] = { {1.0, 0.0, 0.0}, {0.0, 1.0, 0.0}, {0.0, 0.0, 1.0} };
  // ---- ssteqr('I', n=3)
  {
    int l1 = 1, jtot = 0;
    const int nmaxit = 90;
    double wc[2], wsn[2];
    while (l1 <= 3) {
      if (l1 > 1) e[l1 - 2] = 0.0;
      int m = 3;
      for (int mm = l1; mm <= 2; ++mm) {
        double tst = fabs(e[mm - 1]);
        if (tst == 0.0) { m = mm; break; }
        if (tst <= (sqrt(fabs(d[mm - 1])) * sqrt(fabs(d[mm]))) * EPS) { e[mm - 1] = 0.0; m = mm; break; }
      }
      int l = l1, lsv = l, lend = m, lendsv = lend;
      l1 = m + 1;
      if (lend == l) continue;
      double anorm = 0.0;
      for (int i = l; i <= lend; ++i)     anorm = fmax(anorm, fabs(d[i - 1]));
      for (int i = l; i <= lend - 1; ++i) anorm = fmax(anorm, fabs(e[i - 1]));
      if (anorm == 0.0) continue;
      if (fabs(d[lend - 1]) < fabs(d[l - 1])) { lend = lsv; l = lendsv; }
      if (lend > l) {
        // ===== QL =====
        bool done = false;
        while (!done) {
          int mq = lend;
          for (int mm = l; mm <= lend - 1; ++mm) {
            double tst = e[mm - 1] * e[mm - 1];
            if (tst <= (EPS2 * fabs(d[mm - 1])) * fabs(d[mm]) + SAFMIN) { mq = mm; break; }
          }
          if (mq < lend) e[mq - 1] = 0.0;
          double p = d[l - 1];
          if (mq == l) { d[l - 1] = p; ++l; if (l > lend) done = true; continue; }
          if (mq == l + 1) {
            double rt1, rt2, cc, ssn;
            slaev2_dev(d[l - 1], e[l - 1], d[l], &rt1, &rt2, &cc, &ssn);
            for (int i = 0; i < 3; ++i) {
              double t = Z[i][l];
              Z[i][l]     = cc * t - ssn * Z[i][l - 1];
              Z[i][l - 1] = ssn * t + cc * Z[i][l - 1];
            }
            d[l - 1] = rt1; d[l] = rt2; e[l - 1] = 0.0;
            l += 2; if (l > lend) done = true; continue;
          }
          if (jtot >= nmaxit) break;
          ++jtot;
          double g = (d[l] - p) / (2.0 * e[l - 1]);
          double r = sqrt(g * g + 1.0);
          g = d[mq - 1] - p + e[l - 1] / (g + ((g >= 0.0) ? r : -r));
          double ssn = 1.0, cc = 1.0;
          p = 0.0;
          for (int i = mq - 1; i >= l; --i) {
            double f = ssn * e[i - 1], b = cc * e[i - 1];
            slartg_dev(g, f, &cc, &ssn, &r);
            if (i != mq - 1) e[i] = r;
            g = d[i] - p;
            r = (d[i - 1] - g) * ssn + 2.0 * cc * b;
            p = ssn * r;
            d[i] = g + p;
            g = cc * r - b;
            wc[i - 1] = cc; wsn[i - 1] = -ssn;
          }
          for (int j = mq - 1; j >= l; --j) {
            double cj = wc[j - 1], sj = wsn[j - 1];
            for (int i = 0; i < 3; ++i) {
              double t = Z[i][j];
              Z[i][j]     = cj * t - sj * Z[i][j - 1];
              Z[i][j - 1] = sj * t + cj * Z[i][j - 1];
            }
          }
          d[l - 1] -= p; e[l - 1] = g;
        }
      } else {
        // ===== QR =====
        bool done = false;
        while (!done) {
          int mq = lend;
          for (int mm = l; mm >= lend + 1; --mm) {
            double tst = e[mm - 2] * e[mm - 2];
            if (tst <= (EPS2 * fabs(d[mm - 1])) * fabs(d[mm - 2]) + SAFMIN) { mq = mm; break; }
          }
          if (mq > lend) e[mq - 2] = 0.0;
          double p = d[l - 1];
          if (mq == l) { d[l - 1] = p; --l; if (l < lend) done = true; continue; }
          if (mq == l - 1) {
            double rt1, rt2, cc, ssn;
            slaev2_dev(d[l - 2], e[l - 2], d[l - 1], &rt1, &rt2, &cc, &ssn);
            for (int i = 0; i < 3; ++i) {
              double t = Z[i][l - 1];
              Z[i][l - 1] = cc * t - ssn * Z[i][l - 2];
              Z[i][l - 2] = ssn * t + cc * Z[i][l - 2];
            }
            d[l - 2] = rt1; d[l - 1] = rt2; e[l - 2] = 0.0;
            l -= 2; if (l < lend) done = true; continue;
          }
          if (jtot >= nmaxit) break;
          ++jtot;
          double g = (d[l - 2] - p) / (2.0 * e[l - 2]);
          double r = sqrt(g * g + 1.0);
          g = d[mq - 1] - p + e[l - 2] / (g + ((g >= 0.0) ? r : -r));
          double ssn = 1.0, cc = 1.0;
          p = 0.0;
          for (int i = mq; i <= l - 1; ++i) {
            double f = ssn * e[i - 1], b = cc * e[i - 1];
            slartg_dev(g, f, &cc, &ssn, &r);
            if (i != mq) e[i - 2] = r;
            g = d[i - 1] - p;
            r = (d[i] - g) * ssn + 2.0 * cc * b;
            p = ssn * r;
            d[i - 1] = g + p;
            g = cc * r - b;
            wc[i - 1] = cc; wsn[i - 1] = ssn;
          }
          for (int j = mq; j <= l - 1; ++j) {
            double cj = wc[j - 1], sj = wsn[j - 1];
            for (int i = 0; i < 3; ++i) {
              double t = Z[i][j];
              Z[i][j]     = cj * t - sj * Z[i][j - 1];
              Z[i][j - 1] = sj * t + cj * Z[i][j - 1];
            }
          }
          d[l - 1] -= p; e[l - 2] = g;
        }
      }
    }
    // ---- ascending selection sort with column swaps (as in ssteqr)
    for (int ii = 2; ii <= 3; ++ii) {
      int i0 = ii - 1, k = i0;
      double p = d[i0 - 1];
      for (int j = ii; j <= 3; ++j) if (d[j - 1] < p) { k = j; p = d[j - 1]; }
      if (k != i0) {
        d[k - 1] = d[i0 - 1]; d[i0 - 1] = p;
        for (int rr = 0; rr < 3; ++rr) { double t = Z[rr][i0 - 1]; Z[rr][i0 - 1] = Z[rr][k - 1]; Z[rr][k - 1] = t; }
      }
    }
  }
  // ---- sormtr: Z := H1 * Z
  if (tau != 0.0) {
    for (int j = 0; j < 3; ++j) {
      double w = Z[1][j] + v2 * Z[2][j];
      Z[1][j] -= tau * w;
      Z[2][j] -= tau * v2 * w;
    }
  }
  for (int i = 0; i < 3; ++i)
    for (int j = 0; j < 3; ++j)
      V[i][j] = (float)Z[i][2 - j];
}

// ===================== kernel 0: pack pos -> float4 {x,y,z,sq} =====================
__global__ __launch_bounds__(256) void pack_kernel(const float* __restrict__ pos,
                                                   float4* __restrict__ pos4) {
#pragma clang fp contract(off)
  int i = blockIdx.x * 256 + threadIdx.x;
  if (i < NPOINTS) {
    float x = pos[3 * i + 0], y = pos[3 * i + 1], z = pos[3 * i + 2];
    float sq = (x * x + y * y) + z * z;   // XLA reduce order (same as r6)
    pos4[i] = make_float4(x, y, z, sq);
  }
}

// ===================== kernel 1: exact KNN, LDS-tiled + reg prefetch ============
// Order: C = (fkey(d2) << 32) | (0xFFFFFFFF - idx). 32 smallest C == r6-verified
// semantics (key asc, ties -> HIGHER index first). Chain-A d2 unchanged.
// r13: T14-style async-stage — prefetch tile t+1 into regs during compute of t;
// ds_write lands after the top barrier (vmcnt wait ~0 by then).
#define WPB  4    // waves per block
#define RPW  4    // rows per wave -> 16 rows per block
#define TPTS 1024 // tile points (16 KB)
#define NTIL (NPOINTS / TPTS)
#define CAP  128  // candidate capacity per row (E[cnt]~44; serial fallback kept)

__global__ __launch_bounds__(256) void knn_kernel(const float4* __restrict__ pos4,
                                                  unsigned* __restrict__ idx_out) {
#pragma clang fp contract(off)
  __shared__ float4 tile[TPTS];            // 16 KB
  __shared__ ull cand[WPB][RPW][CAP];      // 16 KB
  __shared__ ull sel[WPB][RPW][KNN];       // 4 KB
  const int tid  = threadIdx.x;
  const int lane = tid & 63;
  const int wave = tid >> 6;
  const int rowbase = (blockIdx.x * WPB + wave) * RPW;
  const float INF = __int_as_float(0x7f800000);

  float rx[RPW], ry[RPW], rz[RPW], rq[RPW];
#pragma unroll
  for (int r = 0; r < RPW; ++r) {
    const float4 rp = pos4[rowbase + r];
    rx[r] = rp.x; ry[r] = rp.y; rz[r] = rp.z; rq[r] = rp.w;
  }

  float4 st[TPTS / 256];
#pragma unroll
  for (int q = 0; q < TPTS / 256; ++q) st[q] = pos4[q * 256 + tid];

  // ---- phase A: per-lane MIN d2 only (1 v_min per pair-row) ----
  float k1f[RPW];
#pragma unroll
  for (int r = 0; r < RPW; ++r) k1f[r] = INF;
  for (int t = 0; t < NTIL; ++t) {
    __syncthreads();                       // prior tile fully consumed (r2 lesson)
#pragma unroll
    for (int q = 0; q < TPTS / 256; ++q)
      tile[q * 256 + tid] = st[q];
    __syncthreads();
    if (t + 1 < NTIL) {
#pragma unroll
      for (int q = 0; q < TPTS / 256; ++q)
        st[q] = pos4[(t + 1) * TPTS + q * 256 + tid];   // prefetch (in flight over compute)
    }
#pragma unroll 4
    for (int ch = 0; ch < TPTS / 64; ++ch) {
      const float4 p = tile[ch * 64 + lane];
#pragma unroll
      for (int r = 0; r < RPW; ++r) {
        const float mdot = __builtin_fmaf(rz[r], p.z, __builtin_fmaf(ry[r], p.y, rx[r] * p.x));
        const float d2 = (rq[r] + p.w) - 2.0f * mdot;
        k1f[r] = fminf(k1f[r], d2);
      }
    }
  }

  // ---- per-row float threshold Tt = 32nd smallest of the 64 lane minima ----
  // Certified: <=31 global values strictly < T32, each in one lane => Tt >= T32.
  float Ttf[RPW];
#pragma unroll
  for (int r = 0; r < RPW; ++r) {
    int head = 0;
    float T = 0.f;
    for (int it = 0; it < KNN; ++it) {
      float v = (head == 0) ? k1f[r] : INF;
      float m = v;
      for (int off = 1; off < 64; off <<= 1) {
        float o = __shfl_xor(m, off, 64);
        m = fminf(m, o);
      }
      ull win = __ballot(v == m);
      int wl = __ffsll((long long)win) - 1;
      if (lane == wl) ++head;
      T = m;
    }
    Ttf[r] = T;
  }

  // ---- phase B: compact candidates with d2 <= Ttf per row (tiled + prefetch) ----
#pragma unroll
  for (int q = 0; q < TPTS / 256; ++q) st[q] = pos4[q * 256 + tid];
  unsigned cnt[RPW];
#pragma unroll
  for (int r = 0; r < RPW; ++r) cnt[r] = 0;
  for (int t = 0; t < NTIL; ++t) {
    __syncthreads();
#pragma unroll
    for (int q = 0; q < TPTS / 256; ++q)
      tile[q * 256 + tid] = st[q];
    __syncthreads();
    if (t + 1 < NTIL) {
#pragma unroll
      for (int q = 0; q < TPTS / 256; ++q)
        st[q] = pos4[(t + 1) * TPTS + q * 256 + tid];
    }
#pragma unroll 2
    for (int ch = 0; ch < TPTS / 64; ++ch) {
      const int j = t * TPTS + ch * 64 + lane;
      const float4 p = tile[ch * 64 + lane];
#pragma unroll
      for (int r = 0; r < RPW; ++r) {
        const float mdot = __builtin_fmaf(rz[r], p.z, __builtin_fmaf(ry[r], p.y, rx[r] * p.x));
        const float d2 = (rq[r] + p.w) - 2.0f * mdot;
        const bool c = (d2 <= Ttf[r]);
        const ull m = __ballot(c);
        if (c) {
          unsigned slot = cnt[r] + prefix64(m);
          if (slot < CAP)
            cand[wave][r][slot] = ((ull)fkey(d2) << 32) | (ull)(0xFFFFFFFFu - (unsigned)j);
        }
        cnt[r] += (unsigned)__popcll(m);
      }
    }
  }
  __builtin_amdgcn_s_waitcnt(0);   // drain our ds_writes (wave-private region)

#pragma unroll
  for (int r = 0; r < RPW; ++r) {
    if (cnt[r] <= (unsigned)CAP) {
      // exact wave-parallel extraction of 32 smallest C from <=128 candidates
      ull c0 = (lane < (int)cnt[r]) ? cand[wave][r][lane] : ~0ULL;
      ull c1 = ((lane + 64) < (int)cnt[r]) ? cand[wave][r][lane + 64] : ~0ULL;
      ull lo = (c0 < c1) ? c0 : c1;
      ull hi = (c0 < c1) ? c1 : c0;
      int head = 0;
      for (int it = 0; it < KNN; ++it) {
        ull v = (head == 0) ? lo : ((head == 1) ? hi : ~0ULL);
        ull m = v;
        for (int off = 1; off < 64; off <<= 1) {
          ull o = shflx64(m, off);
          m = (o < m) ? o : m;
        }
        ull win = __ballot(v == m);
        int wl = __ffsll((long long)win) - 1;
        if (lane == wl) ++head;
        if (lane == 0) sel[wave][r][it] = m;
      }
    } else {
      // exact serial fallback (probability ~0)
      if (lane == 0) {
        int n2 = 0;
        for (int j = 0; j < NPOINTS; ++j) {
          const float4 p = pos4[j];
          const float mdot = __builtin_fmaf(rz[r], p.z, __builtin_fmaf(ry[r], p.y, rx[r] * p.x));
          const float d2 = (rq[r] + p.w) - 2.0f * mdot;
          const unsigned key = fkey(d2);
          const ull C = ((ull)key << 32) | (ull)(0xFFFFFFFFu - (unsigned)j);
          if (n2 < KNN) {
            int b = n2 - 1;
            while (b >= 0 && sel[wave][r][b] > C) { sel[wave][r][b + 1] = sel[wave][r][b]; --b; }
            sel[wave][r][b + 1] = C;
            ++n2;
          } else if (C < sel[wave][r][KNN - 1]) {
            int b = KNN - 2;
            while (b >= 0 && sel[wave][r][b] > C) { sel[wave][r][b + 1] = sel[wave][r][b]; --b; }
            sel[wave][r][b + 1] = C;
          }
        }
      }
    }
  }
  __builtin_amdgcn_s_waitcnt(0);

  // finalize (lane 0): C-ascending == (key asc, idx desc). Emission wants
  // (key asc, idx asc): reverse idx within bit-equal-key runs only (rare).
  if (lane == 0) {
#pragma unroll
    for (int r = 0; r < RPW; ++r) {
      unsigned kk[KNN], ii[KNN];
      for (int a = 0; a < KNN; ++a) {
        ull C = sel[wave][r][a];
        kk[a] = (unsigned)(C >> 32);
        ii[a] = 0xFFFFFFFFu - (unsigned)(C & 0xFFFFFFFFULL);
      }
      int a = 0;
      while (a < KNN) {
        int b = a;
        while (b + 1 < KNN && kk[b + 1] == kk[a]) ++b;
        for (int x = a, y = b; x < y; ++x, --y) { unsigned tmp = ii[x]; ii[x] = ii[y]; ii[y] = tmp; }
        a = b + 1;
      }
      unsigned ob = (unsigned)(rowbase + r) * KNN;
      for (int q = 0; q < KNN; ++q) idx_out[ob + q] = ii[q];
    }
  }
}

// ===================== kernel 2: mean + cov + eigh per point (fp32) =====================
__global__ __launch_bounds__(256) void pca_kernel(const float4* __restrict__ pos4,
                                                  const unsigned* __restrict__ idx,
                                                  float* __restrict__ center,
                                                  float* __restrict__ Vmat) {
#pragma clang fp contract(off)
  int n = blockIdx.x * 256 + threadIdx.x;
  if (n >= NPOINTS) return;
  float sx = 0.f, sy = 0.f, sz = 0.f;
  for (int k = 0; k < KNN; ++k) {
    unsigned j = idx[n * KNN + k];
    const float4 p = pos4[j];
    sx += p.x; sy += p.y; sz += p.z;
  }
  float cx = sx * 0.03125f, cy = sy * 0.03125f, cz = sz * 0.03125f;
  float c00 = 0.f, c10 = 0.f, c20 = 0.f, c11 = 0.f, c21 = 0.f, c22 = 0.f;
  for (int k = 0; k < KNN; ++k) {
    unsigned j = idx[n * KNN + k];
    const float4 p = pos4[j];
    float lx = p.x - cx;
    float ly = p.y - cy;
    float lz = p.z - cz;
    c00 += lx * lx; c10 += lx * ly; c20 += lx * lz;
    c11 += ly * ly; c21 += ly * lz; c22 += lz * lz;
  }
  c00 *= 0.03125f; c10 *= 0.03125f; c20 *= 0.03125f;
  c11 *= 0.03125f; c21 *= 0.03125f; c22 *= 0.03125f;
  float V[3][3];
  eigh3(c00, c10, c20, c11, c21, c22, V);
  center[n * 3 + 0] = cx; center[n * 3 + 1] = cy; center[n * 3 + 2] = cz;
  for (int i = 0; i < 3; ++i)
    for (int j2 = 0; j2 < 3; ++j2)
      Vmat[n * 9 + i * 3 + j2] = V[i][j2];
}

// ===================== kernel 3: basis + G[b,i] + 27x (64x64) matmuls =====================
#define NT 8
__global__ __launch_bounds__(256) void conv_kernel(const float4* __restrict__ pos4,
                                                   const float* __restrict__ chan,
                                                   const float* __restrict__ coeff,
                                                   const unsigned* __restrict__ idx,
                                                   const float* __restrict__ center,
                                                   const float* __restrict__ Vmat,
                                                   float* __restrict__ out) {
#pragma clang fp contract(off)
  __shared__ float G[NT][NBASIS][64];
  __shared__ float Tsh[NT][64];
  const int tid  = threadIdx.x;
  const int lane = tid & 63;
  const int wave = tid >> 6;
  const int n0 = blockIdx.x * NT;

  for (int rep = 0; rep < 2; ++rep) {
    const int nl = wave * 2 + rep;
    const int n = n0 + nl;
    const float cx = center[n * 3 + 0], cy = center[n * 3 + 1], cz = center[n * 3 + 2];
    const float V00 = Vmat[n * 9 + 0], V01 = Vmat[n * 9 + 1], V02 = Vmat[n * 9 + 2];
    const float V10 = Vmat[n * 9 + 3], V11 = Vmat[n * 9 + 4], V12 = Vmat[n * 9 + 5];
    const float V20 = Vmat[n * 9 + 6], V21 = Vmat[n * 9 + 7], V22 = Vmat[n * 9 + 8];
    float g[NBASIS];
#pragma unroll
    for (int b = 0; b < NBASIS; ++b) g[b] = 0.f;
    for (int k = 0; k < KNN; ++k) {
      const unsigned j = idx[n * KNN + k];
      const float4 pj = pos4[j];                    // 1 dwordx4 vs 3 dwords
      const float lx = pj.x - cx;
      const float ly = pj.y - cy;
      const float lz = pj.z - cz;
      const float X  = lx * V00 + ly * V10 + lz * V20;
      const float Y  = lx * V01 + ly * V11 + lz * V21;
      const float Zc = lx * V02 + ly * V12 + lz * V22;
      const float r = sqrtf(((X * X + Y * Y) + Zc * Zc) + 1e-8f);
      float u = Zc / r;
      u = fminf(fmaxf(u, -0.999999f), 0.999999f);
      const float ct1 = u, ct2 = 2.f * u * u - 1.f;
      const float rho2 = X * X + Y * Y;
      const float cp1 = (rho2 > 0.f) ? (X / sqrtf(rho2)) : 1.f;
      const float cp2 = 2.f * cp1 * cp1 - 1.f;
      const float f = chan[(size_t)j * 64 + lane];
      const float pr1 = r, pr2 = r * r;
      float tc[9];
      tc[0] = 1.f; tc[1] = cp1; tc[2] = cp2;
      tc[3] = ct1; tc[4] = ct1 * cp1; tc[5] = ct1 * cp2;
      tc[6] = ct2; tc[7] = ct2 * cp1; tc[8] = ct2 * cp2;
#pragma unroll
      for (int m9 = 0; m9 < 9; ++m9) {
        g[m9]      = __builtin_fmaf(tc[m9],       f, g[m9]);
        g[9 + m9]  = __builtin_fmaf(pr1 * tc[m9], f, g[9 + m9]);
        g[18 + m9] = __builtin_fmaf(pr2 * tc[m9], f, g[18 + m9]);
      }
    }
#pragma unroll
    for (int b = 0; b < NBASIS; ++b) G[nl][b][lane] = g[b];
  }
  __syncthreads();

  float acc0 = 0.f, acc1 = 0.f;
  for (int b = 0; b < NBASIS; ++b) {
    const float4* g0p = (const float4*)(&G[wave * 2 + 0][b][0]);   // broadcast reads
    const float4* g1p = (const float4*)(&G[wave * 2 + 1][b][0]);
    const float* cp = coeff + (size_t)(b * 64) * 64 + lane;
#pragma unroll 4
    for (int i4 = 0; i4 < 16; ++i4) {
      const float4 g0 = g0p[i4];
      const float4 g1 = g1p[i4];
      const float c0 = cp[(i4 * 4 + 0) * 64];
      const float c1 = cp[(i4 * 4 + 1) * 64];
      const float c2 = cp[(i4 * 4 + 2) * 64];
      const float c3 = cp[(i4 * 4 + 3) * 64];
      acc0 = __builtin_fmaf(c0, g0.x, acc0);
      acc0 = __builtin_fmaf(c1, g0.y, acc0);
      acc0 = __builtin_fmaf(c2, g0.z, acc0);
      acc0 = __builtin_fmaf(c3, g0.w, acc0);
      acc1 = __builtin_fmaf(c0, g1.x, acc1);
      acc1 = __builtin_fmaf(c1, g1.y, acc1);
      acc1 = __builtin_fmaf(c2, g1.z, acc1);
      acc1 = __builtin_fmaf(c3, g1.w, acc1);
    }
  }
  __syncthreads();
  Tsh[wave * 2 + 0][lane] = acc0 * 0.03125f;
  Tsh[wave * 2 + 1][lane] = acc1 * 0.03125f;
  __syncthreads();
#pragma unroll
  for (int s = 0; s < 2; ++s) {
    const int el = tid + s * 256;
    const int o = el >> 3, nn = el & 7;
    out[(size_t)o * NPOINTS + (n0 + nn)] = Tsh[nn][o];
  }
}

// ===================== launch =====================
extern "C" void kernel_launch(void* const* d_in, const int* in_sizes, int n_in,
                              void* d_out, int out_size, void* d_ws, size_t ws_size,
                              hipStream_t stream) {
  (void)in_sizes; (void)n_in; (void)out_size; (void)ws_size;
  const float* pos   = (const float*)d_in[0];
  const float* chan  = (const float*)d_in[1];
  const float* coeff = (const float*)d_in[2];
  float* out = (float*)d_out;
  unsigned char* ws = (unsigned char*)d_ws;
  float4*   pos4   = (float4*)(ws);                                    // 256 KiB
  unsigned* idx    = (unsigned*)(ws + (size_t)NPOINTS * 16);           // 2 MiB
  float*    center = (float*)(ws + (size_t)NPOINTS * 16 + (size_t)NPOINTS * KNN * 4);          // 192 KiB
  float*    Vmat   = (float*)(ws + (size_t)NPOINTS * 16 + (size_t)NPOINTS * KNN * 4
                              + (size_t)NPOINTS * 12);                 // 576 KiB
  hipLaunchKernelGGL(pack_kernel, dim3(NPOINTS / 256),         dim3(256), 0, stream, pos, pos4);
  hipLaunchKernelGGL(knn_kernel,  dim3(NPOINTS / (WPB * RPW)), dim3(256), 0, stream, pos4, idx);
  hipLaunchKernelGGL(pca_kernel,  dim3(NPOINTS / 256),         dim3(256), 0, stream, pos4, idx, center, Vmat);
  hipLaunchKernelGGL(conv_kernel, dim3(NPOINTS / NT),          dim3(256), 0, stream, pos4, chan, coeff, idx, center, Vmat, out);
}

// Round 14
// 826.891 us; speedup vs baseline: 1.3084x; 1.0543x over previous
//
#include <hip/hip_runtime.h>
#include <math.h>

#define NPOINTS 16384
#define KNN     32
#define NBASIS  27

typedef unsigned long long ull;

// ===================== helpers =====================

__device__ __forceinline__ unsigned fkey(float f) {
  // monotone order-preserving map fp32 -> uint32 (3 VALU: ashr, or, xor)
  unsigned u = __float_as_uint(f);
  unsigned m = (unsigned)((int)u >> 31) | 0x80000000u;
  return u ^ m;
}

__device__ __forceinline__ ull shflx64(ull v, int mask) {
  int lo = __shfl_xor((int)(unsigned)(v & 0xFFFFFFFFULL), mask, 64);
  int hi = __shfl_xor((int)(unsigned)(v >> 32), mask, 64);
  return ((ull)(unsigned)hi << 32) | (ull)(unsigned)lo;
}

// count of set bits in m strictly below this lane (2 VALU)
__device__ __forceinline__ unsigned prefix64(ull m) {
  return __builtin_amdgcn_mbcnt_hi((unsigned)(m >> 32),
         __builtin_amdgcn_mbcnt_lo((unsigned)m, 0u));
}

// ===================== faithful ssyevd(3x3) port (double arith, fp32 eps) ============

__device__ __forceinline__ void slartg_dev(double f, double g, double* c, double* s, double* r) {
#pragma clang fp contract(off)
  // LAPACK >= 3.10 convention (c >= 0)
  if (g == 0.0) { *c = 1.0; *s = 0.0; *r = f; }
  else if (f == 0.0) { *c = 0.0; *s = (g >= 0.0 ? 1.0 : -1.0); *r = fabs(g); }
  else {
    double d = sqrt(f * f + g * g);
    *c = fabs(f) / d;
    *r = (f >= 0.0) ? d : -d;
    *s = g / (*r);
  }
}

__device__ __forceinline__ void slaev2_dev(double a, double b, double c,
                                           double* rt1, double* rt2, double* cs1, double* sn1) {
#pragma clang fp contract(off)
  double sm = a + c, df = a - c, adf = fabs(df), tb = b + b, ab = fabs(tb);
  double acmx, acmn;
  if (fabs(a) > fabs(c)) { acmx = a; acmn = c; } else { acmx = c; acmn = a; }
  double rt;
  if (adf > ab)      rt = adf * sqrt(1.0 + (ab / adf) * (ab / adf));
  else if (adf < ab) rt = ab * sqrt(1.0 + (adf / ab) * (adf / ab));
  else               rt = ab * sqrt(2.0);
  int sgn1;
  if (sm < 0.0) { *rt1 = 0.5 * (sm - rt); sgn1 = -1; *rt2 = (acmx / *rt1) * acmn - (b / *rt1) * b; }
  else if (sm > 0.0) { *rt1 = 0.5 * (sm + rt); sgn1 = 1; *rt2 = (acmx / *rt1) * acmn - (b / *rt1) * b; }
  else { *rt1 = 0.5 * rt; *rt2 = -0.5 * rt; sgn1 = 1; }
  int sgn2; double cs;
  if (df >= 0.0) { cs = df + rt; sgn2 = 1; } else { cs = df - rt; sgn2 = -1; }
  double acs = fabs(cs);
  if (acs > ab) { double ct = -tb / cs; double sn = 1.0 / sqrt(1.0 + ct * ct); *sn1 = sn; *cs1 = ct * sn; }
  else {
    if (ab == 0.0) { *cs1 = 1.0; *sn1 = 0.0; }
    else { double tn = -cs / tb; double c1 = 1.0 / sqrt(1.0 + tn * tn); *cs1 = c1; *sn1 = tn * c1; }
  }
  if (sgn1 == sgn2) { double tn = *cs1; *cs1 = -(*sn1); *sn1 = tn; }
}

// Input: lower triangle of symmetric 3x3 (fp32 cov). Output: V columns in DESCENDING
// eigenvalue order (LAPACK ascending, reversed) = np/jnp eigh + [:, :, ::-1].
__device__ void eigh3(float A00, float A10, float A20, float A11, float A21, float A22,
                      float V[3][3]) {
#pragma clang fp contract(off)
  const double EPS    = 5.9604644775390625e-08;   // fp32 slamch('E')
  const double EPS2   = EPS * EPS;
  const double SAFMIN = 1.1754943508222875e-38;   // fp32 slamch('S')
  double d[3], e[2];
  double tau = 0.0, v2 = 0.0;
  // ---- ssytd2 (uplo='L'), single Householder on [A10; A20]
  {
    double alpha = (double)A10, x = (double)A20;
    double a11 = (double)A11, a21 = (double)A21, a22 = (double)A22;
    double beta;
    if (x == 0.0) { tau = 0.0; v2 = 0.0; beta = alpha; }
    else {
      double nrm = sqrt(alpha * alpha + x * x);          // slapy2
      beta = (alpha >= 0.0) ? -nrm : nrm;                // -sign(nrm, alpha)
      tau = (beta - alpha) / beta;
      v2 = x / (alpha - beta);
    }
    if (tau != 0.0) {
      double w0 = tau * (a11 + a21 * v2);
      double w1 = tau * (a21 + a22 * v2);
      double cc = 0.5 * tau * (w0 + w1 * v2);
      w0 -= cc; w1 -= cc * v2;
      a11 -= 2.0 * w0;
      a21 -= (v2 * w0 + w1);
      a22 -= 2.0 * v2 * w1;
    }
    d[0] = (double)A00; d[1] = a11; d[2] = a22;
    e[0] = beta; e[1] = a21;
  }
  double Z[3][3] = { {1.0, 0.0, 0.0}, {0.0, 1.0, 0.0}, {0.0, 0.0, 1.0} };
  // ---- ssteqr('I', n=3)
  {
    int l1 = 1, jtot = 0;
    const int nmaxit = 90;
    double wc[2], wsn[2];
    while (l1 <= 3) {
      if (l1 > 1) e[l1 - 2] = 0.0;
      int m = 3;
      for (int mm = l1; mm <= 2; ++mm) {
        double tst = fabs(e[mm - 1]);
        if (tst == 0.0) { m = mm; break; }
        if (tst <= (sqrt(fabs(d[mm - 1])) * sqrt(fabs(d[mm]))) * EPS) { e[mm - 1] = 0.0; m = mm; break; }
      }
      int l = l1, lsv = l, lend = m, lendsv = lend;
      l1 = m + 1;
      if (lend == l) continue;
      double anorm = 0.0;
      for (int i = l; i <= lend; ++i)     anorm = fmax(anorm, fabs(d[i - 1]));
      for (int i = l; i <= lend - 1; ++i) anorm = fmax(anorm, fabs(e[i - 1]));
      if (anorm == 0.0) continue;
      if (fabs(d[lend - 1]) < fabs(d[l - 1])) { lend = lsv; l = lendsv; }
      if (lend > l) {
        // ===== QL =====
        bool done = false;
        while (!done) {
          int mq = lend;
          for (int mm = l; mm <= lend - 1; ++mm) {
            double tst = e[mm - 1] * e[mm - 1];
            if (tst <= (EPS2 * fabs(d[mm - 1])) * fabs(d[mm]) + SAFMIN) { mq = mm; break; }
          }
          if (mq < lend) e[mq - 1] = 0.0;
          double p = d[l - 1];
          if (mq == l) { d[l - 1] = p; ++l; if (l > lend) done = true; continue; }
          if (mq == l + 1) {
            double rt1, rt2, cc, ssn;
            slaev2_dev(d[l - 1], e[l - 1], d[l], &rt1, &rt2, &cc, &ssn);
            for (int i = 0; i < 3; ++i) {
              double t = Z[i][l];
              Z[i][l]     = cc * t - ssn * Z[i][l - 1];
              Z[i][l - 1] = ssn * t + cc * Z[i][l - 1];
            }
            d[l - 1] = rt1; d[l] = rt2; e[l - 1] = 0.0;
            l += 2; if (l > lend) done = true; continue;
          }
          if (jtot >= nmaxit) break;
          ++jtot;
          double g = (d[l] - p) / (2.0 * e[l - 1]);
          double r = sqrt(g * g + 1.0);
          g = d[mq - 1] - p + e[l - 1] / (g + ((g >= 0.0) ? r : -r));
          double ssn = 1.0, cc = 1.0;
          p = 0.0;
          for (int i = mq - 1; i >= l; --i) {
            double f = ssn * e[i - 1], b = cc * e[i - 1];
            slartg_dev(g, f, &cc, &ssn, &r);
            if (i != mq - 1) e[i] = r;
            g = d[i] - p;
            r = (d[i - 1] - g) * ssn + 2.0 * cc * b;
            p = ssn * r;
            d[i] = g + p;
            g = cc * r - b;
            wc[i - 1] = cc; wsn[i - 1] = -ssn;
          }
          for (int j = mq - 1; j >= l; --j) {
            double cj = wc[j - 1], sj = wsn[j - 1];
            for (int i = 0; i < 3; ++i) {
              double t = Z[i][j];
              Z[i][j]     = cj * t - sj * Z[i][j - 1];
              Z[i][j - 1] = sj * t + cj * Z[i][j - 1];
            }
          }
          d[l - 1] -= p; e[l - 1] = g;
        }
      } else {
        // ===== QR =====
        bool done = false;
        while (!done) {
          int mq = lend;
          for (int mm = l; mm >= lend + 1; --mm) {
            double tst = e[mm - 2] * e[mm - 2];
            if (tst <= (EPS2 * fabs(d[mm - 1])) * fabs(d[mm - 2]) + SAFMIN) { mq = mm; break; }
          }
          if (mq > lend) e[mq - 2] = 0.0;
          double p = d[l - 1];
          if (mq == l) { d[l - 1] = p; --l; if (l < lend) done = true; continue; }
          if (mq == l - 1) {
            double rt1, rt2, cc, ssn;
            slaev2_dev(d[l - 2], e[l - 2], d[l - 1], &rt1, &rt2, &cc, &ssn);
            for (int i = 0; i < 3; ++i) {
              double t = Z[i][l - 1];
              Z[i][l - 1] = cc * t - ssn * Z[i][l - 2];
              Z[i][l - 2] = ssn * t + cc * Z[i][l - 2];
            }
            d[l - 2] = rt1; d[l - 1] = rt2; e[l - 2] = 0.0;
            l -= 2; if (l < lend) done = true; continue;
          }
          if (jtot >= nmaxit) break;
          ++jtot;
          double g = (d[l - 2] - p) / (2.0 * e[l - 2]);
          double r = sqrt(g * g + 1.0);
          g = d[mq - 1] - p + e[l - 2] / (g + ((g >= 0.0) ? r : -r));
          double ssn = 1.0, cc = 1.0;
          p = 0.0;
          for (int i = mq; i <= l - 1; ++i) {
            double f = ssn * e[i - 1], b = cc * e[i - 1];
            slartg_dev(g, f, &cc, &ssn, &r);
            if (i != mq) e[i - 2] = r;
            g = d[i - 1] - p;
            r = (d[i] - g) * ssn + 2.0 * cc * b;
            p = ssn * r;
            d[i - 1] = g + p;
            g = cc * r - b;
            wc[i - 1] = cc; wsn[i - 1] = ssn;
          }
          for (int j = mq; j <= l - 1; ++j) {
            double cj = wc[j - 1], sj = wsn[j - 1];
            for (int i = 0; i < 3; ++i) {
              double t = Z[i][j];
              Z[i][j]     = cj * t - sj * Z[i][j - 1];
              Z[i][j - 1] = sj * t + cj * Z[i][j - 1];
            }
          }
          d[l - 1] -= p; e[l - 2] = g;
        }
      }
    }
    // ---- ascending selection sort with column swaps (as in ssteqr)
    for (int ii = 2; ii <= 3; ++ii) {
      int i0 = ii - 1, k = i0;
      double p = d[i0 - 1];
      for (int j = ii; j <= 3; ++j) if (d[j - 1] < p) { k = j; p = d[j - 1]; }
      if (k != i0) {
        d[k - 1] = d[i0 - 1]; d[i0 - 1] = p;
        for (int rr = 0; rr < 3; ++rr) { double t = Z[rr][i0 - 1]; Z[rr][i0 - 1] = Z[rr][k - 1]; Z[rr][k - 1] = t; }
      }
    }
  }
  // ---- sormtr: Z := H1 * Z
  if (tau != 0.0) {
    for (int j = 0; j < 3; ++j) {
      double w = Z[1][j] + v2 * Z[2][j];
      Z[1][j] -= tau * w;
      Z[2][j] -= tau * v2 * w;
    }
  }
  for (int i = 0; i < 3; ++i)
    for (int j = 0; j < 3; ++j)
      V[i][j] = (float)Z[i][2 - j];
}

// ===================== kernel 0: pack pos -> float4 {x,y,z,sq} =====================
__global__ __launch_bounds__(256) void pack_kernel(const float* __restrict__ pos,
                                                   float4* __restrict__ pos4) {
#pragma clang fp contract(off)
  int i = blockIdx.x * 256 + threadIdx.x;
  if (i < NPOINTS) {
    float x = pos[3 * i + 0], y = pos[3 * i + 1], z = pos[3 * i + 2];
    float sq = (x * x + y * y) + z * z;   // XLA reduce order (same as r6)
    pos4[i] = make_float4(x, y, z, sq);
  }
}

// ===================== kernel 1: exact KNN, LDS-tiled + NAMED-reg prefetch ============
// Order: C = (fkey(d2) << 32) | (0xFFFFFFFF - idx). 32 smallest C == r6-verified
// semantics (key asc, ties -> HIGHER index first). Chain-A d2 unchanged.
// r14 fix: r13's st[] array went to SCRATCH (WRITE_SIZE 131MB, rule #20).
// Named variables s0..s3 force VGPR allocation — no array indexing anywhere.
#define WPB  4    // waves per block
#define RPW  4    // rows per wave -> 16 rows per block
#define TPTS 1024 // tile points (16 KB)
#define NTIL (NPOINTS / TPTS)
#define CAP  128  // candidate capacity per row (E[cnt]~44; serial fallback kept)

__global__ __launch_bounds__(256) void knn_kernel(const float4* __restrict__ pos4,
                                                  unsigned* __restrict__ idx_out) {
#pragma clang fp contract(off)
  __shared__ float4 tile[TPTS];            // 16 KB
  __shared__ ull cand[WPB][RPW][CAP];      // 16 KB
  __shared__ ull sel[WPB][RPW][KNN];       // 4 KB
  const int tid  = threadIdx.x;
  const int lane = tid & 63;
  const int wave = tid >> 6;
  const int rowbase = (blockIdx.x * WPB + wave) * RPW;
  const float INF = __int_as_float(0x7f800000);

  float rx[RPW], ry[RPW], rz[RPW], rq[RPW];
#pragma unroll
  for (int r = 0; r < RPW; ++r) {
    const float4 rp = pos4[rowbase + r];
    rx[r] = rp.x; ry[r] = rp.y; rz[r] = rp.z; rq[r] = rp.w;
  }

  // named prefetch registers (rule #20: NO arrays)
  float4 s0 = pos4[0 * 256 + tid];
  float4 s1 = pos4[1 * 256 + tid];
  float4 s2 = pos4[2 * 256 + tid];
  float4 s3 = pos4[3 * 256 + tid];

  // ---- phase A: per-lane MIN d2 only (1 v_min per pair-row) ----
  float k1f[RPW];
#pragma unroll
  for (int r = 0; r < RPW; ++r) k1f[r] = INF;
  for (int t = 0; t < NTIL; ++t) {
    __syncthreads();                       // prior tile fully consumed (r2 lesson)
    tile[0 * 256 + tid] = s0;
    tile[1 * 256 + tid] = s1;
    tile[2 * 256 + tid] = s2;
    tile[3 * 256 + tid] = s3;
    __syncthreads();
    if (t + 1 < NTIL) {
      const int base = (t + 1) * TPTS + tid;
      s0 = pos4[base + 0 * 256];
      s1 = pos4[base + 1 * 256];
      s2 = pos4[base + 2 * 256];
      s3 = pos4[base + 3 * 256];           // in flight across the compute below
    }
#pragma unroll 4
    for (int ch = 0; ch < TPTS / 64; ++ch) {
      const float4 p = tile[ch * 64 + lane];
#pragma unroll
      for (int r = 0; r < RPW; ++r) {
        const float mdot = __builtin_fmaf(rz[r], p.z, __builtin_fmaf(ry[r], p.y, rx[r] * p.x));
        const float d2 = (rq[r] + p.w) - 2.0f * mdot;
        k1f[r] = fminf(k1f[r], d2);
      }
    }
  }

  // ---- per-row float threshold Tt = 32nd smallest of the 64 lane minima ----
  // Certified: <=31 global values strictly < T32, each in one lane => Tt >= T32.
  float Ttf[RPW];
#pragma unroll
  for (int r = 0; r < RPW; ++r) {
    int head = 0;
    float T = 0.f;
    for (int it = 0; it < KNN; ++it) {
      float v = (head == 0) ? k1f[r] : INF;
      float m = v;
      for (int off = 1; off < 64; off <<= 1) {
        float o = __shfl_xor(m, off, 64);
        m = fminf(m, o);
      }
      ull win = __ballot(v == m);
      int wl = __ffsll((long long)win) - 1;
      if (lane == wl) ++head;
      T = m;
    }
    Ttf[r] = T;
  }

  // ---- phase B: compact candidates with d2 <= Ttf per row (tiled + named prefetch) ----
  s0 = pos4[0 * 256 + tid];
  s1 = pos4[1 * 256 + tid];
  s2 = pos4[2 * 256 + tid];
  s3 = pos4[3 * 256 + tid];
  unsigned cnt[RPW];
#pragma unroll
  for (int r = 0; r < RPW; ++r) cnt[r] = 0;
  for (int t = 0; t < NTIL; ++t) {
    __syncthreads();
    tile[0 * 256 + tid] = s0;
    tile[1 * 256 + tid] = s1;
    tile[2 * 256 + tid] = s2;
    tile[3 * 256 + tid] = s3;
    __syncthreads();
    if (t + 1 < NTIL) {
      const int base = (t + 1) * TPTS + tid;
      s0 = pos4[base + 0 * 256];
      s1 = pos4[base + 1 * 256];
      s2 = pos4[base + 2 * 256];
      s3 = pos4[base + 3 * 256];
    }
#pragma unroll 2
    for (int ch = 0; ch < TPTS / 64; ++ch) {
      const int j = t * TPTS + ch * 64 + lane;
      const float4 p = tile[ch * 64 + lane];
#pragma unroll
      for (int r = 0; r < RPW; ++r) {
        const float mdot = __builtin_fmaf(rz[r], p.z, __builtin_fmaf(ry[r], p.y, rx[r] * p.x));
        const float d2 = (rq[r] + p.w) - 2.0f * mdot;
        const bool c = (d2 <= Ttf[r]);
        const ull m = __ballot(c);
        if (c) {
          unsigned slot = cnt[r] + prefix64(m);
          if (slot < CAP)
            cand[wave][r][slot] = ((ull)fkey(d2) << 32) | (ull)(0xFFFFFFFFu - (unsigned)j);
        }
        cnt[r] += (unsigned)__popcll(m);
      }
    }
  }
  __builtin_amdgcn_s_waitcnt(0);   // drain our ds_writes (wave-private region)

#pragma unroll
  for (int r = 0; r < RPW; ++r) {
    if (cnt[r] <= (unsigned)CAP) {
      // exact wave-parallel extraction of 32 smallest C from <=128 candidates
      ull c0 = (lane < (int)cnt[r]) ? cand[wave][r][lane] : ~0ULL;
      ull c1 = ((lane + 64) < (int)cnt[r]) ? cand[wave][r][lane + 64] : ~0ULL;
      ull lo = (c0 < c1) ? c0 : c1;
      ull hi = (c0 < c1) ? c1 : c0;
      int head = 0;
      for (int it = 0; it < KNN; ++it) {
        ull v = (head == 0) ? lo : ((head == 1) ? hi : ~0ULL);
        ull m = v;
        for (int off = 1; off < 64; off <<= 1) {
          ull o = shflx64(m, off);
          m = (o < m) ? o : m;
        }
        ull win = __ballot(v == m);
        int wl = __ffsll((long long)win) - 1;
        if (lane == wl) ++head;
        if (lane == 0) sel[wave][r][it] = m;
      }
    } else {
      // exact serial fallback (probability ~0)
      if (lane == 0) {
        int n2 = 0;
        for (int j = 0; j < NPOINTS; ++j) {
          const float4 p = pos4[j];
          const float mdot = __builtin_fmaf(rz[r], p.z, __builtin_fmaf(ry[r], p.y, rx[r] * p.x));
          const float d2 = (rq[r] + p.w) - 2.0f * mdot;
          const unsigned key = fkey(d2);
          const ull C = ((ull)key << 32) | (ull)(0xFFFFFFFFu - (unsigned)j);
          if (n2 < KNN) {
            int b = n2 - 1;
            while (b >= 0 && sel[wave][r][b] > C) { sel[wave][r][b + 1] = sel[wave][r][b]; --b; }
            sel[wave][r][b + 1] = C;
            ++n2;
          } else if (C < sel[wave][r][KNN - 1]) {
            int b = KNN - 2;
            while (b >= 0 && sel[wave][r][b] > C) { sel[wave][r][b + 1] = sel[wave][r][b]; --b; }
            sel[wave][r][b + 1] = C;
          }
        }
      }
    }
  }
  __builtin_amdgcn_s_waitcnt(0);

  // finalize (lane 0): C-ascending == (key asc, idx desc). Emission wants
  // (key asc, idx asc): reverse idx within bit-equal-key runs only (rare).
  if (lane == 0) {
#pragma unroll
    for (int r = 0; r < RPW; ++r) {
      unsigned kk[KNN], ii[KNN];
      for (int a = 0; a < KNN; ++a) {
        ull C = sel[wave][r][a];
        kk[a] = (unsigned)(C >> 32);
        ii[a] = 0xFFFFFFFFu - (unsigned)(C & 0xFFFFFFFFULL);
      }
      int a = 0;
      while (a < KNN) {
        int b = a;
        while (b + 1 < KNN && kk[b + 1] == kk[a]) ++b;
        for (int x = a, y = b; x < y; ++x, --y) { unsigned tmp = ii[x]; ii[x] = ii[y]; ii[y] = tmp; }
        a = b + 1;
      }
      unsigned ob = (unsigned)(rowbase + r) * KNN;
      for (int q = 0; q < KNN; ++q) idx_out[ob + q] = ii[q];
    }
  }
}

// ===================== kernel 2: mean + cov + eigh per point (fp32) =====================
__global__ __launch_bounds__(256) void pca_kernel(const float4* __restrict__ pos4,
                                                  const unsigned* __restrict__ idx,
                                                  float* __restrict__ center,
                                                  float* __restrict__ Vmat) {
#pragma clang fp contract(off)
  int n = blockIdx.x * 256 + threadIdx.x;
  if (n >= NPOINTS) return;
  float sx = 0.f, sy = 0.f, sz = 0.f;
  for (int k = 0; k < KNN; ++k) {
    unsigned j = idx[n * KNN + k];
    const float4 p = pos4[j];
    sx += p.x; sy += p.y; sz += p.z;
  }
  float cx = sx * 0.03125f, cy = sy * 0.03125f, cz = sz * 0.03125f;
  float c00 = 0.f, c10 = 0.f, c20 = 0.f, c11 = 0.f, c21 = 0.f, c22 = 0.f;
  for (int k = 0; k < KNN; ++k) {
    unsigned j = idx[n * KNN + k];
    const float4 p = pos4[j];
    float lx = p.x - cx;
    float ly = p.y - cy;
    float lz = p.z - cz;
    c00 += lx * lx; c10 += lx * ly; c20 += lx * lz;
    c11 += ly * ly; c21 += ly * lz; c22 += lz * lz;
  }
  c00 *= 0.03125f; c10 *= 0.03125f; c20 *= 0.03125f;
  c11 *= 0.03125f; c21 *= 0.03125f; c22 *= 0.03125f;
  float V[3][3];
  eigh3(c00, c10, c20, c11, c21, c22, V);
  center[n * 3 + 0] = cx; center[n * 3 + 1] = cy; center[n * 3 + 2] = cz;
  for (int i = 0; i < 3; ++i)
    for (int j2 = 0; j2 < 3; ++j2)
      Vmat[n * 9 + i * 3 + j2] = V[i][j2];
}

// ===================== kernel 3: basis + G[b,i] + 27x (64x64) matmuls =====================
#define NT 8
__global__ __launch_bounds__(256) void conv_kernel(const float4* __restrict__ pos4,
                                                   const float* __restrict__ chan,
                                                   const float* __restrict__ coeff,
                                                   const unsigned* __restrict__ idx,
                                                   const float* __restrict__ center,
                                                   const float* __restrict__ Vmat,
                                                   float* __restrict__ out) {
#pragma clang fp contract(off)
  __shared__ float G[NT][NBASIS][64];
  __shared__ float Tsh[NT][64];
  const int tid  = threadIdx.x;
  const int lane = tid & 63;
  const int wave = tid >> 6;
  const int n0 = blockIdx.x * NT;

  for (int rep = 0; rep < 2; ++rep) {
    const int nl = wave * 2 + rep;
    const int n = n0 + nl;
    const float cx = center[n * 3 + 0], cy = center[n * 3 + 1], cz = center[n * 3 + 2];
    const float V00 = Vmat[n * 9 + 0], V01 = Vmat[n * 9 + 1], V02 = Vmat[n * 9 + 2];
    const float V10 = Vmat[n * 9 + 3], V11 = Vmat[n * 9 + 4], V12 = Vmat[n * 9 + 5];
    const float V20 = Vmat[n * 9 + 6], V21 = Vmat[n * 9 + 7], V22 = Vmat[n * 9 + 8];
    float g[NBASIS];
#pragma unroll
    for (int b = 0; b < NBASIS; ++b) g[b] = 0.f;
    for (int k = 0; k < KNN; ++k) {
      const unsigned j = idx[n * KNN + k];
      const float4 pj = pos4[j];                    // 1 dwordx4 vs 3 dwords
      const float lx = pj.x - cx;
      const float ly = pj.y - cy;
      const float lz = pj.z - cz;
      const float X  = lx * V00 + ly * V10 + lz * V20;
      const float Y  = lx * V01 + ly * V11 + lz * V21;
      const float Zc = lx * V02 + ly * V12 + lz * V22;
      const float r = sqrtf(((X * X + Y * Y) + Zc * Zc) + 1e-8f);
      float u = Zc / r;
      u = fminf(fmaxf(u, -0.999999f), 0.999999f);
      const float ct1 = u, ct2 = 2.f * u * u - 1.f;
      const float rho2 = X * X + Y * Y;
      const float cp1 = (rho2 > 0.f) ? (X / sqrtf(rho2)) : 1.f;
      const float cp2 = 2.f * cp1 * cp1 - 1.f;
      const float f = chan[(size_t)j * 64 + lane];
      const float pr1 = r, pr2 = r * r;
      float tc[9];
      tc[0] = 1.f; tc[1] = cp1; tc[2] = cp2;
      tc[3] = ct1; tc[4] = ct1 * cp1; tc[5] = ct1 * cp2;
      tc[6] = ct2; tc[7] = ct2 * cp1; tc[8] = ct2 * cp2;
#pragma unroll
      for (int m9 = 0; m9 < 9; ++m9) {
        g[m9]      = __builtin_fmaf(tc[m9],       f, g[m9]);
        g[9 + m9]  = __builtin_fmaf(pr1 * tc[m9], f, g[9 + m9]);
        g[18 + m9] = __builtin_fmaf(pr2 * tc[m9], f, g[18 + m9]);
      }
    }
#pragma unroll
    for (int b = 0; b < NBASIS; ++b) G[nl][b][lane] = g[b];
  }
  __syncthreads();

  float acc0 = 0.f, acc1 = 0.f;
  for (int b = 0; b < NBASIS; ++b) {
    const float4* g0p = (const float4*)(&G[wave * 2 + 0][b][0]);   // broadcast reads
    const float4* g1p = (const float4*)(&G[wave * 2 + 1][b][0]);
    const float* cp = coeff + (size_t)(b * 64) * 64 + lane;
#pragma unroll 4
    for (int i4 = 0; i4 < 16; ++i4) {
      const float4 g0 = g0p[i4];
      const float4 g1 = g1p[i4];
      const float c0 = cp[(i4 * 4 + 0) * 64];
      const float c1 = cp[(i4 * 4 + 1) * 64];
      const float c2 = cp[(i4 * 4 + 2) * 64];
      const float c3 = cp[(i4 * 4 + 3) * 64];
      acc0 = __builtin_fmaf(c0, g0.x, acc0);
      acc0 = __builtin_fmaf(c1, g0.y, acc0);
      acc0 = __builtin_fmaf(c2, g0.z, acc0);
      acc0 = __builtin_fmaf(c3, g0.w, acc0);
      acc1 = __builtin_fmaf(c0, g1.x, acc1);
      acc1 = __builtin_fmaf(c1, g1.y, acc1);
      acc1 = __builtin_fmaf(c2, g1.z, acc1);
      acc1 = __builtin_fmaf(c3, g1.w, acc1);
    }
  }
  __syncthreads();
  Tsh[wave * 2 + 0][lane] = acc0 * 0.03125f;
  Tsh[wave * 2 + 1][lane] = acc1 * 0.03125f;
  __syncthreads();
#pragma unroll
  for (int s = 0; s < 2; ++s) {
    const int el = tid + s * 256;
    const int o = el >> 3, nn = el & 7;
    out[(size_t)o * NPOINTS + (n0 + nn)] = Tsh[nn][o];
  }
}

// ===================== launch =====================
extern "C" void kernel_launch(void* const* d_in, const int* in_sizes, int n_in,
                              void* d_out, int out_size, void* d_ws, size_t ws_size,
                              hipStream_t stream) {
  (void)in_sizes; (void)n_in; (void)out_size; (void)ws_size;
  const float* pos   = (const float*)d_in[0];
  const float* chan  = (const float*)d_in[1];
  const float* coeff = (const float*)d_in[2];
  float* out = (float*)d_out;
  unsigned char* ws = (unsigned char*)d_ws;
  float4*   pos4   = (float4*)(ws);                                    // 256 KiB
  unsigned* idx    = (unsigned*)(ws + (size_t)NPOINTS * 16);           // 2 MiB
  float*    center = (float*)(ws + (size_t)NPOINTS * 16 + (size_t)NPOINTS * KNN * 4);          // 192 KiB
  float*    Vmat   = (float*)(ws + (size_t)NPOINTS * 16 + (size_t)NPOINTS * KNN * 4
                              + (size_t)NPOINTS * 12);                 // 576 KiB
  hipLaunchKernelGGL(pack_kernel, dim3(NPOINTS / 256),         dim3(256), 0, stream, pos, pos4);
  hipLaunchKernelGGL(knn_kernel,  dim3(NPOINTS / (WPB * RPW)), dim3(256), 0, stream, pos4, idx);
  hipLaunchKernelGGL(pca_kernel,  dim3(NPOINTS / 256),         dim3(256), 0, stream, pos4, idx, center, Vmat);
  hipLaunchKernelGGL(conv_kernel, dim3(NPOINTS / NT),          dim3(256), 0, stream, pos4, chan, coeff, idx, center, Vmat, out);
}

// Round 15
// 782.689 us; speedup vs baseline: 1.3823x; 1.0565x over previous
//
#include <hip/hip_runtime.h>
#include <math.h>

#define NPOINTS 16384
#define KNN     32
#define NBASIS  27

typedef unsigned long long ull;

// ===================== helpers =====================

__device__ __forceinline__ unsigned fkey(float f) {
  // monotone order-preserving map fp32 -> uint32 (3 VALU: ashr, or, xor)
  unsigned u = __float_as_uint(f);
  unsigned m = (unsigned)((int)u >> 31) | 0x80000000u;
  return u ^ m;
}

__device__ __forceinline__ ull shflx64(ull v, int mask) {
  int lo = __shfl_xor((int)(unsigned)(v & 0xFFFFFFFFULL), mask, 64);
  int hi = __shfl_xor((int)(unsigned)(v >> 32), mask, 64);
  return ((ull)(unsigned)hi << 32) | (ull)(unsigned)lo;
}

// count of set bits in m strictly below this lane (2 VALU)
__device__ __forceinline__ unsigned prefix64(ull m) {
  return __builtin_amdgcn_mbcnt_hi((unsigned)(m >> 32),
         __builtin_amdgcn_mbcnt_lo((unsigned)m, 0u));
}

// ===================== faithful ssyevd(3x3) port (double arith, fp32 eps) ============

__device__ __forceinline__ void slartg_dev(double f, double g, double* c, double* s, double* r) {
#pragma clang fp contract(off)
  // LAPACK >= 3.10 convention (c >= 0)
  if (g == 0.0) { *c = 1.0; *s = 0.0; *r = f; }
  else if (f == 0.0) { *c = 0.0; *s = (g >= 0.0 ? 1.0 : -1.0); *r = fabs(g); }
  else {
    double d = sqrt(f * f + g * g);
    *c = fabs(f) / d;
    *r = (f >= 0.0) ? d : -d;
    *s = g / (*r);
  }
}

__device__ __forceinline__ void slaev2_dev(double a, double b, double c,
                                           double* rt1, double* rt2, double* cs1, double* sn1) {
#pragma clang fp contract(off)
  double sm = a + c, df = a - c, adf = fabs(df), tb = b + b, ab = fabs(tb);
  double acmx, acmn;
  if (fabs(a) > fabs(c)) { acmx = a; acmn = c; } else { acmx = c; acmn = a; }
  double rt;
  if (adf > ab)      rt = adf * sqrt(1.0 + (ab / adf) * (ab / adf));
  else if (adf < ab) rt = ab * sqrt(1.0 + (adf / ab) * (adf / ab));
  else               rt = ab * sqrt(2.0);
  int sgn1;
  if (sm < 0.0) { *rt1 = 0.5 * (sm - rt); sgn1 = -1; *rt2 = (acmx / *rt1) * acmn - (b / *rt1) * b; }
  else if (sm > 0.0) { *rt1 = 0.5 * (sm + rt); sgn1 = 1; *rt2 = (acmx / *rt1) * acmn - (b / *rt1) * b; }
  else { *rt1 = 0.5 * rt; *rt2 = -0.5 * rt; sgn1 = 1; }
  int sgn2; double cs;
  if (df >= 0.0) { cs = df + rt; sgn2 = 1; } else { cs = df - rt; sgn2 = -1; }
  double acs = fabs(cs);
  if (acs > ab) { double ct = -tb / cs; double sn = 1.0 / sqrt(1.0 + ct * ct); *sn1 = sn; *cs1 = ct * sn; }
  else {
    if (ab == 0.0) { *cs1 = 1.0; *sn1 = 0.0; }
    else { double tn = -cs / tb; double c1 = 1.0 / sqrt(1.0 + tn * tn); *cs1 = c1; *sn1 = tn * c1; }
  }
  if (sgn1 == sgn2) { double tn = *cs1; *cs1 = -(*sn1); *sn1 = tn; }
}

// Input: lower triangle of symmetric 3x3 (fp32 cov). Output: V columns in DESCENDING
// eigenvalue order (LAPACK ascending, reversed) = np/jnp eigh + [:, :, ::-1].
__device__ void eigh3(float A00, float A10, float A20, float A11, float A21, float A22,
                      float V[3][3]) {
#pragma clang fp contract(off)
  const double EPS    = 5.9604644775390625e-08;   // fp32 slamch('E')
  const double EPS2   = EPS * EPS;
  const double SAFMIN = 1.1754943508222875e-38;   // fp32 slamch('S')
  double d[3], e[2];
  double tau = 0.0, v2 = 0.0;
  // ---- ssytd2 (uplo='L'), single Householder on [A10; A20]
  {
    double alpha = (double)A10, x = (double)A20;
    double a11 = (double)A11, a21 = (double)A21, a22 = (double)A22;
    double beta;
    if (x == 0.0) { tau = 0.0; v2 = 0.0; beta = alpha; }
    else {
      double nrm = sqrt(alpha * alpha + x * x);          // slapy2
      beta = (alpha >= 0.0) ? -nrm : nrm;                // -sign(nrm, alpha)
      tau = (beta - alpha) / beta;
      v2 = x / (alpha - beta);
    }
    if (tau != 0.0) {
      double w0 = tau * (a11 + a21 * v2);
      double w1 = tau * (a21 + a22 * v2);
      double cc = 0.5 * tau * (w0 + w1 * v2);
      w0 -= cc; w1 -= cc * v2;
      a11 -= 2.0 * w0;
      a21 -= (v2 * w0 + w1);
      a22 -= 2.0 * v2 * w1;
    }
    d[0] = (double)A00; d[1] = a11; d[2] = a22;
    e[0] = beta; e[1] = a21;
  }
  double Z[3][3] = { {1.0, 0.0, 0.0}, {0.0, 1.0, 0.0}, {0.0, 0.0, 1.0} };
  // ---- ssteqr('I', n=3)
  {
    int l1 = 1, jtot = 0;
    const int nmaxit = 90;
    double wc[2], wsn[2];
    while (l1 <= 3) {
      if (l1 > 1) e[l1 - 2] = 0.0;
      int m = 3;
      for (int mm = l1; mm <= 2; ++mm) {
        double tst = fabs(e[mm - 1]);
        if (tst == 0.0) { m = mm; break; }
        if (tst <= (sqrt(fabs(d[mm - 1])) * sqrt(fabs(d[mm]))) * EPS) { e[mm - 1] = 0.0; m = mm; break; }
      }
      int l = l1, lsv = l, lend = m, lendsv = lend;
      l1 = m + 1;
      if (lend == l) continue;
      double anorm = 0.0;
      for (int i = l; i <= lend; ++i)     anorm = fmax(anorm, fabs(d[i - 1]));
      for (int i = l; i <= lend - 1; ++i) anorm = fmax(anorm, fabs(e[i - 1]));
      if (anorm == 0.0) continue;
      if (fabs(d[lend - 1]) < fabs(d[l - 1])) { lend = lsv; l = lendsv; }
      if (lend > l) {
        // ===== QL =====
        bool done = false;
        while (!done) {
          int mq = lend;
          for (int mm = l; mm <= lend - 1; ++mm) {
            double tst = e[mm - 1] * e[mm - 1];
            if (tst <= (EPS2 * fabs(d[mm - 1])) * fabs(d[mm]) + SAFMIN) { mq = mm; break; }
          }
          if (mq < lend) e[mq - 1] = 0.0;
          double p = d[l - 1];
          if (mq == l) { d[l - 1] = p; ++l; if (l > lend) done = true; continue; }
          if (mq == l + 1) {
            double rt1, rt2, cc, ssn;
            slaev2_dev(d[l - 1], e[l - 1], d[l], &rt1, &rt2, &cc, &ssn);
            for (int i = 0; i < 3; ++i) {
              double t = Z[i][l];
              Z[i][l]     = cc * t - ssn * Z[i][l - 1];
              Z[i][l - 1] = ssn * t + cc * Z[i][l - 1];
            }
            d[l - 1] = rt1; d[l] = rt2; e[l - 1] = 0.0;
            l += 2; if (l > lend) done = true; continue;
          }
          if (jtot >= nmaxit) break;
          ++jtot;
          double g = (d[l] - p) / (2.0 * e[l - 1]);
          double r = sqrt(g * g + 1.0);
          g = d[mq - 1] - p + e[l - 1] / (g + ((g >= 0.0) ? r : -r));
          double ssn = 1.0, cc = 1.0;
          p = 0.0;
          for (int i = mq - 1; i >= l; --i) {
            double f = ssn * e[i - 1], b = cc * e[i - 1];
            slartg_dev(g, f, &cc, &ssn, &r);
            if (i != mq - 1) e[i] = r;
            g = d[i] - p;
            r = (d[i - 1] - g) * ssn + 2.0 * cc * b;
            p = ssn * r;
            d[i] = g + p;
            g = cc * r - b;
            wc[i - 1] = cc; wsn[i - 1] = -ssn;
          }
          for (int j = mq - 1; j >= l; --j) {
            double cj = wc[j - 1], sj = wsn[j - 1];
            for (int i = 0; i < 3; ++i) {
              double t = Z[i][j];
              Z[i][j]     = cj * t - sj * Z[i][j - 1];
              Z[i][j - 1] = sj * t + cj * Z[i][j - 1];
            }
          }
          d[l - 1] -= p; e[l - 1] = g;
        }
      } else {
        // ===== QR =====
        bool done = false;
        while (!done) {
          int mq = lend;
          for (int mm = l; mm >= lend + 1; --mm) {
            double tst = e[mm - 2] * e[mm - 2];
            if (tst <= (EPS2 * fabs(d[mm - 1])) * fabs(d[mm - 2]) + SAFMIN) { mq = mm; break; }
          }
          if (mq > lend) e[mq - 2] = 0.0;
          double p = d[l - 1];
          if (mq == l) { d[l - 1] = p; --l; if (l < lend) done = true; continue; }
          if (mq == l - 1) {
            double rt1, rt2, cc, ssn;
            slaev2_dev(d[l - 2], e[l - 2], d[l - 1], &rt1, &rt2, &cc, &ssn);
            for (int i = 0; i < 3; ++i) {
              double t = Z[i][l - 1];
              Z[i][l - 1] = cc * t - ssn * Z[i][l - 2];
              Z[i][l - 2] = ssn * t + cc * Z[i][l - 2];
            }
            d[l - 2] = rt1; d[l - 1] = rt2; e[l - 2] = 0.0;
            l -= 2; if (l < lend) done = true; continue;
          }
          if (jtot >= nmaxit) break;
          ++jtot;
          double g = (d[l - 2] - p) / (2.0 * e[l - 2]);
          double r = sqrt(g * g + 1.0);
          g = d[mq - 1] - p + e[l - 2] / (g + ((g >= 0.0) ? r : -r));
          double ssn = 1.0, cc = 1.0;
          p = 0.0;
          for (int i = mq; i <= l - 1; ++i) {
            double f = ssn * e[i - 1], b = cc * e[i - 1];
            slartg_dev(g, f, &cc, &ssn, &r);
            if (i != mq) e[i - 2] = r;
            g = d[i - 1] - p;
            r = (d[i] - g) * ssn + 2.0 * cc * b;
            p = ssn * r;
            d[i - 1] = g + p;
            g = cc * r - b;
            wc[i - 1] = cc; wsn[i - 1] = ssn;
          }
          for (int j = mq; j <= l - 1; ++j) {
            double cj = wc[j - 1], sj = wsn[j - 1];
            for (int i = 0; i < 3; ++i) {
              double t = Z[i][j];
              Z[i][j]     = cj * t - sj * Z[i][j - 1];
              Z[i][j - 1] = sj * t + cj * Z[i][j - 1];
            }
          }
          d[l - 1] -= p; e[l - 2] = g;
        }
      }
    }
    // ---- ascending selection sort with column swaps (as in ssteqr)
    for (int ii = 2; ii <= 3; ++ii) {
      int i0 = ii - 1, k = i0;
      double p = d[i0 - 1];
      for (int j = ii; j <= 3; ++j) if (d[j - 1] < p) { k = j; p = d[j - 1]; }
      if (k != i0) {
        d[k - 1] = d[i0 - 1]; d[i0 - 1] = p;
        for (int rr = 0; rr < 3; ++rr) { double t = Z[rr][i0 - 1]; Z[rr][i0 - 1] = Z[rr][k - 1]; Z[rr][k - 1] = t; }
      }
    }
  }
  // ---- sormtr: Z := H1 * Z
  if (tau != 0.0) {
    for (int j = 0; j < 3; ++j) {
      double w = Z[1][j] + v2 * Z[2][j];
      Z[1][j] -= tau * w;
      Z[2][j] -= tau * v2 * w;
    }
  }
  for (int i = 0; i < 3; ++i)
    for (int j = 0; j < 3; ++j)
      V[i][j] = (float)Z[i][2 - j];
}

// ===================== kernel 0: pack pos -> float4 {x,y,z,sq} =====================
__global__ __launch_bounds__(256) void pack_kernel(const float* __restrict__ pos,
                                                   float4* __restrict__ pos4) {
#pragma clang fp contract(off)
  int i = blockIdx.x * 256 + threadIdx.x;
  if (i < NPOINTS) {
    float x = pos[3 * i + 0], y = pos[3 * i + 1], z = pos[3 * i + 2];
    float sq = (x * x + y * y) + z * z;   // XLA reduce order (same as r6)
    pos4[i] = make_float4(x, y, z, sq);
  }
}

// ===================== kernel 1: exact KNN, small-tile for occupancy ============
// Order: C = (fkey(d2) << 32) | (0xFFFFFFFF - idx). 32 smallest C == r6-verified
// semantics (key asc, ties -> HIGHER index first). Chain-A d2 unchanged.
// r15: TPTS 1024->512 cuts LDS 36->28KB => 5 blocks/CU (was ~2.5) for latency hiding.
#define WPB  4    // waves per block
#define RPW  4    // rows per wave -> 16 rows per block
#define TPTS 512  // tile points (8 KB)
#define NTIL (NPOINTS / TPTS)
#define CAP  128  // candidate capacity per row (E[cnt]~44; serial fallback kept)

__global__ __launch_bounds__(256) void knn_kernel(const float4* __restrict__ pos4,
                                                  unsigned* __restrict__ idx_out) {
#pragma clang fp contract(off)
  __shared__ float4 tile[TPTS];            // 8 KB
  __shared__ ull cand[WPB][RPW][CAP];      // 16 KB
  __shared__ ull sel[WPB][RPW][KNN];       // 4 KB
  const int tid  = threadIdx.x;
  const int lane = tid & 63;
  const int wave = tid >> 6;
  const int rowbase = (blockIdx.x * WPB + wave) * RPW;
  const float INF = __int_as_float(0x7f800000);

  float rx[RPW], ry[RPW], rz[RPW], rq[RPW];
#pragma unroll
  for (int r = 0; r < RPW; ++r) {
    const float4 rp = pos4[rowbase + r];
    rx[r] = rp.x; ry[r] = rp.y; rz[r] = rp.z; rq[r] = rp.w;
  }

  // named prefetch registers (rule #20: NO arrays)
  float4 s0 = pos4[0 * 256 + tid];
  float4 s1 = pos4[1 * 256 + tid];

  // ---- phase A: per-lane MIN d2 only (1 v_min per pair-row) ----
  float k1f[RPW];
#pragma unroll
  for (int r = 0; r < RPW; ++r) k1f[r] = INF;
  for (int t = 0; t < NTIL; ++t) {
    __syncthreads();                       // prior tile fully consumed (r2 lesson)
    tile[0 * 256 + tid] = s0;
    tile[1 * 256 + tid] = s1;
    __syncthreads();
    if (t + 1 < NTIL) {
      const int base = (t + 1) * TPTS + tid;
      s0 = pos4[base + 0 * 256];
      s1 = pos4[base + 1 * 256];           // in flight across the compute below
    }
#pragma unroll 4
    for (int ch = 0; ch < TPTS / 64; ++ch) {
      const float4 p = tile[ch * 64 + lane];
#pragma unroll
      for (int r = 0; r < RPW; ++r) {
        const float mdot = __builtin_fmaf(rz[r], p.z, __builtin_fmaf(ry[r], p.y, rx[r] * p.x));
        const float d2 = (rq[r] + p.w) - 2.0f * mdot;
        k1f[r] = fminf(k1f[r], d2);
      }
    }
  }

  // ---- per-row float threshold Tt = 32nd smallest of the 64 lane minima ----
  // Certified: <=31 global values strictly < T32, each in one lane => Tt >= T32.
  float Ttf[RPW];
#pragma unroll
  for (int r = 0; r < RPW; ++r) {
    int head = 0;
    float T = 0.f;
    for (int it = 0; it < KNN; ++it) {
      float v = (head == 0) ? k1f[r] : INF;
      float m = v;
      for (int off = 1; off < 64; off <<= 1) {
        float o = __shfl_xor(m, off, 64);
        m = fminf(m, o);
      }
      ull win = __ballot(v == m);
      int wl = __ffsll((long long)win) - 1;
      if (lane == wl) ++head;
      T = m;
    }
    Ttf[r] = T;
  }

  // ---- phase B: compact candidates with d2 <= Ttf per row (tiled + named prefetch) ----
  s0 = pos4[0 * 256 + tid];
  s1 = pos4[1 * 256 + tid];
  unsigned cnt[RPW];
#pragma unroll
  for (int r = 0; r < RPW; ++r) cnt[r] = 0;
  for (int t = 0; t < NTIL; ++t) {
    __syncthreads();
    tile[0 * 256 + tid] = s0;
    tile[1 * 256 + tid] = s1;
    __syncthreads();
    if (t + 1 < NTIL) {
      const int base = (t + 1) * TPTS + tid;
      s0 = pos4[base + 0 * 256];
      s1 = pos4[base + 1 * 256];
    }
#pragma unroll 2
    for (int ch = 0; ch < TPTS / 64; ++ch) {
      const int j = t * TPTS + ch * 64 + lane;
      const float4 p = tile[ch * 64 + lane];
#pragma unroll
      for (int r = 0; r < RPW; ++r) {
        const float mdot = __builtin_fmaf(rz[r], p.z, __builtin_fmaf(ry[r], p.y, rx[r] * p.x));
        const float d2 = (rq[r] + p.w) - 2.0f * mdot;
        const bool c = (d2 <= Ttf[r]);
        const ull m = __ballot(c);
        if (c) {
          unsigned slot = cnt[r] + prefix64(m);
          if (slot < CAP)
            cand[wave][r][slot] = ((ull)fkey(d2) << 32) | (ull)(0xFFFFFFFFu - (unsigned)j);
        }
        cnt[r] += (unsigned)__popcll(m);
      }
    }
  }
  __builtin_amdgcn_s_waitcnt(0);   // drain our ds_writes (wave-private region)

#pragma unroll
  for (int r = 0; r < RPW; ++r) {
    if (cnt[r] <= (unsigned)CAP) {
      // exact wave-parallel extraction of 32 smallest C from <=128 candidates
      ull c0 = (lane < (int)cnt[r]) ? cand[wave][r][lane] : ~0ULL;
      ull c1 = ((lane + 64) < (int)cnt[r]) ? cand[wave][r][lane + 64] : ~0ULL;
      ull lo = (c0 < c1) ? c0 : c1;
      ull hi = (c0 < c1) ? c1 : c0;
      int head = 0;
      for (int it = 0; it < KNN; ++it) {
        ull v = (head == 0) ? lo : ((head == 1) ? hi : ~0ULL);
        ull m = v;
        for (int off = 1; off < 64; off <<= 1) {
          ull o = shflx64(m, off);
          m = (o < m) ? o : m;
        }
        ull win = __ballot(v == m);
        int wl = __ffsll((long long)win) - 1;
        if (lane == wl) ++head;
        if (lane == 0) sel[wave][r][it] = m;
      }
    } else {
      // exact serial fallback (probability ~0)
      if (lane == 0) {
        int n2 = 0;
        for (int j = 0; j < NPOINTS; ++j) {
          const float4 p = pos4[j];
          const float mdot = __builtin_fmaf(rz[r], p.z, __builtin_fmaf(ry[r], p.y, rx[r] * p.x));
          const float d2 = (rq[r] + p.w) - 2.0f * mdot;
          const unsigned key = fkey(d2);
          const ull C = ((ull)key << 32) | (ull)(0xFFFFFFFFu - (unsigned)j);
          if (n2 < KNN) {
            int b = n2 - 1;
            while (b >= 0 && sel[wave][r][b] > C) { sel[wave][r][b + 1] = sel[wave][r][b]; --b; }
            sel[wave][r][b + 1] = C;
            ++n2;
          } else if (C < sel[wave][r][KNN - 1]) {
            int b = KNN - 2;
            while (b >= 0 && sel[wave][r][b] > C) { sel[wave][r][b + 1] = sel[wave][r][b]; --b; }
            sel[wave][r][b + 1] = C;
          }
        }
      }
    }
  }
  __builtin_amdgcn_s_waitcnt(0);

  // finalize (lane 0): C-ascending == (key asc, idx desc). Emission wants
  // (key asc, idx asc): reverse idx within bit-equal-key runs only (rare).
  if (lane == 0) {
#pragma unroll
    for (int r = 0; r < RPW; ++r) {
      unsigned kk[KNN], ii[KNN];
      for (int a = 0; a < KNN; ++a) {
        ull C = sel[wave][r][a];
        kk[a] = (unsigned)(C >> 32);
        ii[a] = 0xFFFFFFFFu - (unsigned)(C & 0xFFFFFFFFULL);
      }
      int a = 0;
      while (a < KNN) {
        int b = a;
        while (b + 1 < KNN && kk[b + 1] == kk[a]) ++b;
        for (int x = a, y = b; x < y; ++x, --y) { unsigned tmp = ii[x]; ii[x] = ii[y]; ii[y] = tmp; }
        a = b + 1;
      }
      unsigned ob = (unsigned)(rowbase + r) * KNN;
      for (int q = 0; q < KNN; ++q) idx_out[ob + q] = ii[q];
    }
  }
}

// ===================== kernel 2: mean + cov + eigh per point (fp32) =====================
__global__ __launch_bounds__(256) void pca_kernel(const float4* __restrict__ pos4,
                                                  const unsigned* __restrict__ idx,
                                                  float* __restrict__ center,
                                                  float* __restrict__ Vmat) {
#pragma clang fp contract(off)
  int n = blockIdx.x * 256 + threadIdx.x;
  if (n >= NPOINTS) return;
  float sx = 0.f, sy = 0.f, sz = 0.f;
  for (int k = 0; k < KNN; ++k) {
    unsigned j = idx[n * KNN + k];
    const float4 p = pos4[j];
    sx += p.x; sy += p.y; sz += p.z;
  }
  float cx = sx * 0.03125f, cy = sy * 0.03125f, cz = sz * 0.03125f;
  float c00 = 0.f, c10 = 0.f, c20 = 0.f, c11 = 0.f, c21 = 0.f, c22 = 0.f;
  for (int k = 0; k < KNN; ++k) {
    unsigned j = idx[n * KNN + k];
    const float4 p = pos4[j];
    float lx = p.x - cx;
    float ly = p.y - cy;
    float lz = p.z - cz;
    c00 += lx * lx; c10 += lx * ly; c20 += lx * lz;
    c11 += ly * ly; c21 += ly * lz; c22 += lz * lz;
  }
  c00 *= 0.03125f; c10 *= 0.03125f; c20 *= 0.03125f;
  c11 *= 0.03125f; c21 *= 0.03125f; c22 *= 0.03125f;
  float V[3][3];
  eigh3(c00, c10, c20, c11, c21, c22, V);
  center[n * 3 + 0] = cx; center[n * 3 + 1] = cy; center[n * 3 + 2] = cz;
  for (int i = 0; i < 3; ++i)
    for (int j2 = 0; j2 < 3; ++j2)
      Vmat[n * 9 + i * 3 + j2] = V[i][j2];
}

// ===================== kernel 3: basis + G[b,i] + 27x (64x64) matmuls ================
// r15: NT 8->4 (one point per wave), LDS 57->28KB => 5 blocks/CU (was 2).
#define NT 4
__global__ __launch_bounds__(256) void conv_kernel(const float4* __restrict__ pos4,
                                                   const float* __restrict__ chan,
                                                   const float* __restrict__ coeff,
                                                   const unsigned* __restrict__ idx,
                                                   const float* __restrict__ center,
                                                   const float* __restrict__ Vmat,
                                                   float* __restrict__ out) {
#pragma clang fp contract(off)
  __shared__ float G[NT][NBASIS][64];      // 27 KB
  __shared__ float Tsh[NT][64];            // 1 KB
  const int tid  = threadIdx.x;
  const int lane = tid & 63;
  const int wave = tid >> 6;
  const int n0 = blockIdx.x * NT;
  const int n  = n0 + wave;

  {
    const float cx = center[n * 3 + 0], cy = center[n * 3 + 1], cz = center[n * 3 + 2];
    const float V00 = Vmat[n * 9 + 0], V01 = Vmat[n * 9 + 1], V02 = Vmat[n * 9 + 2];
    const float V10 = Vmat[n * 9 + 3], V11 = Vmat[n * 9 + 4], V12 = Vmat[n * 9 + 5];
    const float V20 = Vmat[n * 9 + 6], V21 = Vmat[n * 9 + 7], V22 = Vmat[n * 9 + 8];
    float g[NBASIS];
#pragma unroll
    for (int b = 0; b < NBASIS; ++b) g[b] = 0.f;
    for (int k = 0; k < KNN; ++k) {
      const unsigned j = idx[n * KNN + k];
      const float4 pj = pos4[j];                    // 1 dwordx4 vs 3 dwords
      const float lx = pj.x - cx;
      const float ly = pj.y - cy;
      const float lz = pj.z - cz;
      const float X  = lx * V00 + ly * V10 + lz * V20;
      const float Y  = lx * V01 + ly * V11 + lz * V21;
      const float Zc = lx * V02 + ly * V12 + lz * V22;
      const float r = sqrtf(((X * X + Y * Y) + Zc * Zc) + 1e-8f);
      float u = Zc / r;
      u = fminf(fmaxf(u, -0.999999f), 0.999999f);
      const float ct1 = u, ct2 = 2.f * u * u - 1.f;
      const float rho2 = X * X + Y * Y;
      const float cp1 = (rho2 > 0.f) ? (X / sqrtf(rho2)) : 1.f;
      const float cp2 = 2.f * cp1 * cp1 - 1.f;
      const float f = chan[(size_t)j * 64 + lane];
      const float pr1 = r, pr2 = r * r;
      float tc[9];
      tc[0] = 1.f; tc[1] = cp1; tc[2] = cp2;
      tc[3] = ct1; tc[4] = ct1 * cp1; tc[5] = ct1 * cp2;
      tc[6] = ct2; tc[7] = ct2 * cp1; tc[8] = ct2 * cp2;
#pragma unroll
      for (int m9 = 0; m9 < 9; ++m9) {
        g[m9]      = __builtin_fmaf(tc[m9],       f, g[m9]);
        g[9 + m9]  = __builtin_fmaf(pr1 * tc[m9], f, g[9 + m9]);
        g[18 + m9] = __builtin_fmaf(pr2 * tc[m9], f, g[18 + m9]);
      }
    }
#pragma unroll
    for (int b = 0; b < NBASIS; ++b) G[wave][b][lane] = g[b];
  }
  __syncthreads();

  float acc0 = 0.f;
  for (int b = 0; b < NBASIS; ++b) {
    const float4* g0p = (const float4*)(&G[wave][b][0]);   // broadcast reads
    const float* cp = coeff + (size_t)(b * 64) * 64 + lane;
#pragma unroll 4
    for (int i4 = 0; i4 < 16; ++i4) {
      const float4 g0 = g0p[i4];
      const float c0 = cp[(i4 * 4 + 0) * 64];
      const float c1 = cp[(i4 * 4 + 1) * 64];
      const float c2 = cp[(i4 * 4 + 2) * 64];
      const float c3 = cp[(i4 * 4 + 3) * 64];
      acc0 = __builtin_fmaf(c0, g0.x, acc0);
      acc0 = __builtin_fmaf(c1, g0.y, acc0);
      acc0 = __builtin_fmaf(c2, g0.z, acc0);
      acc0 = __builtin_fmaf(c3, g0.w, acc0);
    }
  }
  __syncthreads();
  Tsh[wave][lane] = acc0 * 0.03125f;
  __syncthreads();
  {
    const int o = tid >> 2, nn = tid & 3;             // 256 threads = 4 pts x 64 outs
    out[(size_t)o * NPOINTS + (n0 + nn)] = Tsh[nn][o];
  }
}

// ===================== launch =====================
extern "C" void kernel_launch(void* const* d_in, const int* in_sizes, int n_in,
                              void* d_out, int out_size, void* d_ws, size_t ws_size,
                              hipStream_t stream) {
  (void)in_sizes; (void)n_in; (void)out_size; (void)ws_size;
  const float* pos   = (const float*)d_in[0];
  const float* chan  = (const float*)d_in[1];
  const float* coeff = (const float*)d_in[2];
  float* out = (float*)d_out;
  unsigned char* ws = (unsigned char*)d_ws;
  float4*   pos4   = (float4*)(ws);                                    // 256 KiB
  unsigned* idx    = (unsigned*)(ws + (size_t)NPOINTS * 16);           // 2 MiB
  float*    center = (float*)(ws + (size_t)NPOINTS * 16 + (size_t)NPOINTS * KNN * 4);          // 192 KiB
  float*    Vmat   = (float*)(ws + (size_t)NPOINTS * 16 + (size_t)NPOINTS * KNN * 4
                              + (size_t)NPOINTS * 12);                 // 576 KiB
  hipLaunchKernelGGL(pack_kernel, dim3(NPOINTS / 256),         dim3(256), 0, stream, pos, pos4);
  hipLaunchKernelGGL(knn_kernel,  dim3(NPOINTS / (WPB * RPW)), dim3(256), 0, stream, pos4, idx);
  hipLaunchKernelGGL(pca_kernel,  dim3(NPOINTS / 256),         dim3(256), 0, stream, pos4, idx, center, Vmat);
  hipLaunchKernelGGL(conv_kernel, dim3(NPOINTS / NT),          dim3(256), 0, stream, pos4, chan, coeff, idx, center, Vmat, out);
}

// Round 16
// 690.781 us; speedup vs baseline: 1.5662x; 1.1330x over previous
//
#include <hip/hip_runtime.h>
#include <math.h>

#define NPOINTS 16384
#define KNN     32
#define NBASIS  27

typedef unsigned long long ull;

// ===================== helpers =====================

__device__ __forceinline__ unsigned fkey(float f) {
  // monotone order-preserving map fp32 -> uint32 (3 VALU: ashr, or, xor)
  unsigned u = __float_as_uint(f);
  unsigned m = (unsigned)((int)u >> 31) | 0x80000000u;
  return u ^ m;
}

__device__ __forceinline__ ull shflx64(ull v, int mask) {
  int lo = __shfl_xor((int)(unsigned)(v & 0xFFFFFFFFULL), mask, 64);
  int hi = __shfl_xor((int)(unsigned)(v >> 32), mask, 64);
  return ((ull)(unsigned)hi << 32) | (ull)(unsigned)lo;
}

// count of set bits in m strictly below this lane (2 VALU)
__device__ __forceinline__ unsigned prefix64(ull m) {
  return __builtin_amdgcn_mbcnt_hi((unsigned)(m >> 32),
         __builtin_amdgcn_mbcnt_lo((unsigned)m, 0u));
}

// ===================== faithful ssyevd(3x3) port (double arith, fp32 eps) ============

__device__ __forceinline__ void slartg_dev(double f, double g, double* c, double* s, double* r) {
#pragma clang fp contract(off)
  // LAPACK >= 3.10 convention (c >= 0)
  if (g == 0.0) { *c = 1.0; *s = 0.0; *r = f; }
  else if (f == 0.0) { *c = 0.0; *s = (g >= 0.0 ? 1.0 : -1.0); *r = fabs(g); }
  else {
    double d = sqrt(f * f + g * g);
    *c = fabs(f) / d;
    *r = (f >= 0.0) ? d : -d;
    *s = g / (*r);
  }
}

__device__ __forceinline__ void slaev2_dev(double a, double b, double c,
                                           double* rt1, double* rt2, double* cs1, double* sn1) {
#pragma clang fp contract(off)
  double sm = a + c, df = a - c, adf = fabs(df), tb = b + b, ab = fabs(tb);
  double acmx, acmn;
  if (fabs(a) > fabs(c)) { acmx = a; acmn = c; } else { acmx = c; acmn = a; }
  double rt;
  if (adf > ab)      rt = adf * sqrt(1.0 + (ab / adf) * (ab / adf));
  else if (adf < ab) rt = ab * sqrt(1.0 + (adf / ab) * (adf / ab));
  else               rt = ab * sqrt(2.0);
  int sgn1;
  if (sm < 0.0) { *rt1 = 0.5 * (sm - rt); sgn1 = -1; *rt2 = (acmx / *rt1) * acmn - (b / *rt1) * b; }
  else if (sm > 0.0) { *rt1 = 0.5 * (sm + rt); sgn1 = 1; *rt2 = (acmx / *rt1) * acmn - (b / *rt1) * b; }
  else { *rt1 = 0.5 * rt; *rt2 = -0.5 * rt; sgn1 = 1; }
  int sgn2; double cs;
  if (df >= 0.0) { cs = df + rt; sgn2 = 1; } else { cs = df - rt; sgn2 = -1; }
  double acs = fabs(cs);
  if (acs > ab) { double ct = -tb / cs; double sn = 1.0 / sqrt(1.0 + ct * ct); *sn1 = sn; *cs1 = ct * sn; }
  else {
    if (ab == 0.0) { *cs1 = 1.0; *sn1 = 0.0; }
    else { double tn = -cs / tb; double c1 = 1.0 / sqrt(1.0 + tn * tn); *cs1 = c1; *sn1 = tn * c1; }
  }
  if (sgn1 == sgn2) { double tn = *cs1; *cs1 = -(*sn1); *sn1 = tn; }
}

// Input: lower triangle of symmetric 3x3 (fp32 cov). Output: V columns in DESCENDING
// eigenvalue order (LAPACK ascending, reversed) = np/jnp eigh + [:, :, ::-1].
__device__ void eigh3(float A00, float A10, float A20, float A11, float A21, float A22,
                      float V[3][3]) {
#pragma clang fp contract(off)
  const double EPS    = 5.9604644775390625e-08;   // fp32 slamch('E')
  const double EPS2   = EPS * EPS;
  const double SAFMIN = 1.1754943508222875e-38;   // fp32 slamch('S')
  double d[3], e[2];
  double tau = 0.0, v2 = 0.0;
  // ---- ssytd2 (uplo='L'), single Householder on [A10; A20]
  {
    double alpha = (double)A10, x = (double)A20;
    double a11 = (double)A11, a21 = (double)A21, a22 = (double)A22;
    double beta;
    if (x == 0.0) { tau = 0.0; v2 = 0.0; beta = alpha; }
    else {
      double nrm = sqrt(alpha * alpha + x * x);          // slapy2
      beta = (alpha >= 0.0) ? -nrm : nrm;                // -sign(nrm, alpha)
      tau = (beta - alpha) / beta;
      v2 = x / (alpha - beta);
    }
    if (tau != 0.0) {
      double w0 = tau * (a11 + a21 * v2);
      double w1 = tau * (a21 + a22 * v2);
      double cc = 0.5 * tau * (w0 + w1 * v2);
      w0 -= cc; w1 -= cc * v2;
      a11 -= 2.0 * w0;
      a21 -= (v2 * w0 + w1);
      a22 -= 2.0 * v2 * w1;
    }
    d[0] = (double)A00; d[1] = a11; d[2] = a22;
    e[0] = beta; e[1] = a21;
  }
  double Z[3][3] = { {1.0, 0.0, 0.0}, {0.0, 1.0, 0.0}, {0.0, 0.0, 1.0} };
  // ---- ssteqr('I', n=3)
  {
    int l1 = 1, jtot = 0;
    const int nmaxit = 90;
    double wc[2], wsn[2];
    while (l1 <= 3) {
      if (l1 > 1) e[l1 - 2] = 0.0;
      int m = 3;
      for (int mm = l1; mm <= 2; ++mm) {
        double tst = fabs(e[mm - 1]);
        if (tst == 0.0) { m = mm; break; }
        if (tst <= (sqrt(fabs(d[mm - 1])) * sqrt(fabs(d[mm]))) * EPS) { e[mm - 1] = 0.0; m = mm; break; }
      }
      int l = l1, lsv = l, lend = m, lendsv = lend;
      l1 = m + 1;
      if (lend == l) continue;
      double anorm = 0.0;
      for (int i = l; i <= lend; ++i)     anorm = fmax(anorm, fabs(d[i - 1]));
      for (int i = l; i <= lend - 1; ++i) anorm = fmax(anorm, fabs(e[i - 1]));
      if (anorm == 0.0) continue;
      if (fabs(d[lend - 1]) < fabs(d[l - 1])) { lend = lsv; l = lendsv; }
      if (lend > l) {
        // ===== QL =====
        bool done = false;
        while (!done) {
          int mq = lend;
          for (int mm = l; mm <= lend - 1; ++mm) {
            double tst = e[mm - 1] * e[mm - 1];
            if (tst <= (EPS2 * fabs(d[mm - 1])) * fabs(d[mm]) + SAFMIN) { mq = mm; break; }
          }
          if (mq < lend) e[mq - 1] = 0.0;
          double p = d[l - 1];
          if (mq == l) { d[l - 1] = p; ++l; if (l > lend) done = true; continue; }
          if (mq == l + 1) {
            double rt1, rt2, cc, ssn;
            slaev2_dev(d[l - 1], e[l - 1], d[l], &rt1, &rt2, &cc, &ssn);
            for (int i = 0; i < 3; ++i) {
              double t = Z[i][l];
              Z[i][l]     = cc * t - ssn * Z[i][l - 1];
              Z[i][l - 1] = ssn * t + cc * Z[i][l - 1];
            }
            d[l - 1] = rt1; d[l] = rt2; e[l - 1] = 0.0;
            l += 2; if (l > lend) done = true; continue;
          }
          if (jtot >= nmaxit) break;
          ++jtot;
          double g = (d[l] - p) / (2.0 * e[l - 1]);
          double r = sqrt(g * g + 1.0);
          g = d[mq - 1] - p + e[l - 1] / (g + ((g >= 0.0) ? r : -r));
          double ssn = 1.0, cc = 1.0;
          p = 0.0;
          for (int i = mq - 1; i >= l; --i) {
            double f = ssn * e[i - 1], b = cc * e[i - 1];
            slartg_dev(g, f, &cc, &ssn, &r);
            if (i != mq - 1) e[i] = r;
            g = d[i] - p;
            r = (d[i - 1] - g) * ssn + 2.0 * cc * b;
            p = ssn * r;
            d[i] = g + p;
            g = cc * r - b;
            wc[i - 1] = cc; wsn[i - 1] = -ssn;
          }
          for (int j = mq - 1; j >= l; --j) {
            double cj = wc[j - 1], sj = wsn[j - 1];
            for (int i = 0; i < 3; ++i) {
              double t = Z[i][j];
              Z[i][j]     = cj * t - sj * Z[i][j - 1];
              Z[i][j - 1] = sj * t + cj * Z[i][j - 1];
            }
          }
          d[l - 1] -= p; e[l - 1] = g;
        }
      } else {
        // ===== QR =====
        bool done = false;
        while (!done) {
          int mq = lend;
          for (int mm = l; mm >= lend + 1; --mm) {
            double tst = e[mm - 2] * e[mm - 2];
            if (tst <= (EPS2 * fabs(d[mm - 1])) * fabs(d[mm - 2]) + SAFMIN) { mq = mm; break; }
          }
          if (mq > lend) e[mq - 2] = 0.0;
          double p = d[l - 1];
          if (mq == l) { d[l - 1] = p; --l; if (l < lend) done = true; continue; }
          if (mq == l - 1) {
            double rt1, rt2, cc, ssn;
            slaev2_dev(d[l - 2], e[l - 2], d[l - 1], &rt1, &rt2, &cc, &ssn);
            for (int i = 0; i < 3; ++i) {
              double t = Z[i][l - 1];
              Z[i][l - 1] = cc * t - ssn * Z[i][l - 2];
              Z[i][l - 2] = ssn * t + cc * Z[i][l - 2];
            }
            d[l - 2] = rt1; d[l - 1] = rt2; e[l - 2] = 0.0;
            l -= 2; if (l < lend) done = true; continue;
          }
          if (jtot >= nmaxit) break;
          ++jtot;
          double g = (d[l - 2] - p) / (2.0 * e[l - 2]);
          double r = sqrt(g * g + 1.0);
          g = d[mq - 1] - p + e[l - 2] / (g + ((g >= 0.0) ? r : -r));
          double ssn = 1.0, cc = 1.0;
          p = 0.0;
          for (int i = mq; i <= l - 1; ++i) {
            double f = ssn * e[i - 1], b = cc * e[i - 1];
            slartg_dev(g, f, &cc, &ssn, &r);
            if (i != mq) e[i - 2] = r;
            g = d[i - 1] - p;
            r = (d[i] - g) * ssn + 2.0 * cc * b;
            p = ssn * r;
            d[i - 1] = g + p;
            g = cc * r - b;
            wc[i - 1] = cc; wsn[i - 1] = ssn;
          }
          for (int j = mq; j <= l - 1; ++j) {
            double cj = wc[j - 1], sj = wsn[j - 1];
            for (int i = 0; i < 3; ++i) {
              double t = Z[i][j];
              Z[i][j]     = cj * t - sj * Z[i][j - 1];
              Z[i][j - 1] = sj * t + cj * Z[i][j - 1];
            }
          }
          d[l - 1] -= p; e[l - 2] = g;
        }
      }
    }
    // ---- ascending selection sort with column swaps (as in ssteqr)
    for (int ii = 2; ii <= 3; ++ii) {
      int i0 = ii - 1, k = i0;
      double p = d[i0 - 1];
      for (int j = ii; j <= 3; ++j) if (d[j - 1] < p) { k = j; p = d[j - 1]; }
      if (k != i0) {
        d[k - 1] = d[i0 - 1]; d[i0 - 1] = p;
        for (int rr = 0; rr < 3; ++rr) { double t = Z[rr][i0 - 1]; Z[rr][i0 - 1] = Z[rr][k - 1]; Z[rr][k - 1] = t; }
      }
    }
  }
  // ---- sormtr: Z := H1 * Z
  if (tau != 0.0) {
    for (int j = 0; j < 3; ++j) {
      double w = Z[1][j] + v2 * Z[2][j];
      Z[1][j] -= tau * w;
      Z[2][j] -= tau * v2 * w;
    }
  }
  for (int i = 0; i < 3; ++i)
    for (int j = 0; j < 3; ++j)
      V[i][j] = (float)Z[i][2 - j];
}

// ===================== kernel 0: pack pos -> float4 {x,y,z,sq} =====================
__global__ __launch_bounds__(256) void pack_kernel(const float* __restrict__ pos,
                                                   float4* __restrict__ pos4) {
#pragma clang fp contract(off)
  int i = blockIdx.x * 256 + threadIdx.x;
  if (i < NPOINTS) {
    float x = pos[3 * i + 0], y = pos[3 * i + 1], z = pos[3 * i + 2];
    float sq = (x * x + y * y) + z * z;   // XLA reduce order (same as r6)
    pos4[i] = make_float4(x, y, z, sq);
  }
}

// ===================== kernel 1: exact KNN, RPW=2 + dual-min chains ============
// Order: C = (fkey(d2) << 32) | (0xFFFFFFFF - idx). 32 smallest C == r6-verified
// semantics (key asc, ties -> HIGHER index first). Chain-A d2 unchanged.
// r16: RPW 4->2 doubles grid (2048 blocks, 8/CU; LDS 18KB -> occupancy cap 100%).
// Dual even/odd min accumulators break the 256-deep fminf dependency chain
// (exact: min is associative; merged lane-min identical -> same threshold).
#define WPB  4    // waves per block
#define RPW  2    // rows per wave -> 8 rows per block
#define TPTS 512  // tile points (8 KB)
#define NTIL (NPOINTS / TPTS)
#define CAP  128  // candidate capacity per row (E[cnt]~44; serial fallback kept)

__global__ __launch_bounds__(256) void knn_kernel(const float4* __restrict__ pos4,
                                                  unsigned* __restrict__ idx_out) {
#pragma clang fp contract(off)
  __shared__ float4 tile[TPTS];            // 8 KB
  __shared__ ull cand[WPB][RPW][CAP];      // 8 KB
  __shared__ ull sel[WPB][RPW][KNN];       // 2 KB
  const int tid  = threadIdx.x;
  const int lane = tid & 63;
  const int wave = tid >> 6;
  const int rowbase = (blockIdx.x * WPB + wave) * RPW;
  const float INF = __int_as_float(0x7f800000);

  float rx[RPW], ry[RPW], rz[RPW], rq[RPW];
#pragma unroll
  for (int r = 0; r < RPW; ++r) {
    const float4 rp = pos4[rowbase + r];
    rx[r] = rp.x; ry[r] = rp.y; rz[r] = rp.z; rq[r] = rp.w;
  }

  // named prefetch registers (rule #20: NO arrays)
  float4 s0 = pos4[0 * 256 + tid];
  float4 s1 = pos4[1 * 256 + tid];

  // ---- phase A: per-lane MIN d2, dual chains (even/odd chunk) ----
  float ka[RPW], kb[RPW];
#pragma unroll
  for (int r = 0; r < RPW; ++r) { ka[r] = INF; kb[r] = INF; }
  for (int t = 0; t < NTIL; ++t) {
    __syncthreads();                       // prior tile fully consumed (r2 lesson)
    tile[0 * 256 + tid] = s0;
    tile[1 * 256 + tid] = s1;
    __syncthreads();
    if (t + 1 < NTIL) {
      const int base = (t + 1) * TPTS + tid;
      s0 = pos4[base + 0 * 256];
      s1 = pos4[base + 1 * 256];           // in flight across the compute below
    }
#pragma unroll 2
    for (int ch = 0; ch < TPTS / 64; ch += 2) {
      const float4 p0 = tile[ch * 64 + lane];
      const float4 p1 = tile[(ch + 1) * 64 + lane];
#pragma unroll
      for (int r = 0; r < RPW; ++r) {
        const float md0 = __builtin_fmaf(rz[r], p0.z, __builtin_fmaf(ry[r], p0.y, rx[r] * p0.x));
        const float d20 = (rq[r] + p0.w) - 2.0f * md0;
        ka[r] = fminf(ka[r], d20);
        const float md1 = __builtin_fmaf(rz[r], p1.z, __builtin_fmaf(ry[r], p1.y, rx[r] * p1.x));
        const float d21 = (rq[r] + p1.w) - 2.0f * md1;
        kb[r] = fminf(kb[r], d21);
      }
    }
  }

  // ---- per-row float threshold Tt = 32nd smallest of the 64 lane minima ----
  // Certified: <=31 global values strictly < T32, each in one lane => Tt >= T32.
  float Ttf[RPW];
#pragma unroll
  for (int r = 0; r < RPW; ++r) {
    float k1f = fminf(ka[r], kb[r]);       // exact lane-min (min associative)
    int head = 0;
    float T = 0.f;
    for (int it = 0; it < KNN; ++it) {
      float v = (head == 0) ? k1f : INF;
      float m = v;
      for (int off = 1; off < 64; off <<= 1) {
        float o = __shfl_xor(m, off, 64);
        m = fminf(m, o);
      }
      ull win = __ballot(v == m);
      int wl = __ffsll((long long)win) - 1;
      if (lane == wl) ++head;
      T = m;
    }
    Ttf[r] = T;
  }

  // ---- phase B: compact candidates with d2 <= Ttf per row (tiled + named prefetch) ----
  s0 = pos4[0 * 256 + tid];
  s1 = pos4[1 * 256 + tid];
  unsigned cnt[RPW];
#pragma unroll
  for (int r = 0; r < RPW; ++r) cnt[r] = 0;
  for (int t = 0; t < NTIL; ++t) {
    __syncthreads();
    tile[0 * 256 + tid] = s0;
    tile[1 * 256 + tid] = s1;
    __syncthreads();
    if (t + 1 < NTIL) {
      const int base = (t + 1) * TPTS + tid;
      s0 = pos4[base + 0 * 256];
      s1 = pos4[base + 1 * 256];
    }
#pragma unroll 2
    for (int ch = 0; ch < TPTS / 64; ++ch) {
      const int j = t * TPTS + ch * 64 + lane;
      const float4 p = tile[ch * 64 + lane];
#pragma unroll
      for (int r = 0; r < RPW; ++r) {
        const float mdot = __builtin_fmaf(rz[r], p.z, __builtin_fmaf(ry[r], p.y, rx[r] * p.x));
        const float d2 = (rq[r] + p.w) - 2.0f * mdot;
        const bool c = (d2 <= Ttf[r]);
        const ull m = __ballot(c);
        if (c) {
          unsigned slot = cnt[r] + prefix64(m);
          if (slot < CAP)
            cand[wave][r][slot] = ((ull)fkey(d2) << 32) | (ull)(0xFFFFFFFFu - (unsigned)j);
        }
        cnt[r] += (unsigned)__popcll(m);
      }
    }
  }
  __builtin_amdgcn_s_waitcnt(0);   // drain our ds_writes (wave-private region)

#pragma unroll
  for (int r = 0; r < RPW; ++r) {
    if (cnt[r] <= (unsigned)CAP) {
      // exact wave-parallel extraction of 32 smallest C from <=128 candidates
      ull c0 = (lane < (int)cnt[r]) ? cand[wave][r][lane] : ~0ULL;
      ull c1 = ((lane + 64) < (int)cnt[r]) ? cand[wave][r][lane + 64] : ~0ULL;
      ull lo = (c0 < c1) ? c0 : c1;
      ull hi = (c0 < c1) ? c1 : c0;
      int head = 0;
      for (int it = 0; it < KNN; ++it) {
        ull v = (head == 0) ? lo : ((head == 1) ? hi : ~0ULL);
        ull m = v;
        for (int off = 1; off < 64; off <<= 1) {
          ull o = shflx64(m, off);
          m = (o < m) ? o : m;
        }
        ull win = __ballot(v == m);
        int wl = __ffsll((long long)win) - 1;
        if (lane == wl) ++head;
        if (lane == 0) sel[wave][r][it] = m;
      }
    } else {
      // exact serial fallback (probability ~0)
      if (lane == 0) {
        int n2 = 0;
        for (int j = 0; j < NPOINTS; ++j) {
          const float4 p = pos4[j];
          const float mdot = __builtin_fmaf(rz[r], p.z, __builtin_fmaf(ry[r], p.y, rx[r] * p.x));
          const float d2 = (rq[r] + p.w) - 2.0f * mdot;
          const unsigned key = fkey(d2);
          const ull C = ((ull)key << 32) | (ull)(0xFFFFFFFFu - (unsigned)j);
          if (n2 < KNN) {
            int b = n2 - 1;
            while (b >= 0 && sel[wave][r][b] > C) { sel[wave][r][b + 1] = sel[wave][r][b]; --b; }
            sel[wave][r][b + 1] = C;
            ++n2;
          } else if (C < sel[wave][r][KNN - 1]) {
            int b = KNN - 2;
            while (b >= 0 && sel[wave][r][b] > C) { sel[wave][r][b + 1] = sel[wave][r][b]; --b; }
            sel[wave][r][b + 1] = C;
          }
        }
      }
    }
  }
  __builtin_amdgcn_s_waitcnt(0);

  // finalize (lane 0): C-ascending == (key asc, idx desc). Emission wants
  // (key asc, idx asc): reverse idx within bit-equal-key runs only (rare).
  if (lane == 0) {
#pragma unroll
    for (int r = 0; r < RPW; ++r) {
      unsigned kk[KNN], ii[KNN];
      for (int a = 0; a < KNN; ++a) {
        ull C = sel[wave][r][a];
        kk[a] = (unsigned)(C >> 32);
        ii[a] = 0xFFFFFFFFu - (unsigned)(C & 0xFFFFFFFFULL);
      }
      int a = 0;
      while (a < KNN) {
        int b = a;
        while (b + 1 < KNN && kk[b + 1] == kk[a]) ++b;
        for (int x = a, y = b; x < y; ++x, --y) { unsigned tmp = ii[x]; ii[x] = ii[y]; ii[y] = tmp; }
        a = b + 1;
      }
      unsigned ob = (unsigned)(rowbase + r) * KNN;
      for (int q = 0; q < KNN; ++q) idx_out[ob + q] = ii[q];
    }
  }
}

// ===================== kernel 2: mean + cov + eigh per point (fp32) =====================
__global__ __launch_bounds__(256) void pca_kernel(const float4* __restrict__ pos4,
                                                  const unsigned* __restrict__ idx,
                                                  float* __restrict__ center,
                                                  float* __restrict__ Vmat) {
#pragma clang fp contract(off)
  int n = blockIdx.x * 256 + threadIdx.x;
  if (n >= NPOINTS) return;
  float sx = 0.f, sy = 0.f, sz = 0.f;
  for (int k = 0; k < KNN; ++k) {
    unsigned j = idx[n * KNN + k];
    const float4 p = pos4[j];
    sx += p.x; sy += p.y; sz += p.z;
  }
  float cx = sx * 0.03125f, cy = sy * 0.03125f, cz = sz * 0.03125f;
  float c00 = 0.f, c10 = 0.f, c20 = 0.f, c11 = 0.f, c21 = 0.f, c22 = 0.f;
  for (int k = 0; k < KNN; ++k) {
    unsigned j = idx[n * KNN + k];
    const float4 p = pos4[j];
    float lx = p.x - cx;
    float ly = p.y - cy;
    float lz = p.z - cz;
    c00 += lx * lx; c10 += lx * ly; c20 += lx * lz;
    c11 += ly * ly; c21 += ly * lz; c22 += lz * lz;
  }
  c00 *= 0.03125f; c10 *= 0.03125f; c20 *= 0.03125f;
  c11 *= 0.03125f; c21 *= 0.03125f; c22 *= 0.03125f;
  float V[3][3];
  eigh3(c00, c10, c20, c11, c21, c22, V);
  center[n * 3 + 0] = cx; center[n * 3 + 1] = cy; center[n * 3 + 2] = cz;
  for (int i = 0; i < 3; ++i)
    for (int j2 = 0; j2 < 3; ++j2)
      Vmat[n * 9 + i * 3 + j2] = V[i][j2];
}

// ===================== kernel 3: basis + G[b,i] + 27x (64x64) matmuls ================
// NT=4 (one point per wave), LDS 28KB => 5 blocks/CU.
#define NT 4
__global__ __launch_bounds__(256) void conv_kernel(const float4* __restrict__ pos4,
                                                   const float* __restrict__ chan,
                                                   const float* __restrict__ coeff,
                                                   const unsigned* __restrict__ idx,
                                                   const float* __restrict__ center,
                                                   const float* __restrict__ Vmat,
                                                   float* __restrict__ out) {
#pragma clang fp contract(off)
  __shared__ float G[NT][NBASIS][64];      // 27 KB
  __shared__ float Tsh[NT][64];            // 1 KB
  const int tid  = threadIdx.x;
  const int lane = tid & 63;
  const int wave = tid >> 6;
  const int n0 = blockIdx.x * NT;
  const int n  = n0 + wave;

  {
    const float cx = center[n * 3 + 0], cy = center[n * 3 + 1], cz = center[n * 3 + 2];
    const float V00 = Vmat[n * 9 + 0], V01 = Vmat[n * 9 + 1], V02 = Vmat[n * 9 + 2];
    const float V10 = Vmat[n * 9 + 3], V11 = Vmat[n * 9 + 4], V12 = Vmat[n * 9 + 5];
    const float V20 = Vmat[n * 9 + 6], V21 = Vmat[n * 9 + 7], V22 = Vmat[n * 9 + 8];
    float g[NBASIS];
#pragma unroll
    for (int b = 0; b < NBASIS; ++b) g[b] = 0.f;
    for (int k = 0; k < KNN; ++k) {
      const unsigned j = idx[n * KNN + k];
      const float4 pj = pos4[j];                    // 1 dwordx4 vs 3 dwords
      const float lx = pj.x - cx;
      const float ly = pj.y - cy;
      const float lz = pj.z - cz;
      const float X  = lx * V00 + ly * V10 + lz * V20;
      const float Y  = lx * V01 + ly * V11 + lz * V21;
      const float Zc = lx * V02 + ly * V12 + lz * V22;
      const float r = sqrtf(((X * X + Y * Y) + Zc * Zc) + 1e-8f);
      float u = Zc / r;
      u = fminf(fmaxf(u, -0.999999f), 0.999999f);
      const float ct1 = u, ct2 = 2.f * u * u - 1.f;
      const float rho2 = X * X + Y * Y;
      const float cp1 = (rho2 > 0.f) ? (X / sqrtf(rho2)) : 1.f;
      const float cp2 = 2.f * cp1 * cp1 - 1.f;
      const float f = chan[(size_t)j * 64 + lane];
      const float pr1 = r, pr2 = r * r;
      float tc[9];
      tc[0] = 1.f; tc[1] = cp1; tc[2] = cp2;
      tc[3] = ct1; tc[4] = ct1 * cp1; tc[5] = ct1 * cp2;
      tc[6] = ct2; tc[7] = ct2 * cp1; tc[8] = ct2 * cp2;
#pragma unroll
      for (int m9 = 0; m9 < 9; ++m9) {
        g[m9]      = __builtin_fmaf(tc[m9],       f, g[m9]);
        g[9 + m9]  = __builtin_fmaf(pr1 * tc[m9], f, g[9 + m9]);
        g[18 + m9] = __builtin_fmaf(pr2 * tc[m9], f, g[18 + m9]);
      }
    }
#pragma unroll
    for (int b = 0; b < NBASIS; ++b) G[wave][b][lane] = g[b];
  }
  __syncthreads();

  float acc0 = 0.f;
  for (int b = 0; b < NBASIS; ++b) {
    const float4* g0p = (const float4*)(&G[wave][b][0]);   // broadcast reads
    const float* cp = coeff + (size_t)(b * 64) * 64 + lane;
#pragma unroll 4
    for (int i4 = 0; i4 < 16; ++i4) {
      const float4 g0 = g0p[i4];
      const float c0 = cp[(i4 * 4 + 0) * 64];
      const float c1 = cp[(i4 * 4 + 1) * 64];
      const float c2 = cp[(i4 * 4 + 2) * 64];
      const float c3 = cp[(i4 * 4 + 3) * 64];
      acc0 = __builtin_fmaf(c0, g0.x, acc0);
      acc0 = __builtin_fmaf(c1, g0.y, acc0);
      acc0 = __builtin_fmaf(c2, g0.z, acc0);
      acc0 = __builtin_fmaf(c3, g0.w, acc0);
    }
  }
  __syncthreads();
  Tsh[wave][lane] = acc0 * 0.03125f;
  __syncthreads();
  {
    const int o = tid >> 2, nn = tid & 3;             // 256 threads = 4 pts x 64 outs
    out[(size_t)o * NPOINTS + (n0 + nn)] = Tsh[nn][o];
  }
}

// ===================== launch =====================
extern "C" void kernel_launch(void* const* d_in, const int* in_sizes, int n_in,
                              void* d_out, int out_size, void* d_ws, size_t ws_size,
                              hipStream_t stream) {
  (void)in_sizes; (void)n_in; (void)out_size; (void)ws_size;
  const float* pos   = (const float*)d_in[0];
  const float* chan  = (const float*)d_in[1];
  const float* coeff = (const float*)d_in[2];
  float* out = (float*)d_out;
  unsigned char* ws = (unsigned char*)d_ws;
  float4*   pos4   = (float4*)(ws);                                    // 256 KiB
  unsigned* idx    = (unsigned*)(ws + (size_t)NPOINTS * 16);           // 2 MiB
  float*    center = (float*)(ws + (size_t)NPOINTS * 16 + (size_t)NPOINTS * KNN * 4);          // 192 KiB
  float*    Vmat   = (float*)(ws + (size_t)NPOINTS * 16 + (size_t)NPOINTS * KNN * 4
                              + (size_t)NPOINTS * 12);                 // 576 KiB
  hipLaunchKernelGGL(pack_kernel, dim3(NPOINTS / 256),         dim3(256), 0, stream, pos, pos4);
  hipLaunchKernelGGL(knn_kernel,  dim3(NPOINTS / (WPB * RPW)), dim3(256), 0, stream, pos4, idx);
  hipLaunchKernelGGL(pca_kernel,  dim3(NPOINTS / 256),         dim3(256), 0, stream, pos4, idx, center, Vmat);
  hipLaunchKernelGGL(conv_kernel, dim3(NPOINTS / NT),          dim3(256), 0, stream, pos4, chan, coeff, idx, center, Vmat, out);
}

// Round 17
// 683.008 us; speedup vs baseline: 1.5840x; 1.0114x over previous
//
#include <hip/hip_runtime.h>
#include <math.h>

#define NPOINTS 16384
#define KNN     32
#define NBASIS  27

typedef unsigned long long ull;

// ===================== helpers =====================

__device__ __forceinline__ unsigned fkey(float f) {
  // monotone order-preserving map fp32 -> uint32 (3 VALU: ashr, or, xor)
  unsigned u = __float_as_uint(f);
  unsigned m = (unsigned)((int)u >> 31) | 0x80000000u;
  return u ^ m;
}

__device__ __forceinline__ ull shflx64(ull v, int mask) {
  int lo = __shfl_xor((int)(unsigned)(v & 0xFFFFFFFFULL), mask, 64);
  int hi = __shfl_xor((int)(unsigned)(v >> 32), mask, 64);
  return ((ull)(unsigned)hi << 32) | (ull)(unsigned)lo;
}

// count of set bits in m strictly below this lane (2 VALU)
__device__ __forceinline__ unsigned prefix64(ull m) {
  return __builtin_amdgcn_mbcnt_hi((unsigned)(m >> 32),
         __builtin_amdgcn_mbcnt_lo((unsigned)m, 0u));
}

// ===================== faithful ssyevd(3x3) port (double arith, fp32 eps) ============

__device__ __forceinline__ void slartg_dev(double f, double g, double* c, double* s, double* r) {
#pragma clang fp contract(off)
  // LAPACK >= 3.10 convention (c >= 0)
  if (g == 0.0) { *c = 1.0; *s = 0.0; *r = f; }
  else if (f == 0.0) { *c = 0.0; *s = (g >= 0.0 ? 1.0 : -1.0); *r = fabs(g); }
  else {
    double d = sqrt(f * f + g * g);
    *c = fabs(f) / d;
    *r = (f >= 0.0) ? d : -d;
    *s = g / (*r);
  }
}

__device__ __forceinline__ void slaev2_dev(double a, double b, double c,
                                           double* rt1, double* rt2, double* cs1, double* sn1) {
#pragma clang fp contract(off)
  double sm = a + c, df = a - c, adf = fabs(df), tb = b + b, ab = fabs(tb);
  double acmx, acmn;
  if (fabs(a) > fabs(c)) { acmx = a; acmn = c; } else { acmx = c; acmn = a; }
  double rt;
  if (adf > ab)      rt = adf * sqrt(1.0 + (ab / adf) * (ab / adf));
  else if (adf < ab) rt = ab * sqrt(1.0 + (adf / ab) * (adf / ab));
  else               rt = ab * sqrt(2.0);
  int sgn1;
  if (sm < 0.0) { *rt1 = 0.5 * (sm - rt); sgn1 = -1; *rt2 = (acmx / *rt1) * acmn - (b / *rt1) * b; }
  else if (sm > 0.0) { *rt1 = 0.5 * (sm + rt); sgn1 = 1; *rt2 = (acmx / *rt1) * acmn - (b / *rt1) * b; }
  else { *rt1 = 0.5 * rt; *rt2 = -0.5 * rt; sgn1 = 1; }
  int sgn2; double cs;
  if (df >= 0.0) { cs = df + rt; sgn2 = 1; } else { cs = df - rt; sgn2 = -1; }
  double acs = fabs(cs);
  if (acs > ab) { double ct = -tb / cs; double sn = 1.0 / sqrt(1.0 + ct * ct); *sn1 = sn; *cs1 = ct * sn; }
  else {
    if (ab == 0.0) { *cs1 = 1.0; *sn1 = 0.0; }
    else { double tn = -cs / tb; double c1 = 1.0 / sqrt(1.0 + tn * tn); *cs1 = c1; *sn1 = tn * c1; }
  }
  if (sgn1 == sgn2) { double tn = *cs1; *cs1 = -(*sn1); *sn1 = tn; }
}

// Input: lower triangle of symmetric 3x3 (fp32 cov). Output: V columns in DESCENDING
// eigenvalue order (LAPACK ascending, reversed) = np/jnp eigh + [:, :, ::-1].
__device__ void eigh3(float A00, float A10, float A20, float A11, float A21, float A22,
                      float V[3][3]) {
#pragma clang fp contract(off)
  const double EPS    = 5.9604644775390625e-08;   // fp32 slamch('E')
  const double EPS2   = EPS * EPS;
  const double SAFMIN = 1.1754943508222875e-38;   // fp32 slamch('S')
  double d[3], e[2];
  double tau = 0.0, v2 = 0.0;
  // ---- ssytd2 (uplo='L'), single Householder on [A10; A20]
  {
    double alpha = (double)A10, x = (double)A20;
    double a11 = (double)A11, a21 = (double)A21, a22 = (double)A22;
    double beta;
    if (x == 0.0) { tau = 0.0; v2 = 0.0; beta = alpha; }
    else {
      double nrm = sqrt(alpha * alpha + x * x);          // slapy2
      beta = (alpha >= 0.0) ? -nrm : nrm;                // -sign(nrm, alpha)
      tau = (beta - alpha) / beta;
      v2 = x / (alpha - beta);
    }
    if (tau != 0.0) {
      double w0 = tau * (a11 + a21 * v2);
      double w1 = tau * (a21 + a22 * v2);
      double cc = 0.5 * tau * (w0 + w1 * v2);
      w0 -= cc; w1 -= cc * v2;
      a11 -= 2.0 * w0;
      a21 -= (v2 * w0 + w1);
      a22 -= 2.0 * v2 * w1;
    }
    d[0] = (double)A00; d[1] = a11; d[2] = a22;
    e[0] = beta; e[1] = a21;
  }
  double Z[3][3] = { {1.0, 0.0, 0.0}, {0.0, 1.0, 0.0}, {0.0, 0.0, 1.0} };
  // ---- ssteqr('I', n=3)
  {
    int l1 = 1, jtot = 0;
    const int nmaxit = 90;
    double wc[2], wsn[2];
    while (l1 <= 3) {
      if (l1 > 1) e[l1 - 2] = 0.0;
      int m = 3;
      for (int mm = l1; mm <= 2; ++mm) {
        double tst = fabs(e[mm - 1]);
        if (tst == 0.0) { m = mm; break; }
        if (tst <= (sqrt(fabs(d[mm - 1])) * sqrt(fabs(d[mm]))) * EPS) { e[mm - 1] = 0.0; m = mm; break; }
      }
      int l = l1, lsv = l, lend = m, lendsv = lend;
      l1 = m + 1;
      if (lend == l) continue;
      double anorm = 0.0;
      for (int i = l; i <= lend; ++i)     anorm = fmax(anorm, fabs(d[i - 1]));
      for (int i = l; i <= lend - 1; ++i) anorm = fmax(anorm, fabs(e[i - 1]));
      if (anorm == 0.0) continue;
      if (fabs(d[lend - 1]) < fabs(d[l - 1])) { lend = lsv; l = lendsv; }
      if (lend > l) {
        // ===== QL =====
        bool done = false;
        while (!done) {
          int mq = lend;
          for (int mm = l; mm <= lend - 1; ++mm) {
            double tst = e[mm - 1] * e[mm - 1];
            if (tst <= (EPS2 * fabs(d[mm - 1])) * fabs(d[mm]) + SAFMIN) { mq = mm; break; }
          }
          if (mq < lend) e[mq - 1] = 0.0;
          double p = d[l - 1];
          if (mq == l) { d[l - 1] = p; ++l; if (l > lend) done = true; continue; }
          if (mq == l + 1) {
            double rt1, rt2, cc, ssn;
            slaev2_dev(d[l - 1], e[l - 1], d[l], &rt1, &rt2, &cc, &ssn);
            for (int i = 0; i < 3; ++i) {
              double t = Z[i][l];
              Z[i][l]     = cc * t - ssn * Z[i][l - 1];
              Z[i][l - 1] = ssn * t + cc * Z[i][l - 1];
            }
            d[l - 1] = rt1; d[l] = rt2; e[l - 1] = 0.0;
            l += 2; if (l > lend) done = true; continue;
          }
          if (jtot >= nmaxit) break;
          ++jtot;
          double g = (d[l] - p) / (2.0 * e[l - 1]);
          double r = sqrt(g * g + 1.0);
          g = d[mq - 1] - p + e[l - 1] / (g + ((g >= 0.0) ? r : -r));
          double ssn = 1.0, cc = 1.0;
          p = 0.0;
          for (int i = mq - 1; i >= l; --i) {
            double f = ssn * e[i - 1], b = cc * e[i - 1];
            slartg_dev(g, f, &cc, &ssn, &r);
            if (i != mq - 1) e[i] = r;
            g = d[i] - p;
            r = (d[i - 1] - g) * ssn + 2.0 * cc * b;
            p = ssn * r;
            d[i] = g + p;
            g = cc * r - b;
            wc[i - 1] = cc; wsn[i - 1] = -ssn;
          }
          for (int j = mq - 1; j >= l; --j) {
            double cj = wc[j - 1], sj = wsn[j - 1];
            for (int i = 0; i < 3; ++i) {
              double t = Z[i][j];
              Z[i][j]     = cj * t - sj * Z[i][j - 1];
              Z[i][j - 1] = sj * t + cj * Z[i][j - 1];
            }
          }
          d[l - 1] -= p; e[l - 1] = g;
        }
      } else {
        // ===== QR =====
        bool done = false;
        while (!done) {
          int mq = lend;
          for (int mm = l; mm >= lend + 1; --mm) {
            double tst = e[mm - 2] * e[mm - 2];
            if (tst <= (EPS2 * fabs(d[mm - 1])) * fabs(d[mm - 2]) + SAFMIN) { mq = mm; break; }
          }
          if (mq > lend) e[mq - 2] = 0.0;
          double p = d[l - 1];
          if (mq == l) { d[l - 1] = p; --l; if (l < lend) done = true; continue; }
          if (mq == l - 1) {
            double rt1, rt2, cc, ssn;
            slaev2_dev(d[l - 2], e[l - 2], d[l - 1], &rt1, &rt2, &cc, &ssn);
            for (int i = 0; i < 3; ++i) {
              double t = Z[i][l - 1];
              Z[i][l - 1] = cc * t - ssn * Z[i][l - 2];
              Z[i][l - 2] = ssn * t + cc * Z[i][l - 2];
            }
            d[l - 2] = rt1; d[l - 1] = rt2; e[l - 2] = 0.0;
            l -= 2; if (l < lend) done = true; continue;
          }
          if (jtot >= nmaxit) break;
          ++jtot;
          double g = (d[l - 2] - p) / (2.0 * e[l - 2]);
          double r = sqrt(g * g + 1.0);
          g = d[mq - 1] - p + e[l - 2] / (g + ((g >= 0.0) ? r : -r));
          double ssn = 1.0, cc = 1.0;
          p = 0.0;
          for (int i = mq; i <= l - 1; ++i) {
            double f = ssn * e[i - 1], b = cc * e[i - 1];
            slartg_dev(g, f, &cc, &ssn, &r);
            if (i != mq) e[i - 2] = r;
            g = d[i - 1] - p;
            r = (d[i] - g) * ssn + 2.0 * cc * b;
            p = ssn * r;
            d[i - 1] = g + p;
            g = cc * r - b;
            wc[i - 1] = cc; wsn[i - 1] = ssn;
          }
          for (int j = mq; j <= l - 1; ++j) {
            double cj = wc[j - 1], sj = wsn[j - 1];
            for (int i = 0; i < 3; ++i) {
              double t = Z[i][j];
              Z[i][j]     = cj * t - sj * Z[i][j - 1];
              Z[i][j - 1] = sj * t + cj * Z[i][j - 1];
            }
          }
          d[l - 1] -= p; e[l - 2] = g;
        }
      }
    }
    // ---- ascending selection sort with column swaps (as in ssteqr)
    for (int ii = 2; ii <= 3; ++ii) {
      int i0 = ii - 1, k = i0;
      double p = d[i0 - 1];
      for (int j = ii; j <= 3; ++j) if (d[j - 1] < p) { k = j; p = d[j - 1]; }
      if (k != i0) {
        d[k - 1] = d[i0 - 1]; d[i0 - 1] = p;
        for (int rr = 0; rr < 3; ++rr) { double t = Z[rr][i0 - 1]; Z[rr][i0 - 1] = Z[rr][k - 1]; Z[rr][k - 1] = t; }
      }
    }
  }
  // ---- sormtr: Z := H1 * Z
  if (tau != 0.0) {
    for (int j = 0; j < 3; ++j) {
      double w = Z[1][j] + v2 * Z[2][j];
      Z[1][j] -= tau * w;
      Z[2][j] -= tau * v2 * w;
    }
  }
  for (int i = 0; i < 3; ++i)
    for (int j = 0; j < 3; ++j)
      V[i][j] = (float)Z[i][2 - j];
}

// ===================== kernel 0: pack pos -> float4 {x,y,z,sq} =====================
__global__ __launch_bounds__(256) void pack_kernel(const float* __restrict__ pos,
                                                   float4* __restrict__ pos4) {
#pragma clang fp contract(off)
  int i = blockIdx.x * 256 + threadIdx.x;
  if (i < NPOINTS) {
    float x = pos[3 * i + 0], y = pos[3 * i + 1], z = pos[3 * i + 2];
    float sq = (x * x + y * y) + z * z;   // XLA reduce order (same as r6)
    pos4[i] = make_float4(x, y, z, sq);
  }
}

// ===================== kernel 1: exact KNN, RPW=2 + dual-min + any-skip ============
// Order: C = (fkey(d2) << 32) | (0xFFFFFFFF - idx). 32 smallest C == r6-verified
// semantics (key asc, ties -> HIGHER index first). Chain-A d2 unchanged.
// r17: phase B guarded by __any(c0|c1) — when no lane qualifies, m==0 and cnt+=0,
// so skipping the compaction block is EXACTLY equivalent (saves ~20 instr on ~70%).
#define WPB  4    // waves per block
#define RPW  2    // rows per wave -> 8 rows per block
#define TPTS 512  // tile points (8 KB)
#define NTIL (NPOINTS / TPTS)
#define CAP  128  // candidate capacity per row (E[cnt]~44; serial fallback kept)

__global__ __launch_bounds__(256) void knn_kernel(const float4* __restrict__ pos4,
                                                  unsigned* __restrict__ idx_out) {
#pragma clang fp contract(off)
  __shared__ float4 tile[TPTS];            // 8 KB
  __shared__ ull cand[WPB][RPW][CAP];      // 8 KB
  __shared__ ull sel[WPB][RPW][KNN];       // 2 KB
  const int tid  = threadIdx.x;
  const int lane = tid & 63;
  const int wave = tid >> 6;
  const int rowbase = (blockIdx.x * WPB + wave) * RPW;
  const float INF = __int_as_float(0x7f800000);

  float rx[RPW], ry[RPW], rz[RPW], rq[RPW];
#pragma unroll
  for (int r = 0; r < RPW; ++r) {
    const float4 rp = pos4[rowbase + r];
    rx[r] = rp.x; ry[r] = rp.y; rz[r] = rp.z; rq[r] = rp.w;
  }

  // named prefetch registers (rule #20: NO arrays)
  float4 s0 = pos4[0 * 256 + tid];
  float4 s1 = pos4[1 * 256 + tid];

  // ---- phase A: per-lane MIN d2, dual chains (even/odd chunk) ----
  float ka[RPW], kb[RPW];
#pragma unroll
  for (int r = 0; r < RPW; ++r) { ka[r] = INF; kb[r] = INF; }
  for (int t = 0; t < NTIL; ++t) {
    __syncthreads();                       // prior tile fully consumed (r2 lesson)
    tile[0 * 256 + tid] = s0;
    tile[1 * 256 + tid] = s1;
    __syncthreads();
    if (t + 1 < NTIL) {
      const int base = (t + 1) * TPTS + tid;
      s0 = pos4[base + 0 * 256];
      s1 = pos4[base + 1 * 256];           // in flight across the compute below
    }
#pragma unroll 2
    for (int ch = 0; ch < TPTS / 64; ch += 2) {
      const float4 p0 = tile[ch * 64 + lane];
      const float4 p1 = tile[(ch + 1) * 64 + lane];
#pragma unroll
      for (int r = 0; r < RPW; ++r) {
        const float md0 = __builtin_fmaf(rz[r], p0.z, __builtin_fmaf(ry[r], p0.y, rx[r] * p0.x));
        const float d20 = (rq[r] + p0.w) - 2.0f * md0;
        ka[r] = fminf(ka[r], d20);
        const float md1 = __builtin_fmaf(rz[r], p1.z, __builtin_fmaf(ry[r], p1.y, rx[r] * p1.x));
        const float d21 = (rq[r] + p1.w) - 2.0f * md1;
        kb[r] = fminf(kb[r], d21);
      }
    }
  }

  // ---- per-row float threshold Tt = 32nd smallest of the 64 lane minima ----
  // Certified: <=31 global values strictly < T32, each in one lane => Tt >= T32.
  float Ttf[RPW];
#pragma unroll
  for (int r = 0; r < RPW; ++r) {
    float k1f = fminf(ka[r], kb[r]);       // exact lane-min (min associative)
    int head = 0;
    float T = 0.f;
    for (int it = 0; it < KNN; ++it) {
      float v = (head == 0) ? k1f : INF;
      float m = v;
      for (int off = 1; off < 64; off <<= 1) {
        float o = __shfl_xor(m, off, 64);
        m = fminf(m, o);
      }
      ull win = __ballot(v == m);
      int wl = __ffsll((long long)win) - 1;
      if (lane == wl) ++head;
      T = m;
    }
    Ttf[r] = T;
  }

  // ---- phase B: compact candidates with d2 <= Ttf per row (tiled + any-skip) ----
  s0 = pos4[0 * 256 + tid];
  s1 = pos4[1 * 256 + tid];
  unsigned cnt0 = 0, cnt1 = 0;
  const float T0 = Ttf[0], T1 = Ttf[1];
  for (int t = 0; t < NTIL; ++t) {
    __syncthreads();
    tile[0 * 256 + tid] = s0;
    tile[1 * 256 + tid] = s1;
    __syncthreads();
    if (t + 1 < NTIL) {
      const int base = (t + 1) * TPTS + tid;
      s0 = pos4[base + 0 * 256];
      s1 = pos4[base + 1 * 256];
    }
#pragma unroll 2
    for (int ch = 0; ch < TPTS / 64; ++ch) {
      const int j = t * TPTS + ch * 64 + lane;
      const float4 p = tile[ch * 64 + lane];
      const float md0 = __builtin_fmaf(rz[0], p.z, __builtin_fmaf(ry[0], p.y, rx[0] * p.x));
      const float d20 = (rq[0] + p.w) - 2.0f * md0;
      const float md1 = __builtin_fmaf(rz[1], p.z, __builtin_fmaf(ry[1], p.y, rx[1] * p.x));
      const float d21 = (rq[1] + p.w) - 2.0f * md1;
      const bool c0 = (d20 <= T0);
      const bool c1 = (d21 <= T1);
      if (__any(c0 || c1)) {               // exact skip: if false, both m==0, cnt+=0
        const ull m0 = __ballot(c0);
        if (c0) {
          unsigned slot = cnt0 + prefix64(m0);
          if (slot < CAP)
            cand[wave][0][slot] = ((ull)fkey(d20) << 32) | (ull)(0xFFFFFFFFu - (unsigned)j);
        }
        cnt0 += (unsigned)__popcll(m0);
        const ull m1 = __ballot(c1);
        if (c1) {
          unsigned slot = cnt1 + prefix64(m1);
          if (slot < CAP)
            cand[wave][1][slot] = ((ull)fkey(d21) << 32) | (ull)(0xFFFFFFFFu - (unsigned)j);
        }
        cnt1 += (unsigned)__popcll(m1);
      }
    }
  }
  __builtin_amdgcn_s_waitcnt(0);   // drain our ds_writes (wave-private region)

  unsigned cnt[RPW];
  cnt[0] = cnt0; cnt[1] = cnt1;
#pragma unroll
  for (int r = 0; r < RPW; ++r) {
    if (cnt[r] <= (unsigned)CAP) {
      // exact wave-parallel extraction of 32 smallest C from <=128 candidates
      ull c0v = (lane < (int)cnt[r]) ? cand[wave][r][lane] : ~0ULL;
      ull c1v = ((lane + 64) < (int)cnt[r]) ? cand[wave][r][lane + 64] : ~0ULL;
      ull lo = (c0v < c1v) ? c0v : c1v;
      ull hi = (c0v < c1v) ? c1v : c0v;
      int head = 0;
      for (int it = 0; it < KNN; ++it) {
        ull v = (head == 0) ? lo : ((head == 1) ? hi : ~0ULL);
        ull m = v;
        for (int off = 1; off < 64; off <<= 1) {
          ull o = shflx64(m, off);
          m = (o < m) ? o : m;
        }
        ull win = __ballot(v == m);
        int wl = __ffsll((long long)win) - 1;
        if (lane == wl) ++head;
        if (lane == 0) sel[wave][r][it] = m;
      }
    } else {
      // exact serial fallback (probability ~0)
      if (lane == 0) {
        int n2 = 0;
        for (int j = 0; j < NPOINTS; ++j) {
          const float4 p = pos4[j];
          const float mdot = __builtin_fmaf(rz[r], p.z, __builtin_fmaf(ry[r], p.y, rx[r] * p.x));
          const float d2 = (rq[r] + p.w) - 2.0f * mdot;
          const unsigned key = fkey(d2);
          const ull C = ((ull)key << 32) | (ull)(0xFFFFFFFFu - (unsigned)j);
          if (n2 < KNN) {
            int b = n2 - 1;
            while (b >= 0 && sel[wave][r][b] > C) { sel[wave][r][b + 1] = sel[wave][r][b]; --b; }
            sel[wave][r][b + 1] = C;
            ++n2;
          } else if (C < sel[wave][r][KNN - 1]) {
            int b = KNN - 2;
            while (b >= 0 && sel[wave][r][b] > C) { sel[wave][r][b + 1] = sel[wave][r][b]; --b; }
            sel[wave][r][b + 1] = C;
          }
        }
      }
    }
  }
  __builtin_amdgcn_s_waitcnt(0);

  // finalize (lane 0): C-ascending == (key asc, idx desc). Emission wants
  // (key asc, idx asc): reverse idx within bit-equal-key runs only (rare).
  if (lane == 0) {
#pragma unroll
    for (int r = 0; r < RPW; ++r) {
      unsigned kk[KNN], ii[KNN];
      for (int a = 0; a < KNN; ++a) {
        ull C = sel[wave][r][a];
        kk[a] = (unsigned)(C >> 32);
        ii[a] = 0xFFFFFFFFu - (unsigned)(C & 0xFFFFFFFFULL);
      }
      int a = 0;
      while (a < KNN) {
        int b = a;
        while (b + 1 < KNN && kk[b + 1] == kk[a]) ++b;
        for (int x = a, y = b; x < y; ++x, --y) { unsigned tmp = ii[x]; ii[x] = ii[y]; ii[y] = tmp; }
        a = b + 1;
      }
      unsigned ob = (unsigned)(rowbase + r) * KNN;
      for (int q = 0; q < KNN; ++q) idx_out[ob + q] = ii[q];
    }
  }
}

// ===================== kernel 2: mean + cov + eigh per point (fp32) =====================
// r17: 64-thread blocks x 256 blocks -> all 256 CUs busy (was 64 blocks / 64 CUs).
__global__ __launch_bounds__(64) void pca_kernel(const float4* __restrict__ pos4,
                                                 const unsigned* __restrict__ idx,
                                                 float* __restrict__ center,
                                                 float* __restrict__ Vmat) {
#pragma clang fp contract(off)
  int n = blockIdx.x * 64 + threadIdx.x;
  if (n >= NPOINTS) return;
  float sx = 0.f, sy = 0.f, sz = 0.f;
  for (int k = 0; k < KNN; ++k) {
    unsigned j = idx[n * KNN + k];
    const float4 p = pos4[j];
    sx += p.x; sy += p.y; sz += p.z;
  }
  float cx = sx * 0.03125f, cy = sy * 0.03125f, cz = sz * 0.03125f;
  float c00 = 0.f, c10 = 0.f, c20 = 0.f, c11 = 0.f, c21 = 0.f, c22 = 0.f;
  for (int k = 0; k < KNN; ++k) {
    unsigned j = idx[n * KNN + k];
    const float4 p = pos4[j];
    float lx = p.x - cx;
    float ly = p.y - cy;
    float lz = p.z - cz;
    c00 += lx * lx; c10 += lx * ly; c20 += lx * lz;
    c11 += ly * ly; c21 += ly * lz; c22 += lz * lz;
  }
  c00 *= 0.03125f; c10 *= 0.03125f; c20 *= 0.03125f;
  c11 *= 0.03125f; c21 *= 0.03125f; c22 *= 0.03125f;
  float V[3][3];
  eigh3(c00, c10, c20, c11, c21, c22, V);
  center[n * 3 + 0] = cx; center[n * 3 + 1] = cy; center[n * 3 + 2] = cz;
  for (int i = 0; i < 3; ++i)
    for (int j2 = 0; j2 < 3; ++j2)
      Vmat[n * 9 + i * 3 + j2] = V[i][j2];
}

// ===================== kernel 3: basis + G[b,i] + 27x (64x64) matmuls ================
// NT=4 (one point per wave), LDS 28KB => 5 blocks/CU.
#define NT 4
__global__ __launch_bounds__(256) void conv_kernel(const float4* __restrict__ pos4,
                                                   const float* __restrict__ chan,
                                                   const float* __restrict__ coeff,
                                                   const unsigned* __restrict__ idx,
                                                   const float* __restrict__ center,
                                                   const float* __restrict__ Vmat,
                                                   float* __restrict__ out) {
#pragma clang fp contract(off)
  __shared__ float G[NT][NBASIS][64];      // 27 KB
  __shared__ float Tsh[NT][64];            // 1 KB
  const int tid  = threadIdx.x;
  const int lane = tid & 63;
  const int wave = tid >> 6;
  const int n0 = blockIdx.x * NT;
  const int n  = n0 + wave;

  {
    const float cx = center[n * 3 + 0], cy = center[n * 3 + 1], cz = center[n * 3 + 2];
    const float V00 = Vmat[n * 9 + 0], V01 = Vmat[n * 9 + 1], V02 = Vmat[n * 9 + 2];
    const float V10 = Vmat[n * 9 + 3], V11 = Vmat[n * 9 + 4], V12 = Vmat[n * 9 + 5];
    const float V20 = Vmat[n * 9 + 6], V21 = Vmat[n * 9 + 7], V22 = Vmat[n * 9 + 8];
    float g[NBASIS];
#pragma unroll
    for (int b = 0; b < NBASIS; ++b) g[b] = 0.f;
    for (int k = 0; k < KNN; ++k) {
      const unsigned j = idx[n * KNN + k];
      const float4 pj = pos4[j];                    // wave-uniform -> scalar load
      const float lx = pj.x - cx;
      const float ly = pj.y - cy;
      const float lz = pj.z - cz;
      const float X  = lx * V00 + ly * V10 + lz * V20;
      const float Y  = lx * V01 + ly * V11 + lz * V21;
      const float Zc = lx * V02 + ly * V12 + lz * V22;
      const float r = sqrtf(((X * X + Y * Y) + Zc * Zc) + 1e-8f);
      float u = Zc / r;
      u = fminf(fmaxf(u, -0.999999f), 0.999999f);
      const float ct1 = u, ct2 = 2.f * u * u - 1.f;
      const float rho2 = X * X + Y * Y;
      const float cp1 = (rho2 > 0.f) ? (X / sqrtf(rho2)) : 1.f;
      const float cp2 = 2.f * cp1 * cp1 - 1.f;
      const float f = chan[(size_t)j * 64 + lane];
      const float pr1 = r, pr2 = r * r;
      float tc[9];
      tc[0] = 1.f; tc[1] = cp1; tc[2] = cp2;
      tc[3] = ct1; tc[4] = ct1 * cp1; tc[5] = ct1 * cp2;
      tc[6] = ct2; tc[7] = ct2 * cp1; tc[8] = ct2 * cp2;
#pragma unroll
      for (int m9 = 0; m9 < 9; ++m9) {
        g[m9]      = __builtin_fmaf(tc[m9],       f, g[m9]);
        g[9 + m9]  = __builtin_fmaf(pr1 * tc[m9], f, g[9 + m9]);
        g[18 + m9] = __builtin_fmaf(pr2 * tc[m9], f, g[18 + m9]);
      }
    }
#pragma unroll
    for (int b = 0; b < NBASIS; ++b) G[wave][b][lane] = g[b];
  }
  __syncthreads();

  float acc0 = 0.f;
  for (int b = 0; b < NBASIS; ++b) {
    const float4* g0p = (const float4*)(&G[wave][b][0]);   // broadcast reads
    const float* cp = coeff + (size_t)(b * 64) * 64 + lane;
#pragma unroll 4
    for (int i4 = 0; i4 < 16; ++i4) {
      const float4 g0 = g0p[i4];
      const float c0 = cp[(i4 * 4 + 0) * 64];
      const float c1 = cp[(i4 * 4 + 1) * 64];
      const float c2 = cp[(i4 * 4 + 2) * 64];
      const float c3 = cp[(i4 * 4 + 3) * 64];
      acc0 = __builtin_fmaf(c0, g0.x, acc0);
      acc0 = __builtin_fmaf(c1, g0.y, acc0);
      acc0 = __builtin_fmaf(c2, g0.z, acc0);
      acc0 = __builtin_fmaf(c3, g0.w, acc0);
    }
  }
  __syncthreads();
  Tsh[wave][lane] = acc0 * 0.03125f;
  __syncthreads();
  {
    const int o = tid >> 2, nn = tid & 3;             // 256 threads = 4 pts x 64 outs
    out[(size_t)o * NPOINTS + (n0 + nn)] = Tsh[nn][o];
  }
}

// ===================== launch =====================
extern "C" void kernel_launch(void* const* d_in, const int* in_sizes, int n_in,
                              void* d_out, int out_size, void* d_ws, size_t ws_size,
                              hipStream_t stream) {
  (void)in_sizes; (void)n_in; (void)out_size; (void)ws_size;
  const float* pos   = (const float*)d_in[0];
  const float* chan  = (const float*)d_in[1];
  const float* coeff = (const float*)d_in[2];
  float* out = (float*)d_out;
  unsigned char* ws = (unsigned char*)d_ws;
  float4*   pos4   = (float4*)(ws);                                    // 256 KiB
  unsigned* idx    = (unsigned*)(ws + (size_t)NPOINTS * 16);           // 2 MiB
  float*    center = (float*)(ws + (size_t)NPOINTS * 16 + (size_t)NPOINTS * KNN * 4);          // 192 KiB
  float*    Vmat   = (float*)(ws + (size_t)NPOINTS * 16 + (size_t)NPOINTS * KNN * 4
                              + (size_t)NPOINTS * 12);                 // 576 KiB
  hipLaunchKernelGGL(pack_kernel, dim3(NPOINTS / 256),         dim3(256), 0, stream, pos, pos4);
  hipLaunchKernelGGL(knn_kernel,  dim3(NPOINTS / (WPB * RPW)), dim3(256), 0, stream, pos4, idx);
  hipLaunchKernelGGL(pca_kernel,  dim3(NPOINTS / 64),          dim3(64),  0, stream, pos4, idx, center, Vmat);
  hipLaunchKernelGGL(conv_kernel, dim3(NPOINTS / NT),          dim3(256), 0, stream, pos4, chan, coeff, idx, center, Vmat, out);
}

// Round 18
// 614.500 us; speedup vs baseline: 1.7606x; 1.1115x over previous
//
#include <hip/hip_runtime.h>
#include <math.h>

#define NPOINTS 16384
#define KNN     32
#define NBASIS  27

typedef unsigned long long ull;

// ===================== helpers =====================

__device__ __forceinline__ unsigned fkey(float f) {
  // monotone order-preserving map fp32 -> uint32 (3 VALU: ashr, or, xor)
  unsigned u = __float_as_uint(f);
  unsigned m = (unsigned)((int)u >> 31) | 0x80000000u;
  return u ^ m;
}

__device__ __forceinline__ ull shflx64(ull v, int mask) {
  int lo = __shfl_xor((int)(unsigned)(v & 0xFFFFFFFFULL), mask, 64);
  int hi = __shfl_xor((int)(unsigned)(v >> 32), mask, 64);
  return ((ull)(unsigned)hi << 32) | (ull)(unsigned)lo;
}

// count of set bits in m strictly below this lane (2 VALU)
__device__ __forceinline__ unsigned prefix64(ull m) {
  return __builtin_amdgcn_mbcnt_hi((unsigned)(m >> 32),
         __builtin_amdgcn_mbcnt_lo((unsigned)m, 0u));
}

// ===================== faithful ssyevd(3x3) port (double arith, fp32 eps) ============

__device__ __forceinline__ void slartg_dev(double f, double g, double* c, double* s, double* r) {
#pragma clang fp contract(off)
  // LAPACK >= 3.10 convention (c >= 0)
  if (g == 0.0) { *c = 1.0; *s = 0.0; *r = f; }
  else if (f == 0.0) { *c = 0.0; *s = (g >= 0.0 ? 1.0 : -1.0); *r = fabs(g); }
  else {
    double d = sqrt(f * f + g * g);
    *c = fabs(f) / d;
    *r = (f >= 0.0) ? d : -d;
    *s = g / (*r);
  }
}

__device__ __forceinline__ void slaev2_dev(double a, double b, double c,
                                           double* rt1, double* rt2, double* cs1, double* sn1) {
#pragma clang fp contract(off)
  double sm = a + c, df = a - c, adf = fabs(df), tb = b + b, ab = fabs(tb);
  double acmx, acmn;
  if (fabs(a) > fabs(c)) { acmx = a; acmn = c; } else { acmx = c; acmn = a; }
  double rt;
  if (adf > ab)      rt = adf * sqrt(1.0 + (ab / adf) * (ab / adf));
  else if (adf < ab) rt = ab * sqrt(1.0 + (adf / ab) * (adf / ab));
  else               rt = ab * sqrt(2.0);
  int sgn1;
  if (sm < 0.0) { *rt1 = 0.5 * (sm - rt); sgn1 = -1; *rt2 = (acmx / *rt1) * acmn - (b / *rt1) * b; }
  else if (sm > 0.0) { *rt1 = 0.5 * (sm + rt); sgn1 = 1; *rt2 = (acmx / *rt1) * acmn - (b / *rt1) * b; }
  else { *rt1 = 0.5 * rt; *rt2 = -0.5 * rt; sgn1 = 1; }
  int sgn2; double cs;
  if (df >= 0.0) { cs = df + rt; sgn2 = 1; } else { cs = df - rt; sgn2 = -1; }
  double acs = fabs(cs);
  if (acs > ab) { double ct = -tb / cs; double sn = 1.0 / sqrt(1.0 + ct * ct); *sn1 = sn; *cs1 = ct * sn; }
  else {
    if (ab == 0.0) { *cs1 = 1.0; *sn1 = 0.0; }
    else { double tn = -cs / tb; double c1 = 1.0 / sqrt(1.0 + tn * tn); *cs1 = c1; *sn1 = tn * c1; }
  }
  if (sgn1 == sgn2) { double tn = *cs1; *cs1 = -(*sn1); *sn1 = tn; }
}

// Input: lower triangle of symmetric 3x3 (fp32 cov). Output: V columns in DESCENDING
// eigenvalue order (LAPACK ascending, reversed) = np/jnp eigh + [:, :, ::-1].
__device__ void eigh3(float A00, float A10, float A20, float A11, float A21, float A22,
                      float V[3][3]) {
#pragma clang fp contract(off)
  const double EPS    = 5.9604644775390625e-08;   // fp32 slamch('E')
  const double EPS2   = EPS * EPS;
  const double SAFMIN = 1.1754943508222875e-38;   // fp32 slamch('S')
  double d[3], e[2];
  double tau = 0.0, v2 = 0.0;
  // ---- ssytd2 (uplo='L'), single Householder on [A10; A20]
  {
    double alpha = (double)A10, x = (double)A20;
    double a11 = (double)A11, a21 = (double)A21, a22 = (double)A22;
    double beta;
    if (x == 0.0) { tau = 0.0; v2 = 0.0; beta = alpha; }
    else {
      double nrm = sqrt(alpha * alpha + x * x);          // slapy2
      beta = (alpha >= 0.0) ? -nrm : nrm;                // -sign(nrm, alpha)
      tau = (beta - alpha) / beta;
      v2 = x / (alpha - beta);
    }
    if (tau != 0.0) {
      double w0 = tau * (a11 + a21 * v2);
      double w1 = tau * (a21 + a22 * v2);
      double cc = 0.5 * tau * (w0 + w1 * v2);
      w0 -= cc; w1 -= cc * v2;
      a11 -= 2.0 * w0;
      a21 -= (v2 * w0 + w1);
      a22 -= 2.0 * v2 * w1;
    }
    d[0] = (double)A00; d[1] = a11; d[2] = a22;
    e[0] = beta; e[1] = a21;
  }
  double Z[3][3] = { {1.0, 0.0, 0.0}, {0.0, 1.0, 0.0}, {0.0, 0.0, 1.0} };
  // ---- ssteqr('I', n=3)
  {
    int l1 = 1, jtot = 0;
    const int nmaxit = 90;
    double wc[2], wsn[2];
    while (l1 <= 3) {
      if (l1 > 1) e[l1 - 2] = 0.0;
      int m = 3;
      for (int mm = l1; mm <= 2; ++mm) {
        double tst = fabs(e[mm - 1]);
        if (tst == 0.0) { m = mm; break; }
        if (tst <= (sqrt(fabs(d[mm - 1])) * sqrt(fabs(d[mm]))) * EPS) { e[mm - 1] = 0.0; m = mm; break; }
      }
      int l = l1, lsv = l, lend = m, lendsv = lend;
      l1 = m + 1;
      if (lend == l) continue;
      double anorm = 0.0;
      for (int i = l; i <= lend; ++i)     anorm = fmax(anorm, fabs(d[i - 1]));
      for (int i = l; i <= lend - 1; ++i) anorm = fmax(anorm, fabs(e[i - 1]));
      if (anorm == 0.0) continue;
      if (fabs(d[lend - 1]) < fabs(d[l - 1])) { lend = lsv; l = lendsv; }
      if (lend > l) {
        // ===== QL =====
        bool done = false;
        while (!done) {
          int mq = lend;
          for (int mm = l; mm <= lend - 1; ++mm) {
            double tst = e[mm - 1] * e[mm - 1];
            if (tst <= (EPS2 * fabs(d[mm - 1])) * fabs(d[mm]) + SAFMIN) { mq = mm; break; }
          }
          if (mq < lend) e[mq - 1] = 0.0;
          double p = d[l - 1];
          if (mq == l) { d[l - 1] = p; ++l; if (l > lend) done = true; continue; }
          if (mq == l + 1) {
            double rt1, rt2, cc, ssn;
            slaev2_dev(d[l - 1], e[l - 1], d[l], &rt1, &rt2, &cc, &ssn);
            for (int i = 0; i < 3; ++i) {
              double t = Z[i][l];
              Z[i][l]     = cc * t - ssn * Z[i][l - 1];
              Z[i][l - 1] = ssn * t + cc * Z[i][l - 1];
            }
            d[l - 1] = rt1; d[l] = rt2; e[l - 1] = 0.0;
            l += 2; if (l > lend) done = true; continue;
          }
          if (jtot >= nmaxit) break;
          ++jtot;
          double g = (d[l] - p) / (2.0 * e[l - 1]);
          double r = sqrt(g * g + 1.0);
          g = d[mq - 1] - p + e[l - 1] / (g + ((g >= 0.0) ? r : -r));
          double ssn = 1.0, cc = 1.0;
          p = 0.0;
          for (int i = mq - 1; i >= l; --i) {
            double f = ssn * e[i - 1], b = cc * e[i - 1];
            slartg_dev(g, f, &cc, &ssn, &r);
            if (i != mq - 1) e[i] = r;
            g = d[i] - p;
            r = (d[i - 1] - g) * ssn + 2.0 * cc * b;
            p = ssn * r;
            d[i] = g + p;
            g = cc * r - b;
            wc[i - 1] = cc; wsn[i - 1] = -ssn;
          }
          for (int j = mq - 1; j >= l; --j) {
            double cj = wc[j - 1], sj = wsn[j - 1];
            for (int i = 0; i < 3; ++i) {
              double t = Z[i][j];
              Z[i][j]     = cj * t - sj * Z[i][j - 1];
              Z[i][j - 1] = sj * t + cj * Z[i][j - 1];
            }
          }
          d[l - 1] -= p; e[l - 1] = g;
        }
      } else {
        // ===== QR =====
        bool done = false;
        while (!done) {
          int mq = lend;
          for (int mm = l; mm >= lend + 1; --mm) {
            double tst = e[mm - 2] * e[mm - 2];
            if (tst <= (EPS2 * fabs(d[mm - 1])) * fabs(d[mm - 2]) + SAFMIN) { mq = mm; break; }
          }
          if (mq > lend) e[mq - 2] = 0.0;
          double p = d[l - 1];
          if (mq == l) { d[l - 1] = p; --l; if (l < lend) done = true; continue; }
          if (mq == l - 1) {
            double rt1, rt2, cc, ssn;
            slaev2_dev(d[l - 2], e[l - 2], d[l - 1], &rt1, &rt2, &cc, &ssn);
            for (int i = 0; i < 3; ++i) {
              double t = Z[i][l - 1];
              Z[i][l - 1] = cc * t - ssn * Z[i][l - 2];
              Z[i][l - 2] = ssn * t + cc * Z[i][l - 2];
            }
            d[l - 2] = rt1; d[l - 1] = rt2; e[l - 2] = 0.0;
            l -= 2; if (l < lend) done = true; continue;
          }
          if (jtot >= nmaxit) break;
          ++jtot;
          double g = (d[l - 2] - p) / (2.0 * e[l - 2]);
          double r = sqrt(g * g + 1.0);
          g = d[mq - 1] - p + e[l - 2] / (g + ((g >= 0.0) ? r : -r));
          double ssn = 1.0, cc = 1.0;
          p = 0.0;
          for (int i = mq; i <= l - 1; ++i) {
            double f = ssn * e[i - 1], b = cc * e[i - 1];
            slartg_dev(g, f, &cc, &ssn, &r);
            if (i != mq) e[i - 2] = r;
            g = d[i - 1] - p;
            r = (d[i] - g) * ssn + 2.0 * cc * b;
            p = ssn * r;
            d[i - 1] = g + p;
            g = cc * r - b;
            wc[i - 1] = cc; wsn[i - 1] = ssn;
          }
          for (int j = mq; j <= l - 1; ++j) {
            double cj = wc[j - 1], sj = wsn[j - 1];
            for (int i = 0; i < 3; ++i) {
              double t = Z[i][j];
              Z[i][j]     = cj * t - sj * Z[i][j - 1];
              Z[i][j - 1] = sj * t + cj * Z[i][j - 1];
            }
          }
          d[l - 1] -= p; e[l - 2] = g;
        }
      }
    }
    // ---- ascending selection sort with column swaps (as in ssteqr)
    for (int ii = 2; ii <= 3; ++ii) {
      int i0 = ii - 1, k = i0;
      double p = d[i0 - 1];
      for (int j = ii; j <= 3; ++j) if (d[j - 1] < p) { k = j; p = d[j - 1]; }
      if (k != i0) {
        d[k - 1] = d[i0 - 1]; d[i0 - 1] = p;
        for (int rr = 0; rr < 3; ++rr) { double t = Z[rr][i0 - 1]; Z[rr][i0 - 1] = Z[rr][k - 1]; Z[rr][k - 1] = t; }
      }
    }
  }
  // ---- sormtr: Z := H1 * Z
  if (tau != 0.0) {
    for (int j = 0; j < 3; ++j) {
      double w = Z[1][j] + v2 * Z[2][j];
      Z[1][j] -= tau * w;
      Z[2][j] -= tau * v2 * w;
    }
  }
  for (int i = 0; i < 3; ++i)
    for (int j = 0; j < 3; ++j)
      V[i][j] = (float)Z[i][2 - j];
}

// ===================== kernel 0: pack pos -> float4 {x,y,z,sq} =====================
__global__ __launch_bounds__(256) void pack_kernel(const float* __restrict__ pos,
                                                   float4* __restrict__ pos4) {
#pragma clang fp contract(off)
  int i = blockIdx.x * 256 + threadIdx.x;
  if (i < NPOINTS) {
    float x = pos[3 * i + 0], y = pos[3 * i + 1], z = pos[3 * i + 2];
    float sq = (x * x + y * y) + z * z;   // XLA reduce order (same as r6)
    pos4[i] = make_float4(x, y, z, sq);
  }
}

// ===================== kernel 1: exact KNN (r17 structure — at its floor ~414us) ======
// Order: C = (fkey(d2) << 32) | (0xFFFFFFFF - idx). 32 smallest C == r6-verified
// semantics (key asc, ties -> HIGHER index first). Chain-A d2 unchanged.
#define WPB  4    // waves per block
#define RPW  2    // rows per wave -> 8 rows per block
#define TPTS 512  // tile points (8 KB)
#define NTIL (NPOINTS / TPTS)
#define CAP  128  // candidate capacity per row (E[cnt]~44; serial fallback kept)

__global__ __launch_bounds__(256) void knn_kernel(const float4* __restrict__ pos4,
                                                  unsigned* __restrict__ idx_out) {
#pragma clang fp contract(off)
  __shared__ float4 tile[TPTS];            // 8 KB
  __shared__ ull cand[WPB][RPW][CAP];      // 8 KB
  __shared__ ull sel[WPB][RPW][KNN];       // 2 KB
  const int tid  = threadIdx.x;
  const int lane = tid & 63;
  const int wave = tid >> 6;
  const int rowbase = (blockIdx.x * WPB + wave) * RPW;
  const float INF = __int_as_float(0x7f800000);

  float rx[RPW], ry[RPW], rz[RPW], rq[RPW];
#pragma unroll
  for (int r = 0; r < RPW; ++r) {
    const float4 rp = pos4[rowbase + r];
    rx[r] = rp.x; ry[r] = rp.y; rz[r] = rp.z; rq[r] = rp.w;
  }

  // named prefetch registers (rule #20: NO arrays)
  float4 s0 = pos4[0 * 256 + tid];
  float4 s1 = pos4[1 * 256 + tid];

  // ---- phase A: per-lane MIN d2, dual chains (even/odd chunk) ----
  float ka[RPW], kb[RPW];
#pragma unroll
  for (int r = 0; r < RPW; ++r) { ka[r] = INF; kb[r] = INF; }
  for (int t = 0; t < NTIL; ++t) {
    __syncthreads();                       // prior tile fully consumed (r2 lesson)
    tile[0 * 256 + tid] = s0;
    tile[1 * 256 + tid] = s1;
    __syncthreads();
    if (t + 1 < NTIL) {
      const int base = (t + 1) * TPTS + tid;
      s0 = pos4[base + 0 * 256];
      s1 = pos4[base + 1 * 256];           // in flight across the compute below
    }
#pragma unroll 2
    for (int ch = 0; ch < TPTS / 64; ch += 2) {
      const float4 p0 = tile[ch * 64 + lane];
      const float4 p1 = tile[(ch + 1) * 64 + lane];
#pragma unroll
      for (int r = 0; r < RPW; ++r) {
        const float md0 = __builtin_fmaf(rz[r], p0.z, __builtin_fmaf(ry[r], p0.y, rx[r] * p0.x));
        const float d20 = (rq[r] + p0.w) - 2.0f * md0;
        ka[r] = fminf(ka[r], d20);
        const float md1 = __builtin_fmaf(rz[r], p1.z, __builtin_fmaf(ry[r], p1.y, rx[r] * p1.x));
        const float d21 = (rq[r] + p1.w) - 2.0f * md1;
        kb[r] = fminf(kb[r], d21);
      }
    }
  }

  // ---- per-row float threshold Tt = 32nd smallest of the 64 lane minima ----
  // Certified: <=31 global values strictly < T32, each in one lane => Tt >= T32.
  float Ttf[RPW];
#pragma unroll
  for (int r = 0; r < RPW; ++r) {
    float k1f = fminf(ka[r], kb[r]);       // exact lane-min (min associative)
    int head = 0;
    float T = 0.f;
    for (int it = 0; it < KNN; ++it) {
      float v = (head == 0) ? k1f : INF;
      float m = v;
      for (int off = 1; off < 64; off <<= 1) {
        float o = __shfl_xor(m, off, 64);
        m = fminf(m, o);
      }
      ull win = __ballot(v == m);
      int wl = __ffsll((long long)win) - 1;
      if (lane == wl) ++head;
      T = m;
    }
    Ttf[r] = T;
  }

  // ---- phase B: compact candidates with d2 <= Ttf per row (tiled + any-skip) ----
  s0 = pos4[0 * 256 + tid];
  s1 = pos4[1 * 256 + tid];
  unsigned cnt0 = 0, cnt1 = 0;
  const float T0 = Ttf[0], T1 = Ttf[1];
  for (int t = 0; t < NTIL; ++t) {
    __syncthreads();
    tile[0 * 256 + tid] = s0;
    tile[1 * 256 + tid] = s1;
    __syncthreads();
    if (t + 1 < NTIL) {
      const int base = (t + 1) * TPTS + tid;
      s0 = pos4[base + 0 * 256];
      s1 = pos4[base + 1 * 256];
    }
#pragma unroll 2
    for (int ch = 0; ch < TPTS / 64; ++ch) {
      const int j = t * TPTS + ch * 64 + lane;
      const float4 p = tile[ch * 64 + lane];
      const float md0 = __builtin_fmaf(rz[0], p.z, __builtin_fmaf(ry[0], p.y, rx[0] * p.x));
      const float d20 = (rq[0] + p.w) - 2.0f * md0;
      const float md1 = __builtin_fmaf(rz[1], p.z, __builtin_fmaf(ry[1], p.y, rx[1] * p.x));
      const float d21 = (rq[1] + p.w) - 2.0f * md1;
      const bool c0 = (d20 <= T0);
      const bool c1 = (d21 <= T1);
      if (__any(c0 || c1)) {               // exact skip: if false, both m==0, cnt+=0
        const ull m0 = __ballot(c0);
        if (c0) {
          unsigned slot = cnt0 + prefix64(m0);
          if (slot < CAP)
            cand[wave][0][slot] = ((ull)fkey(d20) << 32) | (ull)(0xFFFFFFFFu - (unsigned)j);
        }
        cnt0 += (unsigned)__popcll(m0);
        const ull m1 = __ballot(c1);
        if (c1) {
          unsigned slot = cnt1 + prefix64(m1);
          if (slot < CAP)
            cand[wave][1][slot] = ((ull)fkey(d21) << 32) | (ull)(0xFFFFFFFFu - (unsigned)j);
        }
        cnt1 += (unsigned)__popcll(m1);
      }
    }
  }
  __builtin_amdgcn_s_waitcnt(0);   // drain our ds_writes (wave-private region)

  unsigned cnt[RPW];
  cnt[0] = cnt0; cnt[1] = cnt1;
#pragma unroll
  for (int r = 0; r < RPW; ++r) {
    if (cnt[r] <= (unsigned)CAP) {
      // exact wave-parallel extraction of 32 smallest C from <=128 candidates
      ull c0v = (lane < (int)cnt[r]) ? cand[wave][r][lane] : ~0ULL;
      ull c1v = ((lane + 64) < (int)cnt[r]) ? cand[wave][r][lane + 64] : ~0ULL;
      ull lo = (c0v < c1v) ? c0v : c1v;
      ull hi = (c0v < c1v) ? c1v : c0v;
      int head = 0;
      for (int it = 0; it < KNN; ++it) {
        ull v = (head == 0) ? lo : ((head == 1) ? hi : ~0ULL);
        ull m = v;
        for (int off = 1; off < 64; off <<= 1) {
          ull o = shflx64(m, off);
          m = (o < m) ? o : m;
        }
        ull win = __ballot(v == m);
        int wl = __ffsll((long long)win) - 1;
        if (lane == wl) ++head;
        if (lane == 0) sel[wave][r][it] = m;
      }
    } else {
      // exact serial fallback (probability ~0)
      if (lane == 0) {
        int n2 = 0;
        for (int j = 0; j < NPOINTS; ++j) {
          const float4 p = pos4[j];
          const float mdot = __builtin_fmaf(rz[r], p.z, __builtin_fmaf(ry[r], p.y, rx[r] * p.x));
          const float d2 = (rq[r] + p.w) - 2.0f * mdot;
          const unsigned key = fkey(d2);
          const ull C = ((ull)key << 32) | (ull)(0xFFFFFFFFu - (unsigned)j);
          if (n2 < KNN) {
            int b = n2 - 1;
            while (b >= 0 && sel[wave][r][b] > C) { sel[wave][r][b + 1] = sel[wave][r][b]; --b; }
            sel[wave][r][b + 1] = C;
            ++n2;
          } else if (C < sel[wave][r][KNN - 1]) {
            int b = KNN - 2;
            while (b >= 0 && sel[wave][r][b] > C) { sel[wave][r][b + 1] = sel[wave][r][b]; --b; }
            sel[wave][r][b + 1] = C;
          }
        }
      }
    }
  }
  __builtin_amdgcn_s_waitcnt(0);

  // finalize (lane 0): C-ascending == (key asc, idx desc). Emission wants
  // (key asc, idx asc): reverse idx within bit-equal-key runs only (rare).
  if (lane == 0) {
#pragma unroll
    for (int r = 0; r < RPW; ++r) {
      unsigned kk[KNN], ii[KNN];
      for (int a = 0; a < KNN; ++a) {
        ull C = sel[wave][r][a];
        kk[a] = (unsigned)(C >> 32);
        ii[a] = 0xFFFFFFFFu - (unsigned)(C & 0xFFFFFFFFULL);
      }
      int a = 0;
      while (a < KNN) {
        int b = a;
        while (b + 1 < KNN && kk[b + 1] == kk[a]) ++b;
        for (int x = a, y = b; x < y; ++x, --y) { unsigned tmp = ii[x]; ii[x] = ii[y]; ii[y] = tmp; }
        a = b + 1;
      }
      unsigned ob = (unsigned)(rowbase + r) * KNN;
      for (int q = 0; q < KNN; ++q) idx_out[ob + q] = ii[q];
    }
  }
}

// ===================== kernel 2: mean + cov + eigh per point (fp32) =====================
// 64-thread blocks x 256 blocks -> all 256 CUs busy.
__global__ __launch_bounds__(64) void pca_kernel(const float4* __restrict__ pos4,
                                                 const unsigned* __restrict__ idx,
                                                 float* __restrict__ center,
                                                 float* __restrict__ Vmat) {
#pragma clang fp contract(off)
  int n = blockIdx.x * 64 + threadIdx.x;
  if (n >= NPOINTS) return;
  float sx = 0.f, sy = 0.f, sz = 0.f;
  for (int k = 0; k < KNN; ++k) {
    unsigned j = idx[n * KNN + k];
    const float4 p = pos4[j];
    sx += p.x; sy += p.y; sz += p.z;
  }
  float cx = sx * 0.03125f, cy = sy * 0.03125f, cz = sz * 0.03125f;
  float c00 = 0.f, c10 = 0.f, c20 = 0.f, c11 = 0.f, c21 = 0.f, c22 = 0.f;
  for (int k = 0; k < KNN; ++k) {
    unsigned j = idx[n * KNN + k];
    const float4 p = pos4[j];
    float lx = p.x - cx;
    float ly = p.y - cy;
    float lz = p.z - cz;
    c00 += lx * lx; c10 += lx * ly; c20 += lx * lz;
    c11 += ly * ly; c21 += ly * lz; c22 += lz * lz;
  }
  c00 *= 0.03125f; c10 *= 0.03125f; c20 *= 0.03125f;
  c11 *= 0.03125f; c21 *= 0.03125f; c22 *= 0.03125f;
  float V[3][3];
  eigh3(c00, c10, c20, c11, c21, c22, V);
  center[n * 3 + 0] = cx; center[n * 3 + 1] = cy; center[n * 3 + 2] = cz;
  for (int i = 0; i < 3; ++i)
    for (int j2 = 0; j2 < 3; ++j2)
      Vmat[n * 9 + i * 3 + j2] = V[i][j2];
}

// ===================== kernel 3: basis + G[b,i] + i-split matmul ====================
// r18: matmul phase i-SPLIT across waves — wave w handles i in [16w,16w+16) for ALL
// 4 points, loading each coeff value ONCE (4x less L2 coeff traffic: 7.2GB -> 1.8GB).
// Cross-wave partials reduced in fixed order (w0+w1)+(w2+w3) — smooth fp change only.
#define NT 4
__global__ __launch_bounds__(256) void conv_kernel(const float4* __restrict__ pos4,
                                                   const float* __restrict__ chan,
                                                   const float* __restrict__ coeff,
                                                   const unsigned* __restrict__ idx,
                                                   const float* __restrict__ center,
                                                   const float* __restrict__ Vmat,
                                                   float* __restrict__ out) {
#pragma clang fp contract(off)
  __shared__ float G[NT][NBASIS][64];      // 27 KB
  __shared__ float P[NT][NT][64];          // partials [wave][point][lane], 4 KB
  __shared__ float Tsh[NT][64];            // 1 KB
  const int tid  = threadIdx.x;
  const int lane = tid & 63;
  const int wave = tid >> 6;
  const int n0 = blockIdx.x * NT;
  const int n  = n0 + wave;

  {
    const float cx = center[n * 3 + 0], cy = center[n * 3 + 1], cz = center[n * 3 + 2];
    const float V00 = Vmat[n * 9 + 0], V01 = Vmat[n * 9 + 1], V02 = Vmat[n * 9 + 2];
    const float V10 = Vmat[n * 9 + 3], V11 = Vmat[n * 9 + 4], V12 = Vmat[n * 9 + 5];
    const float V20 = Vmat[n * 9 + 6], V21 = Vmat[n * 9 + 7], V22 = Vmat[n * 9 + 8];
    float g[NBASIS];
#pragma unroll
    for (int b = 0; b < NBASIS; ++b) g[b] = 0.f;
    for (int k = 0; k < KNN; ++k) {
      const unsigned j = idx[n * KNN + k];
      const float4 pj = pos4[j];                    // wave-uniform -> scalar load
      const float lx = pj.x - cx;
      const float ly = pj.y - cy;
      const float lz = pj.z - cz;
      const float X  = lx * V00 + ly * V10 + lz * V20;
      const float Y  = lx * V01 + ly * V11 + lz * V21;
      const float Zc = lx * V02 + ly * V12 + lz * V22;
      const float r = sqrtf(((X * X + Y * Y) + Zc * Zc) + 1e-8f);
      float u = Zc / r;
      u = fminf(fmaxf(u, -0.999999f), 0.999999f);
      const float ct1 = u, ct2 = 2.f * u * u - 1.f;
      const float rho2 = X * X + Y * Y;
      const float cp1 = (rho2 > 0.f) ? (X / sqrtf(rho2)) : 1.f;
      const float cp2 = 2.f * cp1 * cp1 - 1.f;
      const float f = chan[(size_t)j * 64 + lane];
      const float pr1 = r, pr2 = r * r;
      float tc[9];
      tc[0] = 1.f; tc[1] = cp1; tc[2] = cp2;
      tc[3] = ct1; tc[4] = ct1 * cp1; tc[5] = ct1 * cp2;
      tc[6] = ct2; tc[7] = ct2 * cp1; tc[8] = ct2 * cp2;
#pragma unroll
      for (int m9 = 0; m9 < 9; ++m9) {
        g[m9]      = __builtin_fmaf(tc[m9],       f, g[m9]);
        g[9 + m9]  = __builtin_fmaf(pr1 * tc[m9], f, g[9 + m9]);
        g[18 + m9] = __builtin_fmaf(pr2 * tc[m9], f, g[18 + m9]);
      }
    }
#pragma unroll
    for (int b = 0; b < NBASIS; ++b) G[wave][b][lane] = g[b];
  }
  __syncthreads();

  // i-split matmul: this wave covers i in [wave*16, wave*16+16) for all 4 points.
  float a0 = 0.f, a1 = 0.f, a2 = 0.f, a3 = 0.f;   // named accumulators (rule #20)
  for (int b = 0; b < NBASIS; ++b) {
    const float4* g0p = (const float4*)(&G[0][b][wave * 16]);
    const float4* g1p = (const float4*)(&G[1][b][wave * 16]);
    const float4* g2p = (const float4*)(&G[2][b][wave * 16]);
    const float4* g3p = (const float4*)(&G[3][b][wave * 16]);
    const float* cp = coeff + (size_t)(b * 64 + wave * 16) * 64 + lane;
#pragma unroll
    for (int i4 = 0; i4 < 4; ++i4) {
      const float c0 = cp[(i4 * 4 + 0) * 64];
      const float c1 = cp[(i4 * 4 + 1) * 64];
      const float c2 = cp[(i4 * 4 + 2) * 64];
      const float c3 = cp[(i4 * 4 + 3) * 64];
      const float4 q0 = g0p[i4];
      const float4 q1 = g1p[i4];
      const float4 q2 = g2p[i4];
      const float4 q3 = g3p[i4];
      a0 = __builtin_fmaf(c0, q0.x, a0); a0 = __builtin_fmaf(c1, q0.y, a0);
      a0 = __builtin_fmaf(c2, q0.z, a0); a0 = __builtin_fmaf(c3, q0.w, a0);
      a1 = __builtin_fmaf(c0, q1.x, a1); a1 = __builtin_fmaf(c1, q1.y, a1);
      a1 = __builtin_fmaf(c2, q1.z, a1); a1 = __builtin_fmaf(c3, q1.w, a1);
      a2 = __builtin_fmaf(c0, q2.x, a2); a2 = __builtin_fmaf(c1, q2.y, a2);
      a2 = __builtin_fmaf(c2, q2.z, a2); a2 = __builtin_fmaf(c3, q2.w, a2);
      a3 = __builtin_fmaf(c0, q3.x, a3); a3 = __builtin_fmaf(c1, q3.y, a3);
      a3 = __builtin_fmaf(c2, q3.z, a3); a3 = __builtin_fmaf(c3, q3.w, a3);
    }
  }
  P[wave][0][lane] = a0;
  P[wave][1][lane] = a1;
  P[wave][2][lane] = a2;
  P[wave][3][lane] = a3;
  __syncthreads();

  // reduce: wave w finalizes point w with fixed order (w0+w1)+(w2+w3)
  {
    const float s = ((P[0][wave][lane] + P[1][wave][lane]) +
                     (P[2][wave][lane] + P[3][wave][lane])) * 0.03125f;
    Tsh[wave][lane] = s;
  }
  __syncthreads();
  {
    const int o = tid >> 2, nn = tid & 3;             // 256 threads = 4 pts x 64 outs
    out[(size_t)o * NPOINTS + (n0 + nn)] = Tsh[nn][o];
  }
}

// ===================== launch =====================
extern "C" void kernel_launch(void* const* d_in, const int* in_sizes, int n_in,
                              void* d_out, int out_size, void* d_ws, size_t ws_size,
                              hipStream_t stream) {
  (void)in_sizes; (void)n_in; (void)out_size; (void)ws_size;
  const float* pos   = (const float*)d_in[0];
  const float* chan  = (const float*)d_in[1];
  const float* coeff = (const float*)d_in[2];
  float* out = (float*)d_out;
  unsigned char* ws = (unsigned char*)d_ws;
  float4*   pos4   = (float4*)(ws);                                    // 256 KiB
  unsigned* idx    = (unsigned*)(ws + (size_t)NPOINTS * 16);           // 2 MiB
  float*    center = (float*)(ws + (size_t)NPOINTS * 16 + (size_t)NPOINTS * KNN * 4);          // 192 KiB
  float*    Vmat   = (float*)(ws + (size_t)NPOINTS * 16 + (size_t)NPOINTS * KNN * 4
                              + (size_t)NPOINTS * 12);                 // 576 KiB
  hipLaunchKernelGGL(pack_kernel, dim3(NPOINTS / 256),         dim3(256), 0, stream, pos, pos4);
  hipLaunchKernelGGL(knn_kernel,  dim3(NPOINTS / (WPB * RPW)), dim3(256), 0, stream, pos4, idx);
  hipLaunchKernelGGL(pca_kernel,  dim3(NPOINTS / 64),          dim3(64),  0, stream, pos4, idx, center, Vmat);
  hipLaunchKernelGGL(conv_kernel, dim3(NPOINTS / NT),          dim3(256), 0, stream, pos4, chan, coeff, idx, center, Vmat, out);
}